// Round 6
// baseline (1697.624 us; speedup 1.0000x reference)
//
#include <hip/hip_runtime.h>
#include <math.h>

// ---------------- problem constants ----------------
#define BB     64
#define LLEN   197
#define BLROWS 12608      // BB*LLEN
#define MPAD   12672      // BLROWS padded to 99*128 (= 792*16)
#define DMODEL 192
#define NHEAD  3
#define DHEAD  64
#define M2FEAT 256
#define FFDIM  768
#define NDEPTH 12
#define NCLS   1000
#define NPATCH 196
#define BPROWS 12544      // BB*NPATCH (= 98*128 exactly)
#define KPATCH 768
#define PHIRS  264        // Phi LDS row stride (256 + 8 pad, 16B-aligned)
#define PHTRS  40         // PhT LDS row stride (32 + 8 pad, 16B-aligned)
#define VLT    208        // Vt row length (197 padded, 16B-aligned)

#define MODE_PLAIN 0
#define MODE_RELU  1
#define MODE_QKV   2      // cols<384 -> qkv; cols>=384 -> transposed Vt

typedef unsigned short ushort;
typedef __attribute__((ext_vector_type(8))) short bf16x8;
typedef __attribute__((ext_vector_type(4))) float floatx4;
typedef __attribute__((ext_vector_type(4))) short short4v;

__device__ __forceinline__ float wave_reduce_sum(float v) {
#pragma unroll
  for (int s = 32; s > 0; s >>= 1) v += __shfl_xor(v, s, 64);
  return v;
}
__device__ __forceinline__ ushort f2bf(float f) {  // RNE fp32->bf16
  unsigned u = __float_as_uint(f);
  return (ushort)((u + 0x7fffu + ((u >> 16) & 1u)) >> 16);
}
__device__ __forceinline__ float bf2f(ushort u) {
  return __uint_as_float(((unsigned)u) << 16);
}
// async global->LDS, 16 B per lane; LDS dest wave-uniform (HW adds lane*16);
// global src is PER-LANE -> swizzled LDS layouts via pre-swizzled src (T2).
__device__ __forceinline__ void gll16(const ushort* g, ushort* l) {
  __builtin_amdgcn_global_load_lds(
      (const __attribute__((address_space(1))) void*)g,
      (__attribute__((address_space(3))) void*)l, 16, 0, 0);
}

__global__ void zero_buf(uint4* __restrict__ p, int n16) {
  const int i = blockIdx.x * 256 + threadIdx.x;
  if (i < n16) p[i] = uint4{0, 0, 0, 0};
}

// ====== bf16 GEMM, 128x64 tile, BK=64, A in LDS (dbuf, swz8), W in REGS ======
// block 256 = 4 waves (2x2 of 64x32). W rows are exactly the per-lane MFMA
// B-fragment (row = col-tile*16+l16, 16 B/lane/k-slice) -> load straight from
// global (L2-resident weights), no LDS staging. 32 KB LDS -> 4+ blocks/CU.
// bias (+relu) out. MODE_QKV: cols<384 -> qkv; [384,576) -> Vt[bh][d][l].
__global__ __launch_bounds__(256) void gemm_bf2(
    const ushort* __restrict__ A, int lda,
    const ushort* __restrict__ W, int ldw,
    const float* __restrict__ bias,
    ushort* __restrict__ C, int ldc, ushort* __restrict__ Vt,
    int Kdim, int mode)
{
  __shared__ __align__(16) ushort As[2][128 * 64];   // 32 KB
  const int tid = threadIdx.x;
  const int bm = blockIdx.x, bn = blockIdx.y;
  const int wave = tid >> 6, lane = tid & 63;
  const int wm = (wave >> 1) * 64, wn = (wave & 1) * 32;
  const int quad = lane >> 4, l16 = lane & 15;
  const int srow = lane >> 3;                 // 0..7 within an 8-row stage call
  const int scol = ((lane & 7) ^ srow) * 8;   // swizzled source col group
  const ushort* Ap = A + (size_t)(bm * 128) * lda;
  const ushort* Wp0 = W + (size_t)(bn * 64 + wn + l16) * ldw;       // j=0 rows
  const ushort* Wp1 = W + (size_t)(bn * 64 + wn + 16 + l16) * ldw;  // j=1 rows
  floatx4 acc[4][2] = {};
  const int nT = Kdim >> 6;
#pragma unroll
  for (int t = 0; t < 4; ++t) {
    const int rb = (t * 4 + wave) * 8;
    gll16(Ap + (size_t)(rb + srow) * lda + scol, &As[0][rb * 64]);
  }
  bf16x8 wf[2][2];   // [ks][j] current k-tile W fragments
#pragma unroll
  for (int ks = 0; ks < 2; ++ks) {
    wf[ks][0] = *(const bf16x8*)(Wp0 + (ks * 4 + quad) * 8);
    wf[ks][1] = *(const bf16x8*)(Wp1 + (ks * 4 + quad) * 8);
  }
  for (int kt = 0; kt < nT; ++kt) {
    const int cur = kt & 1;
    __syncthreads();                 // As[cur] + wf ready (vmcnt0 drain)
    bf16x8 wfn[2][2];
    if (kt + 1 < nT) {
      const int kk = (kt + 1) * 64, nxt = cur ^ 1;
#pragma unroll
      for (int t = 0; t < 4; ++t) {
        const int rb = (t * 4 + wave) * 8;
        gll16(Ap + (size_t)(rb + srow) * lda + kk + scol, &As[nxt][rb * 64]);
      }
#pragma unroll
      for (int ks = 0; ks < 2; ++ks) {
        wfn[ks][0] = *(const bf16x8*)(Wp0 + kk + (ks * 4 + quad) * 8);
        wfn[ks][1] = *(const bf16x8*)(Wp1 + kk + (ks * 4 + quad) * 8);
      }
    }
#pragma unroll
    for (int ks = 0; ks < 2; ++ks) {
      bf16x8 af[4];
#pragma unroll
      for (int i = 0; i < 4; ++i) {
        const int ra = wm + i * 16 + l16;
        af[i] = *(const bf16x8*)&As[cur][ra * 64 + ((((ks << 2) | quad) ^ (ra & 7)) * 8)];
      }
#pragma unroll
      for (int i = 0; i < 4; ++i)
#pragma unroll
        for (int j = 0; j < 2; ++j)
          acc[i][j] = __builtin_amdgcn_mfma_f32_16x16x32_bf16(af[i], wf[ks][j], acc[i][j], 0, 0, 0);
    }
    if (kt + 1 < nT) {
#pragma unroll
      for (int ks = 0; ks < 2; ++ks)
#pragma unroll
        for (int j = 0; j < 2; ++j) wf[ks][j] = wfn[ks][j];
    }
  }
  if (mode == MODE_QKV) {
#pragma unroll
    for (int i = 0; i < 4; ++i)
#pragma unroll
      for (int r = 0; r < 4; ++r) {
        const int grow = bm * 128 + wm + i * 16 + quad * 4 + r;
        const int bidx = grow / 197;           // magic-mul
        const int lloc = grow - bidx * 197;
#pragma unroll
        for (int j = 0; j < 2; ++j) {
          const int col = bn * 64 + wn + j * 16 + l16;
          const float o = acc[i][j][r] + bias[col];
          if (col < 384) {
            C[(size_t)grow * ldc + col] = f2bf(o);
          } else if (grow < BLROWS) {
            const int h = (col - 384) >> 6, d = (col - 384) & 63;
            Vt[((size_t)(bidx * 3 + h) * 64 + d) * VLT + lloc] = f2bf(o);
          }
        }
      }
  } else {
#pragma unroll
    for (int j = 0; j < 2; ++j) {
      const int col = bn * 64 + wn + j * 16 + l16;
      const float bv = bias[col];
#pragma unroll
      for (int i = 0; i < 4; ++i)
#pragma unroll
        for (int r = 0; r < 4; ++r) {
          const int grow = bm * 128 + wm + i * 16 + quad * 4 + r;
          float o = acc[i][j][r] + bv;
          if (mode == MODE_RELU) o = fmaxf(o, 0.f);
          C[(size_t)grow * ldc + col] = f2bf(o);
        }
    }
  }
}

// == fused GEMM + bias + residual + LayerNorm(x1/x2), 16-row tile, W in REGS ==
// grid 792 (3.1/CU), LDS ~5 KB (A dbuf only). 4 waves each own 48 cols
// (3 n-tiles, acc[3]); all share the 16 A-rows. Row LN = quad-shfl partial +
// 4-way cross-wave LDS combine (2 epilogue barriers). Writes XC in place.
__global__ __launch_bounds__(256) void gemm_ln(
    const ushort* __restrict__ A, int lda,
    const ushort* __restrict__ W, int ldw,
    const float* __restrict__ bias,
    ushort* __restrict__ XC,
    const float* __restrict__ ga, const float* __restrict__ ba,
    const float* __restrict__ gb, const float* __restrict__ bb,
    int Kdim, int dln)
{
  __shared__ __align__(16) ushort As[2][16 * 64];    // 4 KB
  __shared__ float p1s[4][16], p1q[4][16], p2s[4][16], p2q[4][16];
  const int tid = threadIdx.x;
  const int bm = blockIdx.x;
  const int wave = tid >> 6, lane = tid & 63;
  const int quad = lane >> 4, l16 = lane & 15;
  const int srow = lane >> 3;
  const int scol = ((lane & 7) ^ srow) * 8;
  const ushort* Ap = A + (size_t)(bm * 16) * lda;
  const ushort* Wp0 = W + (size_t)((wave * 3 + 0) * 16 + l16) * ldw;
  const ushort* Wp1 = W + (size_t)((wave * 3 + 1) * 16 + l16) * ldw;
  const ushort* Wp2 = W + (size_t)((wave * 3 + 2) * 16 + l16) * ldw;
  floatx4 acc[3] = {};
  const int nT = Kdim >> 6;
  if (wave < 2) gll16(Ap + (size_t)(wave * 8 + srow) * lda + scol, &As[0][wave * 8 * 64]);
  bf16x8 wf[2][3];
#pragma unroll
  for (int ks = 0; ks < 2; ++ks) {
    wf[ks][0] = *(const bf16x8*)(Wp0 + (ks * 4 + quad) * 8);
    wf[ks][1] = *(const bf16x8*)(Wp1 + (ks * 4 + quad) * 8);
    wf[ks][2] = *(const bf16x8*)(Wp2 + (ks * 4 + quad) * 8);
  }
  for (int kt = 0; kt < nT; ++kt) {
    const int cur = kt & 1;
    __syncthreads();                 // As[cur] + wf ready
    bf16x8 wfn[2][3];
    if (kt + 1 < nT) {
      const int kk = (kt + 1) * 64, nxt = cur ^ 1;
      if (wave < 2)
        gll16(Ap + (size_t)(wave * 8 + srow) * lda + kk + scol, &As[nxt][wave * 8 * 64]);
#pragma unroll
      for (int ks = 0; ks < 2; ++ks) {
        wfn[ks][0] = *(const bf16x8*)(Wp0 + kk + (ks * 4 + quad) * 8);
        wfn[ks][1] = *(const bf16x8*)(Wp1 + kk + (ks * 4 + quad) * 8);
        wfn[ks][2] = *(const bf16x8*)(Wp2 + kk + (ks * 4 + quad) * 8);
      }
    }
#pragma unroll
    for (int ks = 0; ks < 2; ++ks) {
      const int ra = l16;
      const bf16x8 af = *(const bf16x8*)&As[cur][ra * 64 + ((((ks << 2) | quad) ^ (ra & 7)) * 8)];
#pragma unroll
      for (int j = 0; j < 3; ++j)
        acc[j] = __builtin_amdgcn_mfma_f32_16x16x32_bf16(af, wf[ks][j], acc[j], 0, 0, 0);
    }
    if (kt + 1 < nT) {
#pragma unroll
      for (int ks = 0; ks < 2; ++ks)
#pragma unroll
        for (int j = 0; j < 3; ++j) wf[ks][j] = wfn[ks][j];
    }
  }
  // ---- epilogue: bias + residual; LN = quad shfl + 4-wave combine ----
  float xr[4][3];
#pragma unroll
  for (int r = 0; r < 4; ++r) {
    const int rloc = quad * 4 + r;
    const int row = bm * 16 + rloc;
    const ushort* xp = XC + (size_t)row * DMODEL;
    float s = 0.f, sq = 0.f;
#pragma unroll
    for (int j = 0; j < 3; ++j) {
      const int col = (wave * 3 + j) * 16 + l16;
      const float o = acc[j][r] + bias[col] + bf2f(xp[col]);
      xr[r][j] = o; s += o; sq += o * o;
    }
#pragma unroll
    for (int m = 1; m < 16; m <<= 1) {
      s += __shfl_xor(s, m, 64); sq += __shfl_xor(sq, m, 64);
    }
    if (l16 == 0) { p1s[wave][rloc] = s; p1q[wave][rloc] = sq; }
  }
  __syncthreads();
#pragma unroll
  for (int r = 0; r < 4; ++r) {
    const int rloc = quad * 4 + r;
    const float s = p1s[0][rloc] + p1s[1][rloc] + p1s[2][rloc] + p1s[3][rloc];
    const float sq = p1q[0][rloc] + p1q[1][rloc] + p1q[2][rloc] + p1q[3][rloc];
    const float mu = s * (1.f / 192.f);
    const float var = sq * (1.f / 192.f) - mu * mu;
    const float rs = rsqrtf(var + 1e-5f);
#pragma unroll
    for (int j = 0; j < 3; ++j) {
      const int col = (wave * 3 + j) * 16 + l16;
      xr[r][j] = (xr[r][j] - mu) * rs * ga[col] + ba[col];
    }
  }
  if (dln) {
#pragma unroll
    for (int r = 0; r < 4; ++r) {
      const int rloc = quad * 4 + r;
      float s = 0.f, sq = 0.f;
#pragma unroll
      for (int j = 0; j < 3; ++j) { s += xr[r][j]; sq += xr[r][j] * xr[r][j]; }
#pragma unroll
      for (int m = 1; m < 16; m <<= 1) {
        s += __shfl_xor(s, m, 64); sq += __shfl_xor(sq, m, 64);
      }
      if (l16 == 0) { p2s[wave][rloc] = s; p2q[wave][rloc] = sq; }
    }
    __syncthreads();
#pragma unroll
    for (int r = 0; r < 4; ++r) {
      const int rloc = quad * 4 + r;
      const float s = p2s[0][rloc] + p2s[1][rloc] + p2s[2][rloc] + p2s[3][rloc];
      const float sq = p2q[0][rloc] + p2q[1][rloc] + p2q[2][rloc] + p2q[3][rloc];
      const float mu = s * (1.f / 192.f);
      const float var = sq * (1.f / 192.f) - mu * mu;
      const float rs = rsqrtf(var + 1e-5f);
#pragma unroll
      for (int j = 0; j < 3; ++j) {
        const int col = (wave * 3 + j) * 16 + l16;
        xr[r][j] = (xr[r][j] - mu) * rs * gb[col] + bb[col];
      }
    }
  }
#pragma unroll
  for (int r = 0; r < 4; ++r) {
    const int row = bm * 16 + quad * 4 + r;
    ushort* xp = XC + (size_t)row * DMODEL;
#pragma unroll
    for (int j = 0; j < 3; ++j) xp[(wave * 3 + j) * 16 + l16] = f2bf(xr[r][j]);
  }
}

// =========== fused FAVOR-K + KV accumulation (V pre-transposed) ===========
// grid (192 bh, 2 mh). Per 32-token chunk: u = K*scale @ Om_half^T (MFMA),
// phi -> PhT [128 m][32 l] (pad 40); Vts staged d-major from Vt (dbuf, group-
// swizzled src); KV += PhT @ Vts. Out KVt [bh][80 d][256 f] (d=64: ksum).
__global__ __launch_bounds__(256) void kv_fused(
    const ushort* __restrict__ qkv, const ushort* __restrict__ OmT,
    const ushort* __restrict__ Vt, ushort* __restrict__ KVt)
{
  __shared__ __align__(16) ushort Ks[32 * 64];        // 4 KB (swz8)
  __shared__ __align__(16) ushort Om[64 * 64];        // 8 KB (swz8)
  __shared__ __align__(16) ushort PhT[128 * PHTRS];   // 10 KB
  __shared__ __align__(16) ushort Vts[2][64 * 32];    // 8 KB (swz4, dbuf)
  __shared__ __align__(16) ushort Vcst[16 * 32];      // 1 KB (ksum + zero rows)
  __shared__ float offs[32];
  const int tid = threadIdx.x;
  const int bh = blockIdx.x, mh = blockIdx.y;
  const int b = bh / 3, h = bh - b * 3;
  const int wave = tid >> 6, lane = tid & 63;
  const int quad = lane >> 4, l16 = lane & 15;
  const int lr8 = lane >> 3, g8 = lane & 7;
  const int lr4 = lane >> 2, g4 = lane & 3;
#pragma unroll
  for (int t = 0; t < 2; ++t) {
    const int rb = (t * 4 + wave) * 8;
    const int row = rb + lr8;
    gll16(OmT + (size_t)(mh * 64 + row) * 64 + ((g8 ^ (row & 7)) * 8), &Om[rb * 64]);
  }
  {
    const int rowK = wave * 8 + lr8;
    gll16(qkv + (size_t)(b * 197 + rowK) * 576 + 192 + h * 64 + ((g8 ^ (rowK & 7)) * 8),
          &Ks[wave * 8 * 64]);
    const int rowV = wave * 16 + lr4;
    gll16(Vt + ((size_t)bh * 64 + rowV) * VLT + ((g4 ^ (rowV & 3)) * 8),
          &Vts[0][wave * 16 * 32]);
  }
  for (int e = tid; e < 16 * 32; e += 256) Vcst[e] = (e < 32) ? 0x3F80 : 0;
  floatx4 acc[2][5] = {};
  for (int c = 0; c < 7; ++c) {
    const int l0 = c * 32;
    const int cur = c & 1;
    __syncthreads();   // staged data ready (vmcnt0)
    if (tid < 64) {
      const int row = tid >> 1, half = tid & 1;
      float s = 0.f;
#pragma unroll
      for (int t = 0; t < 4; ++t) {
        bf16x8 v8 = *(const bf16x8*)&Ks[row * 64 + (((half * 4 + t) ^ (row & 7)) * 8)];
#pragma unroll
        for (int q = 0; q < 8; ++q) { float xv = bf2f((ushort)v8[q]); s += xv * xv; }
      }
      s += __shfl_xor(s, 1, 64);
      if (half == 0) offs[row] = 0.0625f * s;   // 0.5*scale^2 (scale^2=0.125)
    }
    floatx4 ui[2] = {};
#pragma unroll
    for (int ksb = 0; ksb < 2; ++ksb) {
      bf16x8 af[2], bfm;
#pragma unroll
      for (int i = 0; i < 2; ++i) {
        const int row = i * 16 + l16;
        af[i] = *(const bf16x8*)&Ks[row * 64 + (((quad + (ksb << 2)) ^ (row & 7)) * 8)];
      }
      {
        const int row = wave * 16 + l16;
        bfm = *(const bf16x8*)&Om[row * 64 + (((quad + (ksb << 2)) ^ (row & 7)) * 8)];
      }
#pragma unroll
      for (int i = 0; i < 2; ++i)
        ui[i] = __builtin_amdgcn_mfma_f32_16x16x32_bf16(af[i], bfm, ui[i], 0, 0, 0);
    }
    __syncthreads();   // Ks/Om reads done
    {
      const int mloc = wave * 16 + l16;
#pragma unroll
      for (int i = 0; i < 2; ++i) {
#pragma unroll
        for (int r = 0; r < 4; ++r) {
          const int ll = i * 16 + quad * 4 + r;
          float ep = 0.f, em = 0.f;
          if (l0 + ll < 197) {
            const float off = offs[ll];
            const float u = ui[i][r];
            ep = __expf(u - off) * 0.0625f;
            em = __expf(-u - off) * 0.0625f;
          }
          PhT[mloc * PHTRS + ll] = f2bf(ep);
          PhT[(64 + mloc) * PHTRS + ll] = f2bf(em);
        }
      }
    }
    if (c + 1 < 7) {   // prefetch next chunk (Ks single-buf safe; Vts dbuf)
      const int rowK = wave * 8 + lr8;
      const int lK = (c + 1) * 32 + rowK;
      gll16(qkv + (size_t)(b * 197 + lK) * 576 + 192 + h * 64 + ((g8 ^ (rowK & 7)) * 8),
            &Ks[wave * 8 * 64]);
      const int rowV = wave * 16 + lr4;
      gll16(Vt + ((size_t)bh * 64 + rowV) * VLT + (c + 1) * 32 + ((g4 ^ (rowV & 3)) * 8),
            &Vts[cur ^ 1][wave * 16 * 32]);
    }
    __syncthreads();   // PhT visible (also drains prefetch; harmless)
    bf16x8 af[2], bf[5];
#pragma unroll
    for (int i = 0; i < 2; ++i)
      af[i] = *(const bf16x8*)&PhT[(wave * 32 + i * 16 + l16) * PHTRS + quad * 8];
#pragma unroll
    for (int j = 0; j < 4; ++j) {
      const int row = j * 16 + l16;
      bf[j] = *(const bf16x8*)&Vts[cur][row * 32 + ((quad ^ (row & 3)) * 8)];
    }
    bf[4] = *(const bf16x8*)&Vcst[l16 * 32 + quad * 8];
#pragma unroll
    for (int i = 0; i < 2; ++i)
#pragma unroll
      for (int j = 0; j < 5; ++j)
        acc[i][j] = __builtin_amdgcn_mfma_f32_16x16x32_bf16(af[i], bf[j], acc[i][j], 0, 0, 0);
  }
#pragma unroll
  for (int i = 0; i < 2; ++i) {
    const int prow0 = wave * 32 + i * 16 + quad * 4;
    const int f0 = (prow0 < 64) ? (mh * 64 + prow0) : (128 + mh * 64 + prow0 - 64);
#pragma unroll
    for (int j = 0; j < 5; ++j) {
      const int d = j * 16 + l16;
      short4v pk;
#pragma unroll
      for (int r = 0; r < 4; ++r) pk[r] = (short)f2bf(acc[i][j][r]);
      *(short4v*)(KVt + ((size_t)bh * 80 + d) * 256 + f0) = pk;
    }
  }
}

// =========== fused FAVOR-Q + attn: out = Z * (phiQ @ KVt^T) ===========
// grid (4 l-tiles of 64, 192 bh) -> 768 blocks = 3/CU for barrier overlap.
__global__ __launch_bounds__(256) void attn_fused(
    const ushort* __restrict__ qkv, const ushort* __restrict__ OmT,
    const ushort* __restrict__ KVt, ushort* __restrict__ OUT)
{
  __shared__ __align__(16) ushort Phi[64 * PHIRS];   // 33 KB; [0:8K)=Qs, [8K:24K)=Om
  __shared__ __align__(16) ushort Bs[2][80 * 32];    // 10 KB (swz4)
  __shared__ float offs[64];
  __shared__ float zs[64];
  ushort* Qs = Phi;                 // 64 x 64 (swz8)
  ushort* Om = Phi + 64 * 64;       // 128 x 64 (swz8)
  const int tid = threadIdx.x;
  const int bx = blockIdx.x, bh = blockIdx.y;
  const int b = bh / 3, h = bh - b * 3;
  const int wave = tid >> 6, lane = tid & 63;
  const int quad = lane >> 4, l16 = lane & 15;
  const int lr8 = lane >> 3, g8 = lane & 7;
  const int lr4 = lane >> 2, g4 = lane & 3;
#pragma unroll
  for (int t = 0; t < 2; ++t) {
    const int rb = wave * 16 + t * 8;
    const int row = rb + lr8;
    const int l = bx * 64 + row;
    gll16(qkv + (size_t)(b * 197 + l) * 576 + h * 64 + ((g8 ^ (row & 7)) * 8), &Qs[rb * 64]);
  }
#pragma unroll
  for (int t = 0; t < 4; ++t) {
    const int rb = wave * 32 + t * 8;
    const int row = rb + lr8;
    gll16(OmT + (size_t)row * 64 + ((g8 ^ (row & 7)) * 8), &Om[rb * 64]);
  }
  __syncthreads();
  if (tid < 128) {
    const int row = tid >> 1, half = tid & 1;
    float s = 0.f;
#pragma unroll
    for (int t = 0; t < 4; ++t) {
      bf16x8 v8 = *(const bf16x8*)&Qs[row * 64 + (((half * 4 + t) ^ (row & 7)) * 8)];
#pragma unroll
      for (int q = 0; q < 8; ++q) { float xv = bf2f((ushort)v8[q]); s += xv * xv; }
    }
    s += __shfl_xor(s, 1, 64);
    if (half == 0) offs[row] = 0.0625f * s;
  }
  floatx4 uacc[8] = {};
#pragma unroll
  for (int ksb = 0; ksb < 2; ++ksb) {
    bf16x8 af, bf[8];
    {
      const int row = wave * 16 + l16;
      af = *(const bf16x8*)&Qs[row * 64 + (((quad + (ksb << 2)) ^ (row & 7)) * 8)];
    }
#pragma unroll
    for (int j = 0; j < 8; ++j) {
      const int row = j * 16 + l16;
      bf[j] = *(const bf16x8*)&Om[row * 64 + (((quad + (ksb << 2)) ^ (row & 7)) * 8)];
    }
#pragma unroll
    for (int j = 0; j < 8; ++j)
      uacc[j] = __builtin_amdgcn_mfma_f32_16x16x32_bf16(af, bf[j], uacc[j], 0, 0, 0);
  }
  __syncthreads();   // Qs/Om reads done -> Phi overwrite legal
#pragma unroll
  for (int r = 0; r < 4; ++r) {
    const int l = wave * 16 + quad * 4 + r;
    const float off = offs[l];
#pragma unroll
    for (int j = 0; j < 8; ++j) {
      const int m = j * 16 + l16;
      const float u = uacc[j][r];
      Phi[l * PHIRS + m]       = f2bf(__expf(u - off)  * 0.0625f);
      Phi[l * PHIRS + m + 128] = f2bf(__expf(-u - off) * 0.0625f);
    }
  }
  const ushort* Bp = KVt + (size_t)bh * 80 * 256;
  {
    const int row = wave * 16 + lr4;
    gll16(Bp + (size_t)row * 256 + ((g4 ^ (row & 3)) * 8), &Bs[0][wave * 16 * 32]);
    if (wave == 0)
      gll16(Bp + (size_t)(64 + lr4) * 256 + ((g4 ^ (lr4 & 3)) * 8), &Bs[0][64 * 32]);
  }
  floatx4 acc[5] = {};
  for (int c = 0; c < 8; ++c) {
    const int cur = c & 1;
    __syncthreads();   // Phi visible (c=0) + Bs staging drained + dbuf guard
    if (c + 1 < 8) {
      const int m0 = (c + 1) * 32, nxt = cur ^ 1;
      const int row = wave * 16 + lr4;
      gll16(Bp + (size_t)row * 256 + m0 + ((g4 ^ (row & 3)) * 8), &Bs[nxt][wave * 16 * 32]);
      if (wave == 0)
        gll16(Bp + (size_t)(64 + lr4) * 256 + m0 + ((g4 ^ (lr4 & 3)) * 8), &Bs[nxt][64 * 32]);
    }
    const int m0 = c * 32;
    bf16x8 af, bf[5];
    af = *(const bf16x8*)&Phi[(wave * 16 + l16) * PHIRS + m0 + quad * 8];
#pragma unroll
    for (int j = 0; j < 5; ++j) {
      const int row = j * 16 + l16;
      bf[j] = *(const bf16x8*)&Bs[cur][row * 32 + ((quad ^ (row & 3)) * 8)];
    }
#pragma unroll
    for (int j = 0; j < 5; ++j)
      acc[j] = __builtin_amdgcn_mfma_f32_16x16x32_bf16(af, bf[j], acc[j], 0, 0, 0);
  }
  if (l16 == 0) {
#pragma unroll
    for (int r = 0; r < 4; ++r)
      zs[wave * 16 + quad * 4 + r] = acc[4][r];
  }
  __syncthreads();
#pragma unroll
  for (int r = 0; r < 4; ++r) {
    const int ll = wave * 16 + quad * 4 + r;
    const int l = bx * 64 + ll;
    if (l >= 197) continue;
    const float z = 1.f / (zs[ll] + 1e-6f);
#pragma unroll
    for (int j = 0; j < 4; ++j)
      OUT[(size_t)(b * 197 + l) * 192 + h * 64 + j * 16 + l16] =
          f2bf(acc[j][r] * z);
  }
}

// ---------------- weight pre-conversion ----------------
__global__ void conv_qkv(const float* __restrict__ Wq, const float* __restrict__ Wk,
                         const float* __restrict__ Wv, const float* __restrict__ bq,
                         const float* __restrict__ bk, const float* __restrict__ bv,
                         ushort* __restrict__ dst, float* __restrict__ bdst) {
  const int l = blockIdx.y;
  const int e = blockIdx.x * 256 + threadIdx.x;   // < 576*192
  const int n = e / 192, k = e - n * 192;
  const float* src;
  if (n < 192)      src = Wq + (size_t)l * 36864 + n * 192;
  else if (n < 384) src = Wk + (size_t)l * 36864 + (n - 192) * 192;
  else              src = Wv + (size_t)l * 36864 + (n - 384) * 192;
  dst[(size_t)l * 640 * 192 + e] = f2bf(src[k]);
  if (e < 576) {
    float bvv;
    if (e < 192)      bvv = bq[l * 192 + e];
    else if (e < 384) bvv = bk[l * 192 + e - 192];
    else              bvv = bv[l * 192 + e - 384];
    bdst[l * 576 + e] = bvv;
  }
}

__global__ void conv_pad(const float* __restrict__ src, ushort* __restrict__ dst,
                         int NK, int padNK) {
  const int l = blockIdx.y;
  const int e = blockIdx.x * 256 + threadIdx.x;
  if (e < NK) dst[(size_t)l * padNK + e] = f2bf(src[(size_t)l * NK + e]);
}

// omega [l][64 d][128 m] -> OmT' [l][128 m][64 d] * sqrt(temp)
__global__ void conv_omt(const float* __restrict__ om, ushort* __restrict__ dst) {
  const int l = blockIdx.y;
  const int e = blockIdx.x * 256 + threadIdx.x;   // < 8192
  const int m = e >> 6, d = e & 63;
  dst[(size_t)l * 8192 + e] = f2bf(0.35355339059327379f * om[(size_t)l * 8192 + d * 128 + m]);
}

// ---------------- im2col (fp32 in -> bf16 out) ----------------
__global__ __launch_bounds__(256) void im2col_kernel(
    const float* __restrict__ X, ushort* __restrict__ Apd)
{
  const int bp = blockIdx.x;
  const int b = bp / NPATCH, p = bp - b * NPATCH;
  const int gh = p / 14, gw = p - gh * 14;
  for (int e = threadIdx.x; e < KPATCH; e += 256) {
    const int c = e >> 8, rem = e & 255, ph = rem >> 4, pw = rem & 15;
    Apd[(size_t)bp * KPATCH + e] =
        f2bf(X[((size_t)(b * 3 + c) * 224 + gh * 16 + ph) * 224 + gw * 16 + pw]);
  }
}

// ---------------- assemble tokens ----------------
__global__ __launch_bounds__(256) void assemble_kernel(
    const ushort* __restrict__ TK, const float* __restrict__ g,
    const float* __restrict__ bt, const float* __restrict__ cls,
    const float* __restrict__ pos, ushort* __restrict__ XC)
{
  const int w = threadIdx.x >> 6, lane = threadIdx.x & 63;
  const int row = blockIdx.x * 4 + w;
  const int b = row / LLEN, l = row - b * LLEN;
  float o0, o1, o2;
  if (l == 0) {
    o0 = cls[lane]; o1 = cls[lane + 64]; o2 = cls[lane + 128];
  } else {
    const ushort* tp = TK + (size_t)(b * NPATCH + l - 1) * DMODEL;
    const float x0 = bf2f(tp[lane]), x1 = bf2f(tp[lane + 64]), x2 = bf2f(tp[lane + 128]);
    const float s  = wave_reduce_sum(x0 + x1 + x2);
    const float sq = wave_reduce_sum(x0 * x0 + x1 * x1 + x2 * x2);
    const float mu = s * (1.f / 192.f);
    const float var = sq * (1.f / 192.f) - mu * mu;
    const float rs = rsqrtf(var + 1e-5f);
    o0 = (x0 - mu) * rs * g[lane]       + bt[lane];
    o1 = (x1 - mu) * rs * g[lane + 64]  + bt[lane + 64];
    o2 = (x2 - mu) * rs * g[lane + 128] + bt[lane + 128];
  }
  o0 += pos[l * DMODEL + lane];
  o1 += pos[l * DMODEL + lane + 64];
  o2 += pos[l * DMODEL + lane + 128];
  ushort* xp = XC + (size_t)row * DMODEL;
  xp[lane] = f2bf(o0); xp[lane + 64] = f2bf(o1); xp[lane + 128] = f2bf(o2);
}

// ---------------- fused pool + head (per-block pool into LDS) ----------------
__global__ __launch_bounds__(256) void head_kernel(
    const ushort* __restrict__ XC, const float* __restrict__ HW,
    const float* __restrict__ HB, float* __restrict__ OUTp)
{
  __shared__ float zsh[DMODEL];
  const int b = blockIdx.y;
  const int tid = threadIdx.x;
  const int wave = tid >> 6, lane = tid & 63;
  if (wave < 3) {
    const int d = wave * 64 + lane;
    const ushort* xp = XC + (size_t)b * LLEN * DMODEL + d;
    float s = 0.f;
#pragma unroll 4
    for (int l = 0; l < LLEN; ++l) s += bf2f(xp[(size_t)l * DMODEL]);
    zsh[d] = s * (1.f / 197.f);
  }
  __syncthreads();
  const int n = blockIdx.x * 256 + tid;
  if (n < NCLS) {
    const float* w = HW + (size_t)n * DMODEL;
    float s = HB[n];
#pragma unroll 4
    for (int d = 0; d < DMODEL; ++d) s = fmaf(zsh[d], w[d], s);
    OUTp[(size_t)b * NCLS + n] = s;
  }
}

// ---------------- host orchestration ----------------
extern "C" void kernel_launch(void* const* d_in, const int* in_sizes, int n_in,
                              void* d_out, int out_size, void* d_ws, size_t ws_size,
                              hipStream_t stream) {
  const float* x        = (const float*)d_in[0];
  const float* patch_w  = (const float*)d_in[1];
  const float* patch_b  = (const float*)d_in[2];
  const float* pe_ln_g  = (const float*)d_in[3];
  const float* pe_ln_b  = (const float*)d_in[4];
  const float* cls_tok  = (const float*)d_in[5];
  const float* pos_emb  = (const float*)d_in[6];
  const float* Wq = (const float*)d_in[7];
  const float* bq = (const float*)d_in[8];
  const float* Wk = (const float*)d_in[9];
  const float* bk = (const float*)d_in[10];
  const float* Wv = (const float*)d_in[11];
  const float* bv = (const float*)d_in[12];
  const float* Wo = (const float*)d_in[13];
  const float* bo = (const float*)d_in[14];
  const float* ln1_g = (const float*)d_in[15];
  const float* ln1_b = (const float*)d_in[16];
  const float* ln2_g = (const float*)d_in[17];
  const float* ln2_b = (const float*)d_in[18];
  const float* lnb_g = (const float*)d_in[19];
  const float* lnb_b = (const float*)d_in[20];
  const float* W1 = (const float*)d_in[21];
  const float* b1 = (const float*)d_in[22];
  const float* W2 = (const float*)d_in[23];
  const float* b2 = (const float*)d_in[24];
  const float* omega  = (const float*)d_in[25];
  const float* head_w = (const float*)d_in[26];
  const float* head_b = (const float*)d_in[27];
  float* out = (float*)d_out;
  char* wsb = (char*)d_ws;

  size_t off = 0;
  auto carve = [&](size_t bytes) { size_t o = off; off += (bytes + 255) & ~(size_t)255; return o; };
  ushort* xc     = (ushort*)(wsb + carve((size_t)MPAD * 192 * 2));
  ushort* qkv    = (ushort*)(wsb + carve((size_t)MPAD * 576 * 2));
  ushort* ab     = (ushort*)(wsb + carve((size_t)MPAD * 192 * 2));
  ushort* hidden = (ushort*)(wsb + carve((size_t)MPAD * 768 * 2));   // aliases im2col
  ushort* KVt    = (ushort*)(wsb + carve((size_t)192 * 80 * 256 * 2));
  ushort* Vt     = (ushort*)(wsb + carve((size_t)192 * 64 * VLT * 2 + 1024)); // +pad for swz overrun
  float*  bqkv   = (float*)(wsb + carve((size_t)12 * 576 * 4));
  ushort* Wqkv_bf = (ushort*)(wsb + carve((size_t)12 * 640 * 192 * 2));
  ushort* Wo_bf   = (ushort*)(wsb + carve((size_t)12 * 256 * 192 * 2));
  ushort* W1_bf   = (ushort*)(wsb + carve((size_t)12 * 768 * 192 * 2));
  ushort* W2_bf   = (ushort*)(wsb + carve((size_t)12 * 256 * 768 * 2));
  ushort* Wp_bf   = (ushort*)(wsb + carve((size_t)256 * 768 * 2));
  ushort* Om_bf   = (ushort*)(wsb + carve((size_t)12 * 128 * 64 * 2));
  ushort* i2c     = hidden;   // patch GEMM consumes before FF uses hidden

  // ---- zero Vt (pad cols l in [197,208) + swz-overrun tail must be finite 0) ----
  {
    const int n16 = (int)(((size_t)192 * 64 * VLT * 2 + 1024) / 16);
    zero_buf<<<(n16 + 255) / 256, 256, 0, stream>>>((uint4*)Vt, n16);
  }

  // ---- pre-conversion ----
  conv_qkv<<<dim3(432, 12), 256, 0, stream>>>(Wq, Wk, Wv, bq, bk, bv, Wqkv_bf, bqkv);
  conv_pad<<<dim3(144, 12), 256, 0, stream>>>(Wo, Wo_bf, 36864, 256 * 192);
  conv_pad<<<dim3(576, 12), 256, 0, stream>>>(W1, W1_bf, 147456, 768 * 192);
  conv_pad<<<dim3(576, 12), 256, 0, stream>>>(W2, W2_bf, 147456, 256 * 768);
  conv_pad<<<dim3(576, 1), 256, 0, stream>>>(patch_w, Wp_bf, 147456, 256 * 768);
  conv_omt<<<dim3(32, 12), 256, 0, stream>>>(omega, Om_bf);

  // ---- patch embedding ----
  im2col_kernel<<<BPROWS, 256, 0, stream>>>(x, i2c);
  gemm_bf2<<<dim3(98, 3), 256, 0, stream>>>(i2c, KPATCH, Wp_bf, KPATCH,
      patch_b, ab, DMODEL, nullptr, KPATCH, MODE_PLAIN);
  assemble_kernel<<<BLROWS / 4, 256, 0, stream>>>(ab, pe_ln_g, pe_ln_b,
                                                  cls_tok, pos_emb, xc);

  const int exits[3] = {3, 7, 11};
  for (int i = 0; i < NDEPTH; ++i) {
    // QKV: 128x64 tiles, N=576 -> 9 N-tiles, 891 blocks; V -> Vt
    gemm_bf2<<<dim3(99, 9), 256, 0, stream>>>(xc, DMODEL,
        Wqkv_bf + (size_t)i * 640 * 192, DMODEL, bqkv + i * 576,
        qkv, 576, Vt, DMODEL, MODE_QKV);
    // fused FAVOR-K + KV (V pre-transposed)
    kv_fused<<<dim3(192, 2), 256, 0, stream>>>(qkv,
        Om_bf + (size_t)i * 8192, Vt, KVt);
    // fused FAVOR-Q + attn (64-row tiles, 768 blocks)
    attn_fused<<<dim3(4, 192), 256, 0, stream>>>(qkv,
        Om_bf + (size_t)i * 8192, KVt, ab);
    // O-proj + bias + residual + LN1, fused (16-row tiles, 792 blocks)
    gemm_ln<<<MPAD / 16, 256, 0, stream>>>(ab, DMODEL,
        Wo_bf + (size_t)i * 256 * 192, DMODEL, bo + i * DMODEL, xc,
        ln1_g + i * DMODEL, ln1_b + i * DMODEL, nullptr, nullptr,
        DMODEL, 0);
    // W1: 128x64 tiles, N=768 -> 12 N-tiles, 1188 blocks
    gemm_bf2<<<dim3(99, 12), 256, 0, stream>>>(xc, DMODEL,
        W1_bf + (size_t)i * 768 * 192, DMODEL, b1 + i * FFDIM,
        hidden, FFDIM, nullptr, DMODEL, MODE_RELU);
    // W2 + bias + residual + LN2 + LNb, fused (16-row tiles, 792 blocks)
    gemm_ln<<<MPAD / 16, 256, 0, stream>>>(hidden, FFDIM,
        W2_bf + (size_t)i * 256 * 768, FFDIM, b2 + i * DMODEL, xc,
        ln2_g + i * DMODEL, ln2_b + i * DMODEL,
        lnb_g + i * DMODEL, lnb_b + i * DMODEL,
        FFDIM, 1);

    for (int j = 0; j < 3; ++j) {
      if (i == exits[j]) {
        head_kernel<<<dim3(4, BB), 256, 0, stream>>>(
            xc, head_w + (size_t)j * NCLS * DMODEL, head_b + (size_t)j * NCLS,
            out + (size_t)j * BB * NCLS);
      }
    }
  }
}

// Round 7
// 1481.067 us; speedup vs baseline: 1.1462x; 1.1462x over previous
//
#include <hip/hip_runtime.h>
#include <math.h>

// ---------------- problem constants ----------------
#define BB     64
#define LLEN   197
#define BLROWS 12608      // BB*LLEN
#define MPAD   12672      // BLROWS padded to 99*128 (= 792*16)
#define DMODEL 192
#define NHEAD  3
#define DHEAD  64
#define M2FEAT 256
#define FFDIM  768
#define NDEPTH 12
#define NCLS   1000
#define NPATCH 196
#define BPROWS 12544      // BB*NPATCH (= 98*128 exactly)
#define KPATCH 768
#define PHIRS  264        // Phi LDS row stride (256 + 8 pad, 16B-aligned)
#define PHTRS  40         // PhT LDS row stride (32 + 8 pad, 16B-aligned)
#define VLT    208        // Vt row length (197 padded, 16B-aligned)

#define MODE_PLAIN 0
#define MODE_RELU  1
#define MODE_QKV   2      // cols<384 -> qkv; cols>=384 -> transposed Vt

typedef unsigned short ushort;
typedef __attribute__((ext_vector_type(8))) short bf16x8;
typedef __attribute__((ext_vector_type(4))) float floatx4;
typedef __attribute__((ext_vector_type(4))) short short4v;

__device__ __forceinline__ float wave_reduce_sum(float v) {
#pragma unroll
  for (int s = 32; s > 0; s >>= 1) v += __shfl_xor(v, s, 64);
  return v;
}
__device__ __forceinline__ ushort f2bf(float f) {  // RNE fp32->bf16
  unsigned u = __float_as_uint(f);
  return (ushort)((u + 0x7fffu + ((u >> 16) & 1u)) >> 16);
}
__device__ __forceinline__ float bf2f(ushort u) {
  return __uint_as_float(((unsigned)u) << 16);
}
// async global->LDS, 16 B per lane; LDS dest wave-uniform (HW adds lane*16);
// global src is PER-LANE -> swizzled LDS layouts via pre-swizzled src (T2).
__device__ __forceinline__ void gll16(const ushort* g, ushort* l) {
  __builtin_amdgcn_global_load_lds(
      (const __attribute__((address_space(1))) void*)g,
      (__attribute__((address_space(3))) void*)l, 16, 0, 0);
}

__global__ void zero_buf(uint4* __restrict__ p, int n16) {
  const int i = blockIdx.x * 256 + threadIdx.x;
  if (i < n16) p[i] = uint4{0, 0, 0, 0};
}

// ====== bf16 GEMM, 128x64 tile, BK=64, dbuf LDS, swz8 (all wide GEMMs) ======
// block 256 = 4 waves (2x2 of 64x32), 48 KB LDS -> 3 blocks/CU for drain
// overlap. bias (+relu) out. MODE_QKV: cols<384 -> qkv; [384,576) -> Vt[bh][d][l].
// (round-5 verified version; W-in-regs variant regressed: uncoalesced 384B-
//  strided per-lane loads — keep W staged via coalesced gll16.)
__global__ __launch_bounds__(256) void gemm_bf2(
    const ushort* __restrict__ A, int lda,
    const ushort* __restrict__ W, int ldw,
    const float* __restrict__ bias,
    ushort* __restrict__ C, int ldc, ushort* __restrict__ Vt,
    int Kdim, int mode)
{
  __shared__ __align__(16) ushort As[2][128 * 64];   // 32 KB
  __shared__ __align__(16) ushort Ws[2][64 * 64];    // 16 KB
  const int tid = threadIdx.x;
  const int bm = blockIdx.x, bn = blockIdx.y;
  const int wave = tid >> 6, lane = tid & 63;
  const int wm = (wave >> 1) * 64, wn = (wave & 1) * 32;
  const int quad = lane >> 4, l16 = lane & 15;
  const int srow = lane >> 3;                 // 0..7 within an 8-row stage call
  const int scol = ((lane & 7) ^ srow) * 8;   // swizzled source col group
  const ushort* Ap = A + (size_t)(bm * 128) * lda;
  const ushort* Wp = W + (size_t)(bn * 64) * ldw;
  floatx4 acc[4][2] = {};
  const int nT = Kdim >> 6;
#pragma unroll
  for (int t = 0; t < 4; ++t) {
    const int rb = (t * 4 + wave) * 8;
    gll16(Ap + (size_t)(rb + srow) * lda + scol, &As[0][rb * 64]);
  }
#pragma unroll
  for (int t = 0; t < 2; ++t) {
    const int rb = (t * 4 + wave) * 8;
    gll16(Wp + (size_t)(rb + srow) * ldw + scol, &Ws[0][rb * 64]);
  }
  for (int kt = 0; kt < nT; ++kt) {
    const int cur = kt & 1;
    __syncthreads();                 // drains prefetch(kt) (vmcnt0) + buf reuse
    if (kt + 1 < nT) {
      const int kk = (kt + 1) * 64, nxt = cur ^ 1;
#pragma unroll
      for (int t = 0; t < 4; ++t) {
        const int rb = (t * 4 + wave) * 8;
        gll16(Ap + (size_t)(rb + srow) * lda + kk + scol, &As[nxt][rb * 64]);
      }
#pragma unroll
      for (int t = 0; t < 2; ++t) {
        const int rb = (t * 4 + wave) * 8;
        gll16(Wp + (size_t)(rb + srow) * ldw + kk + scol, &Ws[nxt][rb * 64]);
      }
    }
#pragma unroll
    for (int ks = 0; ks < 2; ++ks) {
      bf16x8 af[4], bf[2];
#pragma unroll
      for (int i = 0; i < 4; ++i) {
        const int ra = wm + i * 16 + l16;
        af[i] = *(const bf16x8*)&As[cur][ra * 64 + ((((ks << 2) | quad) ^ (ra & 7)) * 8)];
      }
#pragma unroll
      for (int j = 0; j < 2; ++j) {
        const int rw = wn + j * 16 + l16;
        bf[j] = *(const bf16x8*)&Ws[cur][rw * 64 + ((((ks << 2) | quad) ^ (rw & 7)) * 8)];
      }
#pragma unroll
      for (int i = 0; i < 4; ++i)
#pragma unroll
        for (int j = 0; j < 2; ++j)
          acc[i][j] = __builtin_amdgcn_mfma_f32_16x16x32_bf16(af[i], bf[j], acc[i][j], 0, 0, 0);
    }
  }
  if (mode == MODE_QKV) {
#pragma unroll
    for (int i = 0; i < 4; ++i)
#pragma unroll
      for (int r = 0; r < 4; ++r) {
        const int grow = bm * 128 + wm + i * 16 + quad * 4 + r;
        const int bidx = grow / 197;           // magic-mul
        const int lloc = grow - bidx * 197;
#pragma unroll
        for (int j = 0; j < 2; ++j) {
          const int col = bn * 64 + wn + j * 16 + l16;
          const float o = acc[i][j][r] + bias[col];
          if (col < 384) {
            C[(size_t)grow * ldc + col] = f2bf(o);
          } else if (grow < BLROWS) {
            const int h = (col - 384) >> 6, d = (col - 384) & 63;
            Vt[((size_t)(bidx * 3 + h) * 64 + d) * VLT + lloc] = f2bf(o);
          }
        }
      }
  } else {
#pragma unroll
    for (int j = 0; j < 2; ++j) {
      const int col = bn * 64 + wn + j * 16 + l16;
      const float bv = bias[col];
#pragma unroll
      for (int i = 0; i < 4; ++i)
#pragma unroll
        for (int r = 0; r < 4; ++r) {
          const int grow = bm * 128 + wm + i * 16 + quad * 4 + r;
          float o = acc[i][j][r] + bv;
          if (mode == MODE_RELU) o = fmaxf(o, 0.f);
          C[(size_t)grow * ldc + col] = f2bf(o);
        }
    }
  }
}

// == fused GEMM + bias + residual + LayerNorm(x1/x2), 16-row tile, W in LDS ==
// grid 792 (3.1/CU at 53 KB LDS: W dbuf 48 KB + A dbuf 4 KB). 4 waves each own
// 48 cols (3 n-tiles, acc[3]); all share the 16 A-rows. W staged via coalesced
// gll16 (round-6's W-in-regs path regressed on uncoalesced strided loads).
// Row LN = quad-shfl partial + 4-way cross-wave LDS combine. Writes XC in place.
__global__ __launch_bounds__(256) void gemm_ln(
    const ushort* __restrict__ A, int lda,
    const ushort* __restrict__ W, int ldw,
    const float* __restrict__ bias,
    ushort* __restrict__ XC,
    const float* __restrict__ ga, const float* __restrict__ ba,
    const float* __restrict__ gb, const float* __restrict__ bb,
    int Kdim, int dln)
{
  __shared__ __align__(16) ushort As[2][16 * 64];    // 4 KB
  __shared__ __align__(16) ushort Ws[2][192 * 64];   // 48 KB
  __shared__ float p1s[4][16], p1q[4][16], p2s[4][16], p2q[4][16];
  const int tid = threadIdx.x;
  const int bm = blockIdx.x;
  const int wave = tid >> 6, lane = tid & 63;
  const int quad = lane >> 4, l16 = lane & 15;
  const int srow = lane >> 3;
  const int scol = ((lane & 7) ^ srow) * 8;
  const ushort* Ap = A + (size_t)(bm * 16) * lda;
  floatx4 acc[3] = {};
  const int nT = Kdim >> 6;
  if (wave < 2) gll16(Ap + (size_t)(wave * 8 + srow) * lda + scol, &As[0][wave * 8 * 64]);
#pragma unroll
  for (int t = 0; t < 6; ++t) {
    const int rb = (t * 4 + wave) * 8;
    gll16(W + (size_t)(rb + srow) * ldw + scol, &Ws[0][rb * 64]);
  }
  for (int kt = 0; kt < nT; ++kt) {
    const int cur = kt & 1;
    __syncthreads();                 // drains prefetch(kt) + buf reuse
    if (kt + 1 < nT) {
      const int kk = (kt + 1) * 64, nxt = cur ^ 1;
      if (wave < 2)
        gll16(Ap + (size_t)(wave * 8 + srow) * lda + kk + scol, &As[nxt][wave * 8 * 64]);
#pragma unroll
      for (int t = 0; t < 6; ++t) {
        const int rb = (t * 4 + wave) * 8;
        gll16(W + (size_t)(rb + srow) * ldw + kk + scol, &Ws[nxt][rb * 64]);
      }
    }
#pragma unroll
    for (int ks = 0; ks < 2; ++ks) {
      const int ra = l16;
      const bf16x8 af = *(const bf16x8*)&As[cur][ra * 64 + ((((ks << 2) | quad) ^ (ra & 7)) * 8)];
#pragma unroll
      for (int j = 0; j < 3; ++j) {
        const int rw = (wave * 3 + j) * 16 + l16;
        const bf16x8 bf = *(const bf16x8*)&Ws[cur][rw * 64 + ((((ks << 2) | quad) ^ (rw & 7)) * 8)];
        acc[j] = __builtin_amdgcn_mfma_f32_16x16x32_bf16(af, bf, acc[j], 0, 0, 0);
      }
    }
  }
  // ---- epilogue: bias + residual; LN = quad shfl + 4-wave combine ----
  float xr[4][3];
#pragma unroll
  for (int r = 0; r < 4; ++r) {
    const int rloc = quad * 4 + r;
    const int row = bm * 16 + rloc;
    const ushort* xp = XC + (size_t)row * DMODEL;
    float s = 0.f, sq = 0.f;
#pragma unroll
    for (int j = 0; j < 3; ++j) {
      const int col = (wave * 3 + j) * 16 + l16;
      const float o = acc[j][r] + bias[col] + bf2f(xp[col]);
      xr[r][j] = o; s += o; sq += o * o;
    }
#pragma unroll
    for (int m = 1; m < 16; m <<= 1) {
      s += __shfl_xor(s, m, 64); sq += __shfl_xor(sq, m, 64);
    }
    if (l16 == 0) { p1s[wave][rloc] = s; p1q[wave][rloc] = sq; }
  }
  __syncthreads();
#pragma unroll
  for (int r = 0; r < 4; ++r) {
    const int rloc = quad * 4 + r;
    const float s = p1s[0][rloc] + p1s[1][rloc] + p1s[2][rloc] + p1s[3][rloc];
    const float sq = p1q[0][rloc] + p1q[1][rloc] + p1q[2][rloc] + p1q[3][rloc];
    const float mu = s * (1.f / 192.f);
    const float var = sq * (1.f / 192.f) - mu * mu;
    const float rs = rsqrtf(var + 1e-5f);
#pragma unroll
    for (int j = 0; j < 3; ++j) {
      const int col = (wave * 3 + j) * 16 + l16;
      xr[r][j] = (xr[r][j] - mu) * rs * ga[col] + ba[col];
    }
  }
  if (dln) {
#pragma unroll
    for (int r = 0; r < 4; ++r) {
      const int rloc = quad * 4 + r;
      float s = 0.f, sq = 0.f;
#pragma unroll
      for (int j = 0; j < 3; ++j) { s += xr[r][j]; sq += xr[r][j] * xr[r][j]; }
#pragma unroll
      for (int m = 1; m < 16; m <<= 1) {
        s += __shfl_xor(s, m, 64); sq += __shfl_xor(sq, m, 64);
      }
      if (l16 == 0) { p2s[wave][rloc] = s; p2q[wave][rloc] = sq; }
    }
    __syncthreads();
#pragma unroll
    for (int r = 0; r < 4; ++r) {
      const int rloc = quad * 4 + r;
      const float s = p2s[0][rloc] + p2s[1][rloc] + p2s[2][rloc] + p2s[3][rloc];
      const float sq = p2q[0][rloc] + p2q[1][rloc] + p2q[2][rloc] + p2q[3][rloc];
      const float mu = s * (1.f / 192.f);
      const float var = sq * (1.f / 192.f) - mu * mu;
      const float rs = rsqrtf(var + 1e-5f);
#pragma unroll
      for (int j = 0; j < 3; ++j) {
        const int col = (wave * 3 + j) * 16 + l16;
        xr[r][j] = (xr[r][j] - mu) * rs * gb[col] + bb[col];
      }
    }
  }
#pragma unroll
  for (int r = 0; r < 4; ++r) {
    const int row = bm * 16 + quad * 4 + r;
    ushort* xp = XC + (size_t)row * DMODEL;
#pragma unroll
    for (int j = 0; j < 3; ++j) xp[(wave * 3 + j) * 16 + l16] = f2bf(xr[r][j]);
  }
}

// =========== fused FAVOR-K + KV accumulation (V pre-transposed) ===========
// grid (192 bh, 2 mh). Per 32-token chunk: u = K*scale @ Om_half^T (MFMA),
// phi -> PhT [128 m][32 l] (pad 40); Vts staged d-major from Vt (dbuf, group-
// swizzled src); KV += PhT @ Vts. Out KVt [bh][80 d][256 f] (d=64: ksum).
__global__ __launch_bounds__(256) void kv_fused(
    const ushort* __restrict__ qkv, const ushort* __restrict__ OmT,
    const ushort* __restrict__ Vt, ushort* __restrict__ KVt)
{
  __shared__ __align__(16) ushort Ks[32 * 64];        // 4 KB (swz8)
  __shared__ __align__(16) ushort Om[64 * 64];        // 8 KB (swz8)
  __shared__ __align__(16) ushort PhT[128 * PHTRS];   // 10 KB
  __shared__ __align__(16) ushort Vts[2][64 * 32];    // 8 KB (swz4, dbuf)
  __shared__ __align__(16) ushort Vcst[16 * 32];      // 1 KB (ksum + zero rows)
  __shared__ float offs[32];
  const int tid = threadIdx.x;
  const int bh = blockIdx.x, mh = blockIdx.y;
  const int b = bh / 3, h = bh - b * 3;
  const int wave = tid >> 6, lane = tid & 63;
  const int quad = lane >> 4, l16 = lane & 15;
  const int lr8 = lane >> 3, g8 = lane & 7;
  const int lr4 = lane >> 2, g4 = lane & 3;
#pragma unroll
  for (int t = 0; t < 2; ++t) {
    const int rb = (t * 4 + wave) * 8;
    const int row = rb + lr8;
    gll16(OmT + (size_t)(mh * 64 + row) * 64 + ((g8 ^ (row & 7)) * 8), &Om[rb * 64]);
  }
  {
    const int rowK = wave * 8 + lr8;
    gll16(qkv + (size_t)(b * 197 + rowK) * 576 + 192 + h * 64 + ((g8 ^ (rowK & 7)) * 8),
          &Ks[wave * 8 * 64]);
    const int rowV = wave * 16 + lr4;
    gll16(Vt + ((size_t)bh * 64 + rowV) * VLT + ((g4 ^ (rowV & 3)) * 8),
          &Vts[0][wave * 16 * 32]);
  }
  for (int e = tid; e < 16 * 32; e += 256) Vcst[e] = (e < 32) ? 0x3F80 : 0;
  floatx4 acc[2][5] = {};
  for (int c = 0; c < 7; ++c) {
    const int l0 = c * 32;
    const int cur = c & 1;
    __syncthreads();   // staged data ready (vmcnt0)
    if (tid < 64) {
      const int row = tid >> 1, half = tid & 1;
      float s = 0.f;
#pragma unroll
      for (int t = 0; t < 4; ++t) {
        bf16x8 v8 = *(const bf16x8*)&Ks[row * 64 + (((half * 4 + t) ^ (row & 7)) * 8)];
#pragma unroll
        for (int q = 0; q < 8; ++q) { float xv = bf2f((ushort)v8[q]); s += xv * xv; }
      }
      s += __shfl_xor(s, 1, 64);
      if (half == 0) offs[row] = 0.0625f * s;   // 0.5*scale^2 (scale^2=0.125)
    }
    floatx4 ui[2] = {};
#pragma unroll
    for (int ksb = 0; ksb < 2; ++ksb) {
      bf16x8 af[2], bfm;
#pragma unroll
      for (int i = 0; i < 2; ++i) {
        const int row = i * 16 + l16;
        af[i] = *(const bf16x8*)&Ks[row * 64 + (((quad + (ksb << 2)) ^ (row & 7)) * 8)];
      }
      {
        const int row = wave * 16 + l16;
        bfm = *(const bf16x8*)&Om[row * 64 + (((quad + (ksb << 2)) ^ (row & 7)) * 8)];
      }
#pragma unroll
      for (int i = 0; i < 2; ++i)
        ui[i] = __builtin_amdgcn_mfma_f32_16x16x32_bf16(af[i], bfm, ui[i], 0, 0, 0);
    }
    __syncthreads();   // Ks/Om reads done
    {
      const int mloc = wave * 16 + l16;
#pragma unroll
      for (int i = 0; i < 2; ++i) {
#pragma unroll
        for (int r = 0; r < 4; ++r) {
          const int ll = i * 16 + quad * 4 + r;
          float ep = 0.f, em = 0.f;
          if (l0 + ll < 197) {
            const float off = offs[ll];
            const float u = ui[i][r];
            ep = __expf(u - off) * 0.0625f;
            em = __expf(-u - off) * 0.0625f;
          }
          PhT[mloc * PHTRS + ll] = f2bf(ep);
          PhT[(64 + mloc) * PHTRS + ll] = f2bf(em);
        }
      }
    }
    if (c + 1 < 7) {   // prefetch next chunk (Ks single-buf safe; Vts dbuf)
      const int rowK = wave * 8 + lr8;
      const int lK = (c + 1) * 32 + rowK;
      gll16(qkv + (size_t)(b * 197 + lK) * 576 + 192 + h * 64 + ((g8 ^ (rowK & 7)) * 8),
            &Ks[wave * 8 * 64]);
      const int rowV = wave * 16 + lr4;
      gll16(Vt + ((size_t)bh * 64 + rowV) * VLT + (c + 1) * 32 + ((g4 ^ (rowV & 3)) * 8),
            &Vts[cur ^ 1][wave * 16 * 32]);
    }
    __syncthreads();   // PhT visible (also drains prefetch; harmless)
    bf16x8 af[2], bf[5];
#pragma unroll
    for (int i = 0; i < 2; ++i)
      af[i] = *(const bf16x8*)&PhT[(wave * 32 + i * 16 + l16) * PHTRS + quad * 8];
#pragma unroll
    for (int j = 0; j < 4; ++j) {
      const int row = j * 16 + l16;
      bf[j] = *(const bf16x8*)&Vts[cur][row * 32 + ((quad ^ (row & 3)) * 8)];
    }
    bf[4] = *(const bf16x8*)&Vcst[l16 * 32 + quad * 8];
#pragma unroll
    for (int i = 0; i < 2; ++i)
#pragma unroll
      for (int j = 0; j < 5; ++j)
        acc[i][j] = __builtin_amdgcn_mfma_f32_16x16x32_bf16(af[i], bf[j], acc[i][j], 0, 0, 0);
  }
#pragma unroll
  for (int i = 0; i < 2; ++i) {
    const int prow0 = wave * 32 + i * 16 + quad * 4;
    const int f0 = (prow0 < 64) ? (mh * 64 + prow0) : (128 + mh * 64 + prow0 - 64);
#pragma unroll
    for (int j = 0; j < 5; ++j) {
      const int d = j * 16 + l16;
      short4v pk;
#pragma unroll
      for (int r = 0; r < 4; ++r) pk[r] = (short)f2bf(acc[i][j][r]);
      *(short4v*)(KVt + ((size_t)bh * 80 + d) * 256 + f0) = pk;
    }
  }
}

// =========== fused FAVOR-Q + attn: out = Z * (phiQ @ KVt^T) ===========
// grid (4 l-tiles of 64, 192 bh) -> 768 blocks = 3/CU for barrier overlap.
__global__ __launch_bounds__(256) void attn_fused(
    const ushort* __restrict__ qkv, const ushort* __restrict__ OmT,
    const ushort* __restrict__ KVt, ushort* __restrict__ OUT)
{
  __shared__ __align__(16) ushort Phi[64 * PHIRS];   // 33 KB; [0:8K)=Qs, [8K:24K)=Om
  __shared__ __align__(16) ushort Bs[2][80 * 32];    // 10 KB (swz4)
  __shared__ float offs[64];
  __shared__ float zs[64];
  ushort* Qs = Phi;                 // 64 x 64 (swz8)
  ushort* Om = Phi + 64 * 64;       // 128 x 64 (swz8)
  const int tid = threadIdx.x;
  const int bx = blockIdx.x, bh = blockIdx.y;
  const int b = bh / 3, h = bh - b * 3;
  const int wave = tid >> 6, lane = tid & 63;
  const int quad = lane >> 4, l16 = lane & 15;
  const int lr8 = lane >> 3, g8 = lane & 7;
  const int lr4 = lane >> 2, g4 = lane & 3;
#pragma unroll
  for (int t = 0; t < 2; ++t) {
    const int rb = wave * 16 + t * 8;
    const int row = rb + lr8;
    const int l = bx * 64 + row;
    gll16(qkv + (size_t)(b * 197 + l) * 576 + h * 64 + ((g8 ^ (row & 7)) * 8), &Qs[rb * 64]);
  }
#pragma unroll
  for (int t = 0; t < 4; ++t) {
    const int rb = wave * 32 + t * 8;
    const int row = rb + lr8;
    gll16(OmT + (size_t)row * 64 + ((g8 ^ (row & 7)) * 8), &Om[rb * 64]);
  }
  __syncthreads();
  if (tid < 128) {
    const int row = tid >> 1, half = tid & 1;
    float s = 0.f;
#pragma unroll
    for (int t = 0; t < 4; ++t) {
      bf16x8 v8 = *(const bf16x8*)&Qs[row * 64 + (((half * 4 + t) ^ (row & 7)) * 8)];
#pragma unroll
      for (int q = 0; q < 8; ++q) { float xv = bf2f((ushort)v8[q]); s += xv * xv; }
    }
    s += __shfl_xor(s, 1, 64);
    if (half == 0) offs[row] = 0.0625f * s;
  }
  floatx4 uacc[8] = {};
#pragma unroll
  for (int ksb = 0; ksb < 2; ++ksb) {
    bf16x8 af, bf[8];
    {
      const int row = wave * 16 + l16;
      af = *(const bf16x8*)&Qs[row * 64 + (((quad + (ksb << 2)) ^ (row & 7)) * 8)];
    }
#pragma unroll
    for (int j = 0; j < 8; ++j) {
      const int row = j * 16 + l16;
      bf[j] = *(const bf16x8*)&Om[row * 64 + (((quad + (ksb << 2)) ^ (row & 7)) * 8)];
    }
#pragma unroll
    for (int j = 0; j < 8; ++j)
      uacc[j] = __builtin_amdgcn_mfma_f32_16x16x32_bf16(af, bf[j], uacc[j], 0, 0, 0);
  }
  __syncthreads();   // Qs/Om reads done -> Phi overwrite legal
#pragma unroll
  for (int r = 0; r < 4; ++r) {
    const int l = wave * 16 + quad * 4 + r;
    const float off = offs[l];
#pragma unroll
    for (int j = 0; j < 8; ++j) {
      const int m = j * 16 + l16;
      const float u = uacc[j][r];
      Phi[l * PHIRS + m]       = f2bf(__expf(u - off)  * 0.0625f);
      Phi[l * PHIRS + m + 128] = f2bf(__expf(-u - off) * 0.0625f);
    }
  }
  const ushort* Bp = KVt + (size_t)bh * 80 * 256;
  {
    const int row = wave * 16 + lr4;
    gll16(Bp + (size_t)row * 256 + ((g4 ^ (row & 3)) * 8), &Bs[0][wave * 16 * 32]);
    if (wave == 0)
      gll16(Bp + (size_t)(64 + lr4) * 256 + ((g4 ^ (lr4 & 3)) * 8), &Bs[0][64 * 32]);
  }
  floatx4 acc[5] = {};
  for (int c = 0; c < 8; ++c) {
    const int cur = c & 1;
    __syncthreads();   // Phi visible (c=0) + Bs staging drained + dbuf guard
    if (c + 1 < 8) {
      const int m0 = (c + 1) * 32, nxt = cur ^ 1;
      const int row = wave * 16 + lr4;
      gll16(Bp + (size_t)row * 256 + m0 + ((g4 ^ (row & 3)) * 8), &Bs[nxt][wave * 16 * 32]);
      if (wave == 0)
        gll16(Bp + (size_t)(64 + lr4) * 256 + m0 + ((g4 ^ (lr4 & 3)) * 8), &Bs[nxt][64 * 32]);
    }
    const int m0 = c * 32;
    bf16x8 af, bf[5];
    af = *(const bf16x8*)&Phi[(wave * 16 + l16) * PHIRS + m0 + quad * 8];
#pragma unroll
    for (int j = 0; j < 5; ++j) {
      const int row = j * 16 + l16;
      bf[j] = *(const bf16x8*)&Bs[cur][row * 32 + ((quad ^ (row & 3)) * 8)];
    }
#pragma unroll
    for (int j = 0; j < 5; ++j)
      acc[j] = __builtin_amdgcn_mfma_f32_16x16x32_bf16(af, bf[j], acc[j], 0, 0, 0);
  }
  if (l16 == 0) {
#pragma unroll
    for (int r = 0; r < 4; ++r)
      zs[wave * 16 + quad * 4 + r] = acc[4][r];
  }
  __syncthreads();
#pragma unroll
  for (int r = 0; r < 4; ++r) {
    const int ll = wave * 16 + quad * 4 + r;
    const int l = bx * 64 + ll;
    if (l >= 197) continue;
    const float z = 1.f / (zs[ll] + 1e-6f);
#pragma unroll
    for (int j = 0; j < 4; ++j)
      OUT[(size_t)(b * 197 + l) * 192 + h * 64 + j * 16 + l16] =
          f2bf(acc[j][r] * z);
  }
}

// ---------------- weight pre-conversion ----------------
__global__ void conv_qkv(const float* __restrict__ Wq, const float* __restrict__ Wk,
                         const float* __restrict__ Wv, const float* __restrict__ bq,
                         const float* __restrict__ bk, const float* __restrict__ bv,
                         ushort* __restrict__ dst, float* __restrict__ bdst) {
  const int l = blockIdx.y;
  const int e = blockIdx.x * 256 + threadIdx.x;   // < 576*192
  const int n = e / 192, k = e - n * 192;
  const float* src;
  if (n < 192)      src = Wq + (size_t)l * 36864 + n * 192;
  else if (n < 384) src = Wk + (size_t)l * 36864 + (n - 192) * 192;
  else              src = Wv + (size_t)l * 36864 + (n - 384) * 192;
  dst[(size_t)l * 640 * 192 + e] = f2bf(src[k]);
  if (e < 576) {
    float bvv;
    if (e < 192)      bvv = bq[l * 192 + e];
    else if (e < 384) bvv = bk[l * 192 + e - 192];
    else              bvv = bv[l * 192 + e - 384];
    bdst[l * 576 + e] = bvv;
  }
}

__global__ void conv_pad(const float* __restrict__ src, ushort* __restrict__ dst,
                         int NK, int padNK) {
  const int l = blockIdx.y;
  const int e = blockIdx.x * 256 + threadIdx.x;
  if (e < NK) dst[(size_t)l * padNK + e] = f2bf(src[(size_t)l * NK + e]);
}

// omega [l][64 d][128 m] -> OmT' [l][128 m][64 d] * sqrt(temp)
__global__ void conv_omt(const float* __restrict__ om, ushort* __restrict__ dst) {
  const int l = blockIdx.y;
  const int e = blockIdx.x * 256 + threadIdx.x;   // < 8192
  const int m = e >> 6, d = e & 63;
  dst[(size_t)l * 8192 + e] = f2bf(0.35355339059327379f * om[(size_t)l * 8192 + d * 128 + m]);
}

// ---------------- im2col (fp32 in -> bf16 out) ----------------
__global__ __launch_bounds__(256) void im2col_kernel(
    const float* __restrict__ X, ushort* __restrict__ Apd)
{
  const int bp = blockIdx.x;
  const int b = bp / NPATCH, p = bp - b * NPATCH;
  const int gh = p / 14, gw = p - gh * 14;
  for (int e = threadIdx.x; e < KPATCH; e += 256) {
    const int c = e >> 8, rem = e & 255, ph = rem >> 4, pw = rem & 15;
    Apd[(size_t)bp * KPATCH + e] =
        f2bf(X[((size_t)(b * 3 + c) * 224 + gh * 16 + ph) * 224 + gw * 16 + pw]);
  }
}

// ---------------- assemble tokens ----------------
__global__ __launch_bounds__(256) void assemble_kernel(
    const ushort* __restrict__ TK, const float* __restrict__ g,
    const float* __restrict__ bt, const float* __restrict__ cls,
    const float* __restrict__ pos, ushort* __restrict__ XC)
{
  const int w = threadIdx.x >> 6, lane = threadIdx.x & 63;
  const int row = blockIdx.x * 4 + w;
  const int b = row / LLEN, l = row - b * LLEN;
  float o0, o1, o2;
  if (l == 0) {
    o0 = cls[lane]; o1 = cls[lane + 64]; o2 = cls[lane + 128];
  } else {
    const ushort* tp = TK + (size_t)(b * NPATCH + l - 1) * DMODEL;
    const float x0 = bf2f(tp[lane]), x1 = bf2f(tp[lane + 64]), x2 = bf2f(tp[lane + 128]);
    const float s  = wave_reduce_sum(x0 + x1 + x2);
    const float sq = wave_reduce_sum(x0 * x0 + x1 * x1 + x2 * x2);
    const float mu = s * (1.f / 192.f);
    const float var = sq * (1.f / 192.f) - mu * mu;
    const float rs = rsqrtf(var + 1e-5f);
    o0 = (x0 - mu) * rs * g[lane]       + bt[lane];
    o1 = (x1 - mu) * rs * g[lane + 64]  + bt[lane + 64];
    o2 = (x2 - mu) * rs * g[lane + 128] + bt[lane + 128];
  }
  o0 += pos[l * DMODEL + lane];
  o1 += pos[l * DMODEL + lane + 64];
  o2 += pos[l * DMODEL + lane + 128];
  ushort* xp = XC + (size_t)row * DMODEL;
  xp[lane] = f2bf(o0); xp[lane + 64] = f2bf(o1); xp[lane + 128] = f2bf(o2);
}

// ---------------- fused pool + head (per-block pool into LDS) ----------------
__global__ __launch_bounds__(256) void head_kernel(
    const ushort* __restrict__ XC, const float* __restrict__ HW,
    const float* __restrict__ HB, float* __restrict__ OUTp)
{
  __shared__ float zsh[DMODEL];
  const int b = blockIdx.y;
  const int tid = threadIdx.x;
  const int wave = tid >> 6, lane = tid & 63;
  if (wave < 3) {
    const int d = wave * 64 + lane;
    const ushort* xp = XC + (size_t)b * LLEN * DMODEL + d;
    float s = 0.f;
#pragma unroll 4
    for (int l = 0; l < LLEN; ++l) s += bf2f(xp[(size_t)l * DMODEL]);
    zsh[d] = s * (1.f / 197.f);
  }
  __syncthreads();
  const int n = blockIdx.x * 256 + tid;
  if (n < NCLS) {
    const float* w = HW + (size_t)n * DMODEL;
    float s = HB[n];
#pragma unroll 4
    for (int d = 0; d < DMODEL; ++d) s = fmaf(zsh[d], w[d], s);
    OUTp[(size_t)b * NCLS + n] = s;
  }
}

// ---------------- host orchestration ----------------
extern "C" void kernel_launch(void* const* d_in, const int* in_sizes, int n_in,
                              void* d_out, int out_size, void* d_ws, size_t ws_size,
                              hipStream_t stream) {
  const float* x        = (const float*)d_in[0];
  const float* patch_w  = (const float*)d_in[1];
  const float* patch_b  = (const float*)d_in[2];
  const float* pe_ln_g  = (const float*)d_in[3];
  const float* pe_ln_b  = (const float*)d_in[4];
  const float* cls_tok  = (const float*)d_in[5];
  const float* pos_emb  = (const float*)d_in[6];
  const float* Wq = (const float*)d_in[7];
  const float* bq = (const float*)d_in[8];
  const float* Wk = (const float*)d_in[9];
  const float* bk = (const float*)d_in[10];
  const float* Wv = (const float*)d_in[11];
  const float* bv = (const float*)d_in[12];
  const float* Wo = (const float*)d_in[13];
  const float* bo = (const float*)d_in[14];
  const float* ln1_g = (const float*)d_in[15];
  const float* ln1_b = (const float*)d_in[16];
  const float* ln2_g = (const float*)d_in[17];
  const float* ln2_b = (const float*)d_in[18];
  const float* lnb_g = (const float*)d_in[19];
  const float* lnb_b = (const float*)d_in[20];
  const float* W1 = (const float*)d_in[21];
  const float* b1 = (const float*)d_in[22];
  const float* W2 = (const float*)d_in[23];
  const float* b2 = (const float*)d_in[24];
  const float* omega  = (const float*)d_in[25];
  const float* head_w = (const float*)d_in[26];
  const float* head_b = (const float*)d_in[27];
  float* out = (float*)d_out;
  char* wsb = (char*)d_ws;

  size_t off = 0;
  auto carve = [&](size_t bytes) { size_t o = off; off += (bytes + 255) & ~(size_t)255; return o; };
  ushort* xc     = (ushort*)(wsb + carve((size_t)MPAD * 192 * 2));
  ushort* qkv    = (ushort*)(wsb + carve((size_t)MPAD * 576 * 2));
  ushort* ab     = (ushort*)(wsb + carve((size_t)MPAD * 192 * 2));
  ushort* hidden = (ushort*)(wsb + carve((size_t)MPAD * 768 * 2));   // aliases im2col
  ushort* KVt    = (ushort*)(wsb + carve((size_t)192 * 80 * 256 * 2));
  ushort* Vt     = (ushort*)(wsb + carve((size_t)192 * 64 * VLT * 2 + 1024)); // +pad for swz overrun
  float*  bqkv   = (float*)(wsb + carve((size_t)12 * 576 * 4));
  ushort* Wqkv_bf = (ushort*)(wsb + carve((size_t)12 * 640 * 192 * 2));
  ushort* Wo_bf   = (ushort*)(wsb + carve((size_t)12 * 256 * 192 * 2));
  ushort* W1_bf   = (ushort*)(wsb + carve((size_t)12 * 768 * 192 * 2));
  ushort* W2_bf   = (ushort*)(wsb + carve((size_t)12 * 256 * 768 * 2));
  ushort* Wp_bf   = (ushort*)(wsb + carve((size_t)256 * 768 * 2));
  ushort* Om_bf   = (ushort*)(wsb + carve((size_t)12 * 128 * 64 * 2));
  ushort* i2c     = hidden;   // patch GEMM consumes before FF uses hidden

  // ---- zero Vt (pad cols l in [197,208) + swz-overrun tail must be finite 0) ----
  {
    const int n16 = (int)(((size_t)192 * 64 * VLT * 2 + 1024) / 16);
    zero_buf<<<(n16 + 255) / 256, 256, 0, stream>>>((uint4*)Vt, n16);
  }

  // ---- pre-conversion ----
  conv_qkv<<<dim3(432, 12), 256, 0, stream>>>(Wq, Wk, Wv, bq, bk, bv, Wqkv_bf, bqkv);
  conv_pad<<<dim3(144, 12), 256, 0, stream>>>(Wo, Wo_bf, 36864, 256 * 192);
  conv_pad<<<dim3(576, 12), 256, 0, stream>>>(W1, W1_bf, 147456, 768 * 192);
  conv_pad<<<dim3(576, 12), 256, 0, stream>>>(W2, W2_bf, 147456, 256 * 768);
  conv_pad<<<dim3(576, 1), 256, 0, stream>>>(patch_w, Wp_bf, 147456, 256 * 768);
  conv_omt<<<dim3(32, 12), 256, 0, stream>>>(omega, Om_bf);

  // ---- patch embedding ----
  im2col_kernel<<<BPROWS, 256, 0, stream>>>(x, i2c);
  gemm_bf2<<<dim3(98, 3), 256, 0, stream>>>(i2c, KPATCH, Wp_bf, KPATCH,
      patch_b, ab, DMODEL, nullptr, KPATCH, MODE_PLAIN);
  assemble_kernel<<<BLROWS / 4, 256, 0, stream>>>(ab, pe_ln_g, pe_ln_b,
                                                  cls_tok, pos_emb, xc);

  const int exits[3] = {3, 7, 11};
  for (int i = 0; i < NDEPTH; ++i) {
    // QKV: 128x64 tiles, N=576 -> 9 N-tiles, 891 blocks; V -> Vt
    gemm_bf2<<<dim3(99, 9), 256, 0, stream>>>(xc, DMODEL,
        Wqkv_bf + (size_t)i * 640 * 192, DMODEL, bqkv + i * 576,
        qkv, 576, Vt, DMODEL, MODE_QKV);
    // fused FAVOR-K + KV (V pre-transposed)
    kv_fused<<<dim3(192, 2), 256, 0, stream>>>(qkv,
        Om_bf + (size_t)i * 8192, Vt, KVt);
    // fused FAVOR-Q + attn (64-row tiles, 768 blocks)
    attn_fused<<<dim3(4, 192), 256, 0, stream>>>(qkv,
        Om_bf + (size_t)i * 8192, KVt, ab);
    // O-proj + bias + residual + LN1, fused (16-row tiles, 792 blocks, W-LDS)
    gemm_ln<<<MPAD / 16, 256, 0, stream>>>(ab, DMODEL,
        Wo_bf + (size_t)i * 256 * 192, DMODEL, bo + i * DMODEL, xc,
        ln1_g + i * DMODEL, ln1_b + i * DMODEL, nullptr, nullptr,
        DMODEL, 0);
    // W1: 128x64 tiles, N=768 -> 12 N-tiles, 1188 blocks
    gemm_bf2<<<dim3(99, 12), 256, 0, stream>>>(xc, DMODEL,
        W1_bf + (size_t)i * 768 * 192, DMODEL, b1 + i * FFDIM,
        hidden, FFDIM, nullptr, DMODEL, MODE_RELU);
    // W2 + bias + residual + LN2 + LNb, fused (16-row tiles, 792 blocks, W-LDS)
    gemm_ln<<<MPAD / 16, 256, 0, stream>>>(hidden, FFDIM,
        W2_bf + (size_t)i * 256 * 768, FFDIM, b2 + i * DMODEL, xc,
        ln2_g + i * DMODEL, ln2_b + i * DMODEL,
        lnb_g + i * DMODEL, lnb_b + i * DMODEL,
        FFDIM, 1);

    for (int j = 0; j < 3; ++j) {
      if (i == exits[j]) {
        head_kernel<<<dim3(4, BB), 256, 0, stream>>>(
            xc, head_w + (size_t)j * NCLS * DMODEL, head_b + (size_t)j * NCLS,
            out + (size_t)j * BB * NCLS);
      }
    }
  }
}

// Round 8
// 1414.267 us; speedup vs baseline: 1.2004x; 1.0472x over previous
//
#include <hip/hip_runtime.h>
#include <math.h>

// ---------------- problem constants ----------------
#define BB     64
#define LLEN   197
#define BLROWS 12608      // BB*LLEN
#define MPAD   12672      // BLROWS padded to 99*128 (= 396*32)
#define DMODEL 192
#define NHEAD  3
#define DHEAD  64
#define M2FEAT 256
#define FFDIM  768
#define NDEPTH 12
#define NCLS   1000
#define NPATCH 196
#define BPROWS 12544      // BB*NPATCH (= 98*128 exactly)
#define KPATCH 768
#define PHIRS  264        // Phi LDS row stride (256 + 8 pad, 16B-aligned)
#define PHTRS  40         // PhT LDS row stride (32 + 8 pad, 16B-aligned)
#define VLT    208        // Vt row length (197 padded, 16B-aligned)

#define MODE_PLAIN 0
#define MODE_RELU  1
#define MODE_QKV   2      // cols<384 -> qkv; cols>=384 -> transposed Vt

typedef unsigned short ushort;
typedef __attribute__((ext_vector_type(8))) short bf16x8;
typedef __attribute__((ext_vector_type(4))) float floatx4;
typedef __attribute__((ext_vector_type(4))) short short4v;

__device__ __forceinline__ float wave_reduce_sum(float v) {
#pragma unroll
  for (int s = 32; s > 0; s >>= 1) v += __shfl_xor(v, s, 64);
  return v;
}
__device__ __forceinline__ ushort f2bf(float f) {  // RNE fp32->bf16
  unsigned u = __float_as_uint(f);
  return (ushort)((u + 0x7fffu + ((u >> 16) & 1u)) >> 16);
}
__device__ __forceinline__ float bf2f(ushort u) {
  return __uint_as_float(((unsigned)u) << 16);
}
// async global->LDS, 16 B per lane; LDS dest wave-uniform (HW adds lane*16);
// global src is PER-LANE -> swizzled LDS layouts via pre-swizzled src (T2).
__device__ __forceinline__ void gll16(const ushort* g, ushort* l) {
  __builtin_amdgcn_global_load_lds(
      (const __attribute__((address_space(1))) void*)g,
      (__attribute__((address_space(3))) void*)l, 16, 0, 0);
}

__global__ void zero_buf(uint4* __restrict__ p, int n16) {
  const int i = blockIdx.x * 256 + threadIdx.x;
  if (i < n16) p[i] = uint4{0, 0, 0, 0};
}

// ====== bf16 GEMM, 128x64 tile, BK=64, dbuf LDS, swz8 (all wide GEMMs) ======
// block 256 = 4 waves (2x2 of 64x32), 48 KB LDS -> 3 blocks/CU for drain
// overlap. bias (+relu) out. MODE_QKV: cols<384 -> qkv; [384,576) -> Vt[bh][d][l].
// (round-5 verified version; W-in-regs variant regressed: uncoalesced 384B-
//  strided per-lane loads — keep W staged via coalesced gll16.)
__global__ __launch_bounds__(256) void gemm_bf2(
    const ushort* __restrict__ A, int lda,
    const ushort* __restrict__ W, int ldw,
    const float* __restrict__ bias,
    ushort* __restrict__ C, int ldc, ushort* __restrict__ Vt,
    int Kdim, int mode)
{
  __shared__ __align__(16) ushort As[2][128 * 64];   // 32 KB
  __shared__ __align__(16) ushort Ws[2][64 * 64];    // 16 KB
  const int tid = threadIdx.x;
  const int bm = blockIdx.x, bn = blockIdx.y;
  const int wave = tid >> 6, lane = tid & 63;
  const int wm = (wave >> 1) * 64, wn = (wave & 1) * 32;
  const int quad = lane >> 4, l16 = lane & 15;
  const int srow = lane >> 3;                 // 0..7 within an 8-row stage call
  const int scol = ((lane & 7) ^ srow) * 8;   // swizzled source col group
  const ushort* Ap = A + (size_t)(bm * 128) * lda;
  const ushort* Wp = W + (size_t)(bn * 64) * ldw;
  floatx4 acc[4][2] = {};
  const int nT = Kdim >> 6;
#pragma unroll
  for (int t = 0; t < 4; ++t) {
    const int rb = (t * 4 + wave) * 8;
    gll16(Ap + (size_t)(rb + srow) * lda + scol, &As[0][rb * 64]);
  }
#pragma unroll
  for (int t = 0; t < 2; ++t) {
    const int rb = (t * 4 + wave) * 8;
    gll16(Wp + (size_t)(rb + srow) * ldw + scol, &Ws[0][rb * 64]);
  }
  for (int kt = 0; kt < nT; ++kt) {
    const int cur = kt & 1;
    __syncthreads();                 // drains prefetch(kt) (vmcnt0) + buf reuse
    if (kt + 1 < nT) {
      const int kk = (kt + 1) * 64, nxt = cur ^ 1;
#pragma unroll
      for (int t = 0; t < 4; ++t) {
        const int rb = (t * 4 + wave) * 8;
        gll16(Ap + (size_t)(rb + srow) * lda + kk + scol, &As[nxt][rb * 64]);
      }
#pragma unroll
      for (int t = 0; t < 2; ++t) {
        const int rb = (t * 4 + wave) * 8;
        gll16(Wp + (size_t)(rb + srow) * ldw + kk + scol, &Ws[nxt][rb * 64]);
      }
    }
#pragma unroll
    for (int ks = 0; ks < 2; ++ks) {
      bf16x8 af[4], bf[2];
#pragma unroll
      for (int i = 0; i < 4; ++i) {
        const int ra = wm + i * 16 + l16;
        af[i] = *(const bf16x8*)&As[cur][ra * 64 + ((((ks << 2) | quad) ^ (ra & 7)) * 8)];
      }
#pragma unroll
      for (int j = 0; j < 2; ++j) {
        const int rw = wn + j * 16 + l16;
        bf[j] = *(const bf16x8*)&Ws[cur][rw * 64 + ((((ks << 2) | quad) ^ (rw & 7)) * 8)];
      }
#pragma unroll
      for (int i = 0; i < 4; ++i)
#pragma unroll
        for (int j = 0; j < 2; ++j)
          acc[i][j] = __builtin_amdgcn_mfma_f32_16x16x32_bf16(af[i], bf[j], acc[i][j], 0, 0, 0);
    }
  }
  if (mode == MODE_QKV) {
#pragma unroll
    for (int i = 0; i < 4; ++i)
#pragma unroll
      for (int r = 0; r < 4; ++r) {
        const int grow = bm * 128 + wm + i * 16 + quad * 4 + r;
        const int bidx = grow / 197;           // magic-mul
        const int lloc = grow - bidx * 197;
#pragma unroll
        for (int j = 0; j < 2; ++j) {
          const int col = bn * 64 + wn + j * 16 + l16;
          const float o = acc[i][j][r] + bias[col];
          if (col < 384) {
            C[(size_t)grow * ldc + col] = f2bf(o);
          } else if (grow < BLROWS) {
            const int h = (col - 384) >> 6, d = (col - 384) & 63;
            Vt[((size_t)(bidx * 3 + h) * 64 + d) * VLT + lloc] = f2bf(o);
          }
        }
      }
  } else {
#pragma unroll
    for (int j = 0; j < 2; ++j) {
      const int col = bn * 64 + wn + j * 16 + l16;
      const float bv = bias[col];
#pragma unroll
      for (int i = 0; i < 4; ++i)
#pragma unroll
        for (int r = 0; r < 4; ++r) {
          const int grow = bm * 128 + wm + i * 16 + quad * 4 + r;
          float o = acc[i][j][r] + bv;
          if (mode == MODE_RELU) o = fmaxf(o, 0.f);
          C[(size_t)grow * ldc + col] = f2bf(o);
        }
    }
  }
}

// ====== fused GEMM + bias + residual + LayerNorm(x1 or x2), BK=64, swz8 ======
// Tile 32 rows x 192 cols -> 396 blocks (round-5 verified sweet spot: 16-row/
// 792-block variant regressed — W-staging per block is fixed, so halving rows
// doubles total W LDS-staging traffic; 64-row/198-block under-occupies CUs).
// 4 waves: rg=wave>>1 picks row half (16 rows), cg=wave&1 picks col half
// (96 cols, 6 n-tiles -> acc[6]). Row LN = quad shfl + cross-wave LDS partial
// combine (2 extra barriers total). Writes XC in place.
__global__ __launch_bounds__(256) void gemm_ln(
    const ushort* __restrict__ A, int lda,
    const ushort* __restrict__ W, int ldw,
    const float* __restrict__ bias,
    ushort* __restrict__ XC,
    const float* __restrict__ ga, const float* __restrict__ ba,
    const float* __restrict__ gb, const float* __restrict__ bb,
    int Kdim, int dln)
{
  __shared__ __align__(16) ushort As[2][32 * 64];    // 8 KB
  __shared__ __align__(16) ushort Ws[2][192 * 64];   // 48 KB
  __shared__ float p1s[2][32], p1q[2][32], p2s[2][32], p2q[2][32];
  const int tid = threadIdx.x;
  const int bm = blockIdx.x;
  const int wave = tid >> 6, lane = tid & 63;
  const int rg = wave >> 1, cg = wave & 1;
  const int quad = lane >> 4, l16 = lane & 15;
  const int srow = lane >> 3;
  const int scol = ((lane & 7) ^ srow) * 8;
  const ushort* Ap = A + (size_t)(bm * 32) * lda;
  floatx4 acc[6] = {};
  const int nT = Kdim >> 6;
  gll16(Ap + (size_t)(wave * 8 + srow) * lda + scol, &As[0][wave * 8 * 64]);
#pragma unroll
  for (int t = 0; t < 6; ++t) {
    const int rb = (t * 4 + wave) * 8;
    gll16(W + (size_t)(rb + srow) * ldw + scol, &Ws[0][rb * 64]);
  }
  for (int kt = 0; kt < nT; ++kt) {
    const int cur = kt & 1;
    __syncthreads();
    if (kt + 1 < nT) {
      const int kk = (kt + 1) * 64, nxt = cur ^ 1;
      gll16(Ap + (size_t)(wave * 8 + srow) * lda + kk + scol, &As[nxt][wave * 8 * 64]);
#pragma unroll
      for (int t = 0; t < 6; ++t) {
        const int rb = (t * 4 + wave) * 8;
        gll16(W + (size_t)(rb + srow) * ldw + kk + scol, &Ws[nxt][rb * 64]);
      }
    }
#pragma unroll
    for (int ks = 0; ks < 2; ++ks) {
      const int ra = rg * 16 + l16;
      const bf16x8 af = *(const bf16x8*)&As[cur][ra * 64 + ((((ks << 2) | quad) ^ (ra & 7)) * 8)];
#pragma unroll
      for (int j = 0; j < 6; ++j) {
        const int rw = (cg * 6 + j) * 16 + l16;
        const bf16x8 bf = *(const bf16x8*)&Ws[cur][rw * 64 + ((((ks << 2) | quad) ^ (rw & 7)) * 8)];
        acc[j] = __builtin_amdgcn_mfma_f32_16x16x32_bf16(af, bf, acc[j], 0, 0, 0);
      }
    }
  }
  // ---- epilogue: bias + residual; LN via quad-shfl + cross-wave combine ----
  float xr[4][6];
#pragma unroll
  for (int r = 0; r < 4; ++r) {
    const int rloc = rg * 16 + quad * 4 + r;
    const int row = bm * 32 + rloc;
    const ushort* xp = XC + (size_t)row * DMODEL;
    float s = 0.f, sq = 0.f;
#pragma unroll
    for (int j = 0; j < 6; ++j) {
      const int col = (cg * 6 + j) * 16 + l16;
      const float o = acc[j][r] + bias[col] + bf2f(xp[col]);
      xr[r][j] = o; s += o; sq += o * o;
    }
#pragma unroll
    for (int m = 1; m < 16; m <<= 1) {
      s += __shfl_xor(s, m, 64); sq += __shfl_xor(sq, m, 64);
    }
    if (l16 == 0) { p1s[cg][rloc] = s; p1q[cg][rloc] = sq; }
  }
  __syncthreads();
#pragma unroll
  for (int r = 0; r < 4; ++r) {
    const int rloc = rg * 16 + quad * 4 + r;
    const float s = p1s[0][rloc] + p1s[1][rloc];
    const float sq = p1q[0][rloc] + p1q[1][rloc];
    const float mu = s * (1.f / 192.f);
    const float var = sq * (1.f / 192.f) - mu * mu;
    const float rs = rsqrtf(var + 1e-5f);
#pragma unroll
    for (int j = 0; j < 6; ++j) {
      const int col = (cg * 6 + j) * 16 + l16;
      xr[r][j] = (xr[r][j] - mu) * rs * ga[col] + ba[col];
    }
  }
  if (dln) {
#pragma unroll
    for (int r = 0; r < 4; ++r) {
      const int rloc = rg * 16 + quad * 4 + r;
      float s = 0.f, sq = 0.f;
#pragma unroll
      for (int j = 0; j < 6; ++j) { s += xr[r][j]; sq += xr[r][j] * xr[r][j]; }
#pragma unroll
      for (int m = 1; m < 16; m <<= 1) {
        s += __shfl_xor(s, m, 64); sq += __shfl_xor(sq, m, 64);
      }
      if (l16 == 0) { p2s[cg][rloc] = s; p2q[cg][rloc] = sq; }
    }
    __syncthreads();
#pragma unroll
    for (int r = 0; r < 4; ++r) {
      const int rloc = rg * 16 + quad * 4 + r;
      const float s = p2s[0][rloc] + p2s[1][rloc];
      const float sq = p2q[0][rloc] + p2q[1][rloc];
      const float mu = s * (1.f / 192.f);
      const float var = sq * (1.f / 192.f) - mu * mu;
      const float rs = rsqrtf(var + 1e-5f);
#pragma unroll
      for (int j = 0; j < 6; ++j) {
        const int col = (cg * 6 + j) * 16 + l16;
        xr[r][j] = (xr[r][j] - mu) * rs * gb[col] + bb[col];
      }
    }
  }
#pragma unroll
  for (int r = 0; r < 4; ++r) {
    const int row = bm * 32 + rg * 16 + quad * 4 + r;
    ushort* xp = XC + (size_t)row * DMODEL;
#pragma unroll
    for (int j = 0; j < 6; ++j) xp[(cg * 6 + j) * 16 + l16] = f2bf(xr[r][j]);
  }
}

// =========== fused FAVOR-K + KV accumulation (V pre-transposed) ===========
// grid (192 bh, 2 mh). Per 32-token chunk: u = K*scale @ Om_half^T (MFMA),
// phi -> PhT [128 m][32 l] (pad 40); Vts staged d-major from Vt (dbuf, group-
// swizzled src); KV += PhT @ Vts. Out KVt [bh][80 d][256 f] (d=64: ksum).
__global__ __launch_bounds__(256) void kv_fused(
    const ushort* __restrict__ qkv, const ushort* __restrict__ OmT,
    const ushort* __restrict__ Vt, ushort* __restrict__ KVt)
{
  __shared__ __align__(16) ushort Ks[32 * 64];        // 4 KB (swz8)
  __shared__ __align__(16) ushort Om[64 * 64];        // 8 KB (swz8)
  __shared__ __align__(16) ushort PhT[128 * PHTRS];   // 10 KB
  __shared__ __align__(16) ushort Vts[2][64 * 32];    // 8 KB (swz4, dbuf)
  __shared__ __align__(16) ushort Vcst[16 * 32];      // 1 KB (ksum + zero rows)
  __shared__ float offs[32];
  const int tid = threadIdx.x;
  const int bh = blockIdx.x, mh = blockIdx.y;
  const int b = bh / 3, h = bh - b * 3;
  const int wave = tid >> 6, lane = tid & 63;
  const int quad = lane >> 4, l16 = lane & 15;
  const int lr8 = lane >> 3, g8 = lane & 7;
  const int lr4 = lane >> 2, g4 = lane & 3;
#pragma unroll
  for (int t = 0; t < 2; ++t) {
    const int rb = (t * 4 + wave) * 8;
    const int row = rb + lr8;
    gll16(OmT + (size_t)(mh * 64 + row) * 64 + ((g8 ^ (row & 7)) * 8), &Om[rb * 64]);
  }
  {
    const int rowK = wave * 8 + lr8;
    gll16(qkv + (size_t)(b * 197 + rowK) * 576 + 192 + h * 64 + ((g8 ^ (rowK & 7)) * 8),
          &Ks[wave * 8 * 64]);
    const int rowV = wave * 16 + lr4;
    gll16(Vt + ((size_t)bh * 64 + rowV) * VLT + ((g4 ^ (rowV & 3)) * 8),
          &Vts[0][wave * 16 * 32]);
  }
  for (int e = tid; e < 16 * 32; e += 256) Vcst[e] = (e < 32) ? 0x3F80 : 0;
  floatx4 acc[2][5] = {};
  for (int c = 0; c < 7; ++c) {
    const int l0 = c * 32;
    const int cur = c & 1;
    __syncthreads();   // staged data ready (vmcnt0)
    if (tid < 64) {
      const int row = tid >> 1, half = tid & 1;
      float s = 0.f;
#pragma unroll
      for (int t = 0; t < 4; ++t) {
        bf16x8 v8 = *(const bf16x8*)&Ks[row * 64 + (((half * 4 + t) ^ (row & 7)) * 8)];
#pragma unroll
        for (int q = 0; q < 8; ++q) { float xv = bf2f((ushort)v8[q]); s += xv * xv; }
      }
      s += __shfl_xor(s, 1, 64);
      if (half == 0) offs[row] = 0.0625f * s;   // 0.5*scale^2 (scale^2=0.125)
    }
    floatx4 ui[2] = {};
#pragma unroll
    for (int ksb = 0; ksb < 2; ++ksb) {
      bf16x8 af[2], bfm;
#pragma unroll
      for (int i = 0; i < 2; ++i) {
        const int row = i * 16 + l16;
        af[i] = *(const bf16x8*)&Ks[row * 64 + (((quad + (ksb << 2)) ^ (row & 7)) * 8)];
      }
      {
        const int row = wave * 16 + l16;
        bfm = *(const bf16x8*)&Om[row * 64 + (((quad + (ksb << 2)) ^ (row & 7)) * 8)];
      }
#pragma unroll
      for (int i = 0; i < 2; ++i)
        ui[i] = __builtin_amdgcn_mfma_f32_16x16x32_bf16(af[i], bfm, ui[i], 0, 0, 0);
    }
    __syncthreads();   // Ks/Om reads done
    {
      const int mloc = wave * 16 + l16;
#pragma unroll
      for (int i = 0; i < 2; ++i) {
#pragma unroll
        for (int r = 0; r < 4; ++r) {
          const int ll = i * 16 + quad * 4 + r;
          float ep = 0.f, em = 0.f;
          if (l0 + ll < 197) {
            const float off = offs[ll];
            const float u = ui[i][r];
            ep = __expf(u - off) * 0.0625f;
            em = __expf(-u - off) * 0.0625f;
          }
          PhT[mloc * PHTRS + ll] = f2bf(ep);
          PhT[(64 + mloc) * PHTRS + ll] = f2bf(em);
        }
      }
    }
    if (c + 1 < 7) {   // prefetch next chunk (Ks single-buf safe; Vts dbuf)
      const int rowK = wave * 8 + lr8;
      const int lK = (c + 1) * 32 + rowK;
      gll16(qkv + (size_t)(b * 197 + lK) * 576 + 192 + h * 64 + ((g8 ^ (rowK & 7)) * 8),
            &Ks[wave * 8 * 64]);
      const int rowV = wave * 16 + lr4;
      gll16(Vt + ((size_t)bh * 64 + rowV) * VLT + (c + 1) * 32 + ((g4 ^ (rowV & 3)) * 8),
            &Vts[cur ^ 1][wave * 16 * 32]);
    }
    __syncthreads();   // PhT visible (also drains prefetch; harmless)
    bf16x8 af[2], bf[5];
#pragma unroll
    for (int i = 0; i < 2; ++i)
      af[i] = *(const bf16x8*)&PhT[(wave * 32 + i * 16 + l16) * PHTRS + quad * 8];
#pragma unroll
    for (int j = 0; j < 4; ++j) {
      const int row = j * 16 + l16;
      bf[j] = *(const bf16x8*)&Vts[cur][row * 32 + ((quad ^ (row & 3)) * 8)];
    }
    bf[4] = *(const bf16x8*)&Vcst[l16 * 32 + quad * 8];
#pragma unroll
    for (int i = 0; i < 2; ++i)
#pragma unroll
      for (int j = 0; j < 5; ++j)
        acc[i][j] = __builtin_amdgcn_mfma_f32_16x16x32_bf16(af[i], bf[j], acc[i][j], 0, 0, 0);
  }
#pragma unroll
  for (int i = 0; i < 2; ++i) {
    const int prow0 = wave * 32 + i * 16 + quad * 4;
    const int f0 = (prow0 < 64) ? (mh * 64 + prow0) : (128 + mh * 64 + prow0 - 64);
#pragma unroll
    for (int j = 0; j < 5; ++j) {
      const int d = j * 16 + l16;
      short4v pk;
#pragma unroll
      for (int r = 0; r < 4; ++r) pk[r] = (short)f2bf(acc[i][j][r]);
      *(short4v*)(KVt + ((size_t)bh * 80 + d) * 256 + f0) = pk;
    }
  }
}

// =========== fused FAVOR-Q + attn: out = Z * (phiQ @ KVt^T) ===========
// grid (4 l-tiles of 64, 192 bh) -> 768 blocks = 3/CU for barrier overlap.
__global__ __launch_bounds__(256) void attn_fused(
    const ushort* __restrict__ qkv, const ushort* __restrict__ OmT,
    const ushort* __restrict__ KVt, ushort* __restrict__ OUT)
{
  __shared__ __align__(16) ushort Phi[64 * PHIRS];   // 33 KB; [0:8K)=Qs, [8K:24K)=Om
  __shared__ __align__(16) ushort Bs[2][80 * 32];    // 10 KB (swz4)
  __shared__ float offs[64];
  __shared__ float zs[64];
  ushort* Qs = Phi;                 // 64 x 64 (swz8)
  ushort* Om = Phi + 64 * 64;       // 128 x 64 (swz8)
  const int tid = threadIdx.x;
  const int bx = blockIdx.x, bh = blockIdx.y;
  const int b = bh / 3, h = bh - b * 3;
  const int wave = tid >> 6, lane = tid & 63;
  const int quad = lane >> 4, l16 = lane & 15;
  const int lr8 = lane >> 3, g8 = lane & 7;
  const int lr4 = lane >> 2, g4 = lane & 3;
#pragma unroll
  for (int t = 0; t < 2; ++t) {
    const int rb = wave * 16 + t * 8;
    const int row = rb + lr8;
    const int l = bx * 64 + row;
    gll16(qkv + (size_t)(b * 197 + l) * 576 + h * 64 + ((g8 ^ (row & 7)) * 8), &Qs[rb * 64]);
  }
#pragma unroll
  for (int t = 0; t < 4; ++t) {
    const int rb = wave * 32 + t * 8;
    const int row = rb + lr8;
    gll16(OmT + (size_t)row * 64 + ((g8 ^ (row & 7)) * 8), &Om[rb * 64]);
  }
  __syncthreads();
  if (tid < 128) {
    const int row = tid >> 1, half = tid & 1;
    float s = 0.f;
#pragma unroll
    for (int t = 0; t < 4; ++t) {
      bf16x8 v8 = *(const bf16x8*)&Qs[row * 64 + (((half * 4 + t) ^ (row & 7)) * 8)];
#pragma unroll
      for (int q = 0; q < 8; ++q) { float xv = bf2f((ushort)v8[q]); s += xv * xv; }
    }
    s += __shfl_xor(s, 1, 64);
    if (half == 0) offs[row] = 0.0625f * s;
  }
  floatx4 uacc[8] = {};
#pragma unroll
  for (int ksb = 0; ksb < 2; ++ksb) {
    bf16x8 af, bf[8];
    {
      const int row = wave * 16 + l16;
      af = *(const bf16x8*)&Qs[row * 64 + (((quad + (ksb << 2)) ^ (row & 7)) * 8)];
    }
#pragma unroll
    for (int j = 0; j < 8; ++j) {
      const int row = j * 16 + l16;
      bf[j] = *(const bf16x8*)&Om[row * 64 + (((quad + (ksb << 2)) ^ (row & 7)) * 8)];
    }
#pragma unroll
    for (int j = 0; j < 8; ++j)
      uacc[j] = __builtin_amdgcn_mfma_f32_16x16x32_bf16(af, bf[j], uacc[j], 0, 0, 0);
  }
  __syncthreads();   // Qs/Om reads done -> Phi overwrite legal
#pragma unroll
  for (int r = 0; r < 4; ++r) {
    const int l = wave * 16 + quad * 4 + r;
    const float off = offs[l];
#pragma unroll
    for (int j = 0; j < 8; ++j) {
      const int m = j * 16 + l16;
      const float u = uacc[j][r];
      Phi[l * PHIRS + m]       = f2bf(__expf(u - off)  * 0.0625f);
      Phi[l * PHIRS + m + 128] = f2bf(__expf(-u - off) * 0.0625f);
    }
  }
  const ushort* Bp = KVt + (size_t)bh * 80 * 256;
  {
    const int row = wave * 16 + lr4;
    gll16(Bp + (size_t)row * 256 + ((g4 ^ (row & 3)) * 8), &Bs[0][wave * 16 * 32]);
    if (wave == 0)
      gll16(Bp + (size_t)(64 + lr4) * 256 + ((g4 ^ (lr4 & 3)) * 8), &Bs[0][64 * 32]);
  }
  floatx4 acc[5] = {};
  for (int c = 0; c < 8; ++c) {
    const int cur = c & 1;
    __syncthreads();   // Phi visible (c=0) + Bs staging drained + dbuf guard
    if (c + 1 < 8) {
      const int m0 = (c + 1) * 32, nxt = cur ^ 1;
      const int row = wave * 16 + lr4;
      gll16(Bp + (size_t)row * 256 + m0 + ((g4 ^ (row & 3)) * 8), &Bs[nxt][wave * 16 * 32]);
      if (wave == 0)
        gll16(Bp + (size_t)(64 + lr4) * 256 + m0 + ((g4 ^ (lr4 & 3)) * 8), &Bs[nxt][64 * 32]);
    }
    const int m0 = c * 32;
    bf16x8 af, bf[5];
    af = *(const bf16x8*)&Phi[(wave * 16 + l16) * PHIRS + m0 + quad * 8];
#pragma unroll
    for (int j = 0; j < 5; ++j) {
      const int row = j * 16 + l16;
      bf[j] = *(const bf16x8*)&Bs[cur][row * 32 + ((quad ^ (row & 3)) * 8)];
    }
#pragma unroll
    for (int j = 0; j < 5; ++j)
      acc[j] = __builtin_amdgcn_mfma_f32_16x16x32_bf16(af, bf[j], acc[j], 0, 0, 0);
  }
  if (l16 == 0) {
#pragma unroll
    for (int r = 0; r < 4; ++r)
      zs[wave * 16 + quad * 4 + r] = acc[4][r];
  }
  __syncthreads();
#pragma unroll
  for (int r = 0; r < 4; ++r) {
    const int ll = wave * 16 + quad * 4 + r;
    const int l = bx * 64 + ll;
    if (l >= 197) continue;
    const float z = 1.f / (zs[ll] + 1e-6f);
#pragma unroll
    for (int j = 0; j < 4; ++j)
      OUT[(size_t)(b * 197 + l) * 192 + h * 64 + j * 16 + l16] =
          f2bf(acc[j][r] * z);
  }
}

// ---------------- weight pre-conversion ----------------
__global__ void conv_qkv(const float* __restrict__ Wq, const float* __restrict__ Wk,
                         const float* __restrict__ Wv, const float* __restrict__ bq,
                         const float* __restrict__ bk, const float* __restrict__ bv,
                         ushort* __restrict__ dst, float* __restrict__ bdst) {
  const int l = blockIdx.y;
  const int e = blockIdx.x * 256 + threadIdx.x;   // < 576*192
  const int n = e / 192, k = e - n * 192;
  const float* src;
  if (n < 192)      src = Wq + (size_t)l * 36864 + n * 192;
  else if (n < 384) src = Wk + (size_t)l * 36864 + (n - 192) * 192;
  else              src = Wv + (size_t)l * 36864 + (n - 384) * 192;
  dst[(size_t)l * 640 * 192 + e] = f2bf(src[k]);
  if (e < 576) {
    float bvv;
    if (e < 192)      bvv = bq[l * 192 + e];
    else if (e < 384) bvv = bk[l * 192 + e - 192];
    else              bvv = bv[l * 192 + e - 384];
    bdst[l * 576 + e] = bvv;
  }
}

__global__ void conv_pad(const float* __restrict__ src, ushort* __restrict__ dst,
                         int NK, int padNK) {
  const int l = blockIdx.y;
  const int e = blockIdx.x * 256 + threadIdx.x;
  if (e < NK) dst[(size_t)l * padNK + e] = f2bf(src[(size_t)l * NK + e]);
}

// omega [l][64 d][128 m] -> OmT' [l][128 m][64 d] * sqrt(temp)
__global__ void conv_omt(const float* __restrict__ om, ushort* __restrict__ dst) {
  const int l = blockIdx.y;
  const int e = blockIdx.x * 256 + threadIdx.x;   // < 8192
  const int m = e >> 6, d = e & 63;
  dst[(size_t)l * 8192 + e] = f2bf(0.35355339059327379f * om[(size_t)l * 8192 + d * 128 + m]);
}

// ---------------- im2col (fp32 in -> bf16 out) ----------------
__global__ __launch_bounds__(256) void im2col_kernel(
    const float* __restrict__ X, ushort* __restrict__ Apd)
{
  const int bp = blockIdx.x;
  const int b = bp / NPATCH, p = bp - b * NPATCH;
  const int gh = p / 14, gw = p - gh * 14;
  for (int e = threadIdx.x; e < KPATCH; e += 256) {
    const int c = e >> 8, rem = e & 255, ph = rem >> 4, pw = rem & 15;
    Apd[(size_t)bp * KPATCH + e] =
        f2bf(X[((size_t)(b * 3 + c) * 224 + gh * 16 + ph) * 224 + gw * 16 + pw]);
  }
}

// ---------------- assemble tokens ----------------
__global__ __launch_bounds__(256) void assemble_kernel(
    const ushort* __restrict__ TK, const float* __restrict__ g,
    const float* __restrict__ bt, const float* __restrict__ cls,
    const float* __restrict__ pos, ushort* __restrict__ XC)
{
  const int w = threadIdx.x >> 6, lane = threadIdx.x & 63;
  const int row = blockIdx.x * 4 + w;
  const int b = row / LLEN, l = row - b * LLEN;
  float o0, o1, o2;
  if (l == 0) {
    o0 = cls[lane]; o1 = cls[lane + 64]; o2 = cls[lane + 128];
  } else {
    const ushort* tp = TK + (size_t)(b * NPATCH + l - 1) * DMODEL;
    const float x0 = bf2f(tp[lane]), x1 = bf2f(tp[lane + 64]), x2 = bf2f(tp[lane + 128]);
    const float s  = wave_reduce_sum(x0 + x1 + x2);
    const float sq = wave_reduce_sum(x0 * x0 + x1 * x1 + x2 * x2);
    const float mu = s * (1.f / 192.f);
    const float var = sq * (1.f / 192.f) - mu * mu;
    const float rs = rsqrtf(var + 1e-5f);
    o0 = (x0 - mu) * rs * g[lane]       + bt[lane];
    o1 = (x1 - mu) * rs * g[lane + 64]  + bt[lane + 64];
    o2 = (x2 - mu) * rs * g[lane + 128] + bt[lane + 128];
  }
  o0 += pos[l * DMODEL + lane];
  o1 += pos[l * DMODEL + lane + 64];
  o2 += pos[l * DMODEL + lane + 128];
  ushort* xp = XC + (size_t)row * DMODEL;
  xp[lane] = f2bf(o0); xp[lane + 64] = f2bf(o1); xp[lane + 128] = f2bf(o2);
}

// ---------------- fused pool + head (one class per wave, coalesced) ---------
// Old version: each thread owned a class -> 192 scalar fp32 loads at 768 B
// thread-stride (64 cache lines/wave/iter, 4 B used each) -> 39.7 us. Now:
// wave owns a class; lane l reads w[n][l], w[n][l+64], w[n][l+128] (three
// coalesced 256 B wave-reads), z held in regs, 6-step shfl reduce.
__global__ __launch_bounds__(256) void head_kernel(
    const ushort* __restrict__ XC, const float* __restrict__ HW,
    const float* __restrict__ HB, float* __restrict__ OUTp)
{
  __shared__ float zsh[DMODEL];
  const int b = blockIdx.y;
  const int tid = threadIdx.x;
  const int wave = tid >> 6, lane = tid & 63;
  if (wave < 3) {
    const int d = wave * 64 + lane;
    const ushort* xp = XC + (size_t)b * LLEN * DMODEL + d;
    float s = 0.f;
#pragma unroll 4
    for (int l = 0; l < LLEN; ++l) s += bf2f(xp[(size_t)l * DMODEL]);
    zsh[d] = s * (1.f / 197.f);
  }
  __syncthreads();
  const float z0 = zsh[lane], z1 = zsh[lane + 64], z2 = zsh[lane + 128];
  const int n0 = blockIdx.x * 250;
  for (int n = n0 + wave; n < n0 + 250; n += 4) {
    const float* w = HW + (size_t)n * DMODEL;
    float s = z0 * w[lane] + z1 * w[lane + 64] + z2 * w[lane + 128];
    s = wave_reduce_sum(s);
    if (lane == 0) OUTp[(size_t)b * NCLS + n] = s + HB[n];
  }
}

// ---------------- host orchestration ----------------
extern "C" void kernel_launch(void* const* d_in, const int* in_sizes, int n_in,
                              void* d_out, int out_size, void* d_ws, size_t ws_size,
                              hipStream_t stream) {
  const float* x        = (const float*)d_in[0];
  const float* patch_w  = (const float*)d_in[1];
  const float* patch_b  = (const float*)d_in[2];
  const float* pe_ln_g  = (const float*)d_in[3];
  const float* pe_ln_b  = (const float*)d_in[4];
  const float* cls_tok  = (const float*)d_in[5];
  const float* pos_emb  = (const float*)d_in[6];
  const float* Wq = (const float*)d_in[7];
  const float* bq = (const float*)d_in[8];
  const float* Wk = (const float*)d_in[9];
  const float* bk = (const float*)d_in[10];
  const float* Wv = (const float*)d_in[11];
  const float* bv = (const float*)d_in[12];
  const float* Wo = (const float*)d_in[13];
  const float* bo = (const float*)d_in[14];
  const float* ln1_g = (const float*)d_in[15];
  const float* ln1_b = (const float*)d_in[16];
  const float* ln2_g = (const float*)d_in[17];
  const float* ln2_b = (const float*)d_in[18];
  const float* lnb_g = (const float*)d_in[19];
  const float* lnb_b = (const float*)d_in[20];
  const float* W1 = (const float*)d_in[21];
  const float* b1 = (const float*)d_in[22];
  const float* W2 = (const float*)d_in[23];
  const float* b2 = (const float*)d_in[24];
  const float* omega  = (const float*)d_in[25];
  const float* head_w = (const float*)d_in[26];
  const float* head_b = (const float*)d_in[27];
  float* out = (float*)d_out;
  char* wsb = (char*)d_ws;

  size_t off = 0;
  auto carve = [&](size_t bytes) { size_t o = off; off += (bytes + 255) & ~(size_t)255; return o; };
  ushort* xc     = (ushort*)(wsb + carve((size_t)MPAD * 192 * 2));
  ushort* qkv    = (ushort*)(wsb + carve((size_t)MPAD * 576 * 2));
  ushort* ab     = (ushort*)(wsb + carve((size_t)MPAD * 192 * 2));
  ushort* hidden = (ushort*)(wsb + carve((size_t)MPAD * 768 * 2));   // aliases im2col
  ushort* KVt    = (ushort*)(wsb + carve((size_t)192 * 80 * 256 * 2));
  ushort* Vt     = (ushort*)(wsb + carve((size_t)192 * 64 * VLT * 2 + 1024)); // +pad for swz overrun
  float*  bqkv   = (float*)(wsb + carve((size_t)12 * 576 * 4));
  ushort* Wqkv_bf = (ushort*)(wsb + carve((size_t)12 * 640 * 192 * 2));
  ushort* Wo_bf   = (ushort*)(wsb + carve((size_t)12 * 256 * 192 * 2));
  ushort* W1_bf   = (ushort*)(wsb + carve((size_t)12 * 768 * 192 * 2));
  ushort* W2_bf   = (ushort*)(wsb + carve((size_t)12 * 256 * 768 * 2));
  ushort* Wp_bf   = (ushort*)(wsb + carve((size_t)256 * 768 * 2));
  ushort* Om_bf   = (ushort*)(wsb + carve((size_t)12 * 128 * 64 * 2));
  ushort* i2c     = hidden;   // patch GEMM consumes before FF uses hidden

  // ---- zero Vt (pad cols l in [197,208) + swz-overrun tail must be finite 0) ----
  {
    const int n16 = (int)(((size_t)192 * 64 * VLT * 2 + 1024) / 16);
    zero_buf<<<(n16 + 255) / 256, 256, 0, stream>>>((uint4*)Vt, n16);
  }

  // ---- pre-conversion ----
  conv_qkv<<<dim3(432, 12), 256, 0, stream>>>(Wq, Wk, Wv, bq, bk, bv, Wqkv_bf, bqkv);
  conv_pad<<<dim3(144, 12), 256, 0, stream>>>(Wo, Wo_bf, 36864, 256 * 192);
  conv_pad<<<dim3(576, 12), 256, 0, stream>>>(W1, W1_bf, 147456, 768 * 192);
  conv_pad<<<dim3(576, 12), 256, 0, stream>>>(W2, W2_bf, 147456, 256 * 768);
  conv_pad<<<dim3(576, 1), 256, 0, stream>>>(patch_w, Wp_bf, 147456, 256 * 768);
  conv_omt<<<dim3(32, 12), 256, 0, stream>>>(omega, Om_bf);

  // ---- patch embedding ----
  im2col_kernel<<<BPROWS, 256, 0, stream>>>(x, i2c);
  gemm_bf2<<<dim3(98, 3), 256, 0, stream>>>(i2c, KPATCH, Wp_bf, KPATCH,
      patch_b, ab, DMODEL, nullptr, KPATCH, MODE_PLAIN);
  assemble_kernel<<<BLROWS / 4, 256, 0, stream>>>(ab, pe_ln_g, pe_ln_b,
                                                  cls_tok, pos_emb, xc);

  const int exits[3] = {3, 7, 11};
  for (int i = 0; i < NDEPTH; ++i) {
    // QKV: 128x64 tiles, N=576 -> 9 N-tiles, 891 blocks; V -> Vt
    gemm_bf2<<<dim3(99, 9), 256, 0, stream>>>(xc, DMODEL,
        Wqkv_bf + (size_t)i * 640 * 192, DMODEL, bqkv + i * 576,
        qkv, 576, Vt, DMODEL, MODE_QKV);
    // fused FAVOR-K + KV (V pre-transposed)
    kv_fused<<<dim3(192, 2), 256, 0, stream>>>(qkv,
        Om_bf + (size_t)i * 8192, Vt, KVt);
    // fused FAVOR-Q + attn (64-row tiles, 768 blocks)
    attn_fused<<<dim3(4, 192), 256, 0, stream>>>(qkv,
        Om_bf + (size_t)i * 8192, KVt, ab);
    // O-proj + bias + residual + LN1, fused (32-row tiles, 396 blocks)
    gemm_ln<<<MPAD / 32, 256, 0, stream>>>(ab, DMODEL,
        Wo_bf + (size_t)i * 256 * 192, DMODEL, bo + i * DMODEL, xc,
        ln1_g + i * DMODEL, ln1_b + i * DMODEL, nullptr, nullptr,
        DMODEL, 0);
    // W1: 128x64 tiles, N=768 -> 12 N-tiles, 1188 blocks
    gemm_bf2<<<dim3(99, 12), 256, 0, stream>>>(xc, DMODEL,
        W1_bf + (size_t)i * 768 * 192, DMODEL, b1 + i * FFDIM,
        hidden, FFDIM, nullptr, DMODEL, MODE_RELU);
    // W2 + bias + residual + LN2 + LNb, fused (32-row tiles, 396 blocks)
    gemm_ln<<<MPAD / 32, 256, 0, stream>>>(hidden, FFDIM,
        W2_bf + (size_t)i * 256 * 768, FFDIM, b2 + i * DMODEL, xc,
        ln2_g + i * DMODEL, ln2_b + i * DMODEL,
        lnb_g + i * DMODEL, lnb_b + i * DMODEL,
        FFDIM, 1);

    for (int j = 0; j < 3; ++j) {
      if (i == exits[j]) {
        head_kernel<<<dim3(4, BB), 256, 0, stream>>>(
            xc, head_w + (size_t)j * NCLS * DMODEL, head_b + (size_t)j * NCLS,
            out + (size_t)j * BB * NCLS);
      }
    }
  }
}

// Round 9
// 1324.463 us; speedup vs baseline: 1.2817x; 1.0678x over previous
//
#include <hip/hip_runtime.h>
#include <math.h>

// ---------------- problem constants ----------------
#define BB     64
#define LLEN   197
#define BLROWS 12608      // BB*LLEN
#define MPAD   12672      // BLROWS padded to 99*128 (= 396*32)
#define DMODEL 192
#define NHEAD  3
#define DHEAD  64
#define M2FEAT 256
#define FFDIM  768
#define NDEPTH 12
#define NCLS   1000
#define NPATCH 196
#define BPROWS 12544      // BB*NPATCH (= 98*128 exactly)
#define KPATCH 768
#define PHIRS  264        // Phi LDS row stride (256 + 8 pad, 16B-aligned)
#define PHTRS  40         // PhT LDS row stride (32 + 8 pad, 16B-aligned)
#define VLT    208        // Vt row length (197 padded, 16B-aligned)

#define MODE_PLAIN 0
#define MODE_RELU  1
#define MODE_QKV   2      // cols<384 -> qkv; cols>=384 -> transposed Vt

typedef unsigned short ushort;
typedef __attribute__((ext_vector_type(8))) short bf16x8;
typedef __attribute__((ext_vector_type(4))) float floatx4;
typedef __attribute__((ext_vector_type(4))) short short4v;

__device__ __forceinline__ float wave_reduce_sum(float v) {
#pragma unroll
  for (int s = 32; s > 0; s >>= 1) v += __shfl_xor(v, s, 64);
  return v;
}
__device__ __forceinline__ ushort f2bf(float f) {  // RNE fp32->bf16
  unsigned u = __float_as_uint(f);
  return (ushort)((u + 0x7fffu + ((u >> 16) & 1u)) >> 16);
}
__device__ __forceinline__ float bf2f(ushort u) {
  return __uint_as_float(((unsigned)u) << 16);
}
// async global->LDS, 16 B per lane; LDS dest wave-uniform (HW adds lane*16);
// global src is PER-LANE -> swizzled LDS layouts via pre-swizzled src (T2).
__device__ __forceinline__ void gll16(const ushort* g, ushort* l) {
  __builtin_amdgcn_global_load_lds(
      (const __attribute__((address_space(1))) void*)g,
      (__attribute__((address_space(3))) void*)l, 16, 0, 0);
}

__global__ void zero_buf(uint4* __restrict__ p, int n16) {
  const int i = blockIdx.x * 256 + threadIdx.x;
  if (i < n16) p[i] = uint4{0, 0, 0, 0};
}

// ====== bf16 GEMM, 128x64 tile, BK=64, dbuf LDS, swz8 (all wide GEMMs) ======
// block 256 = 4 waves (2x2 of 64x32), 48 KB LDS -> 3 blocks/CU for drain
// overlap. bias (+relu) out. MODE_QKV: cols<384 -> qkv; [384,576) -> Vt[bh][d][l].
// (round-5 verified version; W-in-regs variant regressed: uncoalesced 384B-
//  strided per-lane loads — keep W staged via coalesced gll16.)
__global__ __launch_bounds__(256) void gemm_bf2(
    const ushort* __restrict__ A, int lda,
    const ushort* __restrict__ W, int ldw,
    const float* __restrict__ bias,
    ushort* __restrict__ C, int ldc, ushort* __restrict__ Vt,
    int Kdim, int mode)
{
  __shared__ __align__(16) ushort As[2][128 * 64];   // 32 KB
  __shared__ __align__(16) ushort Ws[2][64 * 64];    // 16 KB
  const int tid = threadIdx.x;
  const int bm = blockIdx.x, bn = blockIdx.y;
  const int wave = tid >> 6, lane = tid & 63;
  const int wm = (wave >> 1) * 64, wn = (wave & 1) * 32;
  const int quad = lane >> 4, l16 = lane & 15;
  const int srow = lane >> 3;                 // 0..7 within an 8-row stage call
  const int scol = ((lane & 7) ^ srow) * 8;   // swizzled source col group
  const ushort* Ap = A + (size_t)(bm * 128) * lda;
  const ushort* Wp = W + (size_t)(bn * 64) * ldw;
  floatx4 acc[4][2] = {};
  const int nT = Kdim >> 6;
#pragma unroll
  for (int t = 0; t < 4; ++t) {
    const int rb = (t * 4 + wave) * 8;
    gll16(Ap + (size_t)(rb + srow) * lda + scol, &As[0][rb * 64]);
  }
#pragma unroll
  for (int t = 0; t < 2; ++t) {
    const int rb = (t * 4 + wave) * 8;
    gll16(Wp + (size_t)(rb + srow) * ldw + scol, &Ws[0][rb * 64]);
  }
  for (int kt = 0; kt < nT; ++kt) {
    const int cur = kt & 1;
    __syncthreads();                 // drains prefetch(kt) (vmcnt0) + buf reuse
    if (kt + 1 < nT) {
      const int kk = (kt + 1) * 64, nxt = cur ^ 1;
#pragma unroll
      for (int t = 0; t < 4; ++t) {
        const int rb = (t * 4 + wave) * 8;
        gll16(Ap + (size_t)(rb + srow) * lda + kk + scol, &As[nxt][rb * 64]);
      }
#pragma unroll
      for (int t = 0; t < 2; ++t) {
        const int rb = (t * 4 + wave) * 8;
        gll16(Wp + (size_t)(rb + srow) * ldw + kk + scol, &Ws[nxt][rb * 64]);
      }
    }
#pragma unroll
    for (int ks = 0; ks < 2; ++ks) {
      bf16x8 af[4], bf[2];
#pragma unroll
      for (int i = 0; i < 4; ++i) {
        const int ra = wm + i * 16 + l16;
        af[i] = *(const bf16x8*)&As[cur][ra * 64 + ((((ks << 2) | quad) ^ (ra & 7)) * 8)];
      }
#pragma unroll
      for (int j = 0; j < 2; ++j) {
        const int rw = wn + j * 16 + l16;
        bf[j] = *(const bf16x8*)&Ws[cur][rw * 64 + ((((ks << 2) | quad) ^ (rw & 7)) * 8)];
      }
#pragma unroll
      for (int i = 0; i < 4; ++i)
#pragma unroll
        for (int j = 0; j < 2; ++j)
          acc[i][j] = __builtin_amdgcn_mfma_f32_16x16x32_bf16(af[i], bf[j], acc[i][j], 0, 0, 0);
    }
  }
  if (mode == MODE_QKV) {
#pragma unroll
    for (int i = 0; i < 4; ++i)
#pragma unroll
      for (int r = 0; r < 4; ++r) {
        const int grow = bm * 128 + wm + i * 16 + quad * 4 + r;
        const int bidx = grow / 197;           // magic-mul
        const int lloc = grow - bidx * 197;
#pragma unroll
        for (int j = 0; j < 2; ++j) {
          const int col = bn * 64 + wn + j * 16 + l16;
          const float o = acc[i][j][r] + bias[col];
          if (col < 384) {
            C[(size_t)grow * ldc + col] = f2bf(o);
          } else if (grow < BLROWS) {
            const int h = (col - 384) >> 6, d = (col - 384) & 63;
            Vt[((size_t)(bidx * 3 + h) * 64 + d) * VLT + lloc] = f2bf(o);
          }
        }
      }
  } else {
#pragma unroll
    for (int j = 0; j < 2; ++j) {
      const int col = bn * 64 + wn + j * 16 + l16;
      const float bv = bias[col];
#pragma unroll
      for (int i = 0; i < 4; ++i)
#pragma unroll
        for (int r = 0; r < 4; ++r) {
          const int grow = bm * 128 + wm + i * 16 + quad * 4 + r;
          float o = acc[i][j][r] + bv;
          if (mode == MODE_RELU) o = fmaxf(o, 0.f);
          C[(size_t)grow * ldc + col] = f2bf(o);
        }
    }
  }
}

// ====== fused GEMM + bias + residual + LayerNorm(x1 or x2), BK=64, swz8 ======
// Tile 32 rows x 192 cols -> 396 blocks (round-5 verified sweet spot: 16-row/
// 792-block variant regressed — W-staging per block is fixed, so halving rows
// doubles total W LDS-staging traffic; 64-row/198-block under-occupies CUs).
// 4 waves: rg=wave>>1 picks row half (16 rows), cg=wave&1 picks col half
// (96 cols, 6 n-tiles -> acc[6]). Row LN = quad shfl + cross-wave LDS partial
// combine (2 extra barriers total). Writes XC in place.
__global__ __launch_bounds__(256) void gemm_ln(
    const ushort* __restrict__ A, int lda,
    const ushort* __restrict__ W, int ldw,
    const float* __restrict__ bias,
    ushort* __restrict__ XC,
    const float* __restrict__ ga, const float* __restrict__ ba,
    const float* __restrict__ gb, const float* __restrict__ bb,
    int Kdim, int dln)
{
  __shared__ __align__(16) ushort As[2][32 * 64];    // 8 KB
  __shared__ __align__(16) ushort Ws[2][192 * 64];   // 48 KB
  __shared__ float p1s[2][32], p1q[2][32], p2s[2][32], p2q[2][32];
  const int tid = threadIdx.x;
  const int bm = blockIdx.x;
  const int wave = tid >> 6, lane = tid & 63;
  const int rg = wave >> 1, cg = wave & 1;
  const int quad = lane >> 4, l16 = lane & 15;
  const int srow = lane >> 3;
  const int scol = ((lane & 7) ^ srow) * 8;
  const ushort* Ap = A + (size_t)(bm * 32) * lda;
  floatx4 acc[6] = {};
  const int nT = Kdim >> 6;
  gll16(Ap + (size_t)(wave * 8 + srow) * lda + scol, &As[0][wave * 8 * 64]);
#pragma unroll
  for (int t = 0; t < 6; ++t) {
    const int rb = (t * 4 + wave) * 8;
    gll16(W + (size_t)(rb + srow) * ldw + scol, &Ws[0][rb * 64]);
  }
  for (int kt = 0; kt < nT; ++kt) {
    const int cur = kt & 1;
    __syncthreads();
    if (kt + 1 < nT) {
      const int kk = (kt + 1) * 64, nxt = cur ^ 1;
      gll16(Ap + (size_t)(wave * 8 + srow) * lda + kk + scol, &As[nxt][wave * 8 * 64]);
#pragma unroll
      for (int t = 0; t < 6; ++t) {
        const int rb = (t * 4 + wave) * 8;
        gll16(W + (size_t)(rb + srow) * ldw + kk + scol, &Ws[nxt][rb * 64]);
      }
    }
#pragma unroll
    for (int ks = 0; ks < 2; ++ks) {
      const int ra = rg * 16 + l16;
      const bf16x8 af = *(const bf16x8*)&As[cur][ra * 64 + ((((ks << 2) | quad) ^ (ra & 7)) * 8)];
#pragma unroll
      for (int j = 0; j < 6; ++j) {
        const int rw = (cg * 6 + j) * 16 + l16;
        const bf16x8 bf = *(const bf16x8*)&Ws[cur][rw * 64 + ((((ks << 2) | quad) ^ (rw & 7)) * 8)];
        acc[j] = __builtin_amdgcn_mfma_f32_16x16x32_bf16(af, bf, acc[j], 0, 0, 0);
      }
    }
  }
  // ---- epilogue: bias + residual; LN via quad-shfl + cross-wave combine ----
  float xr[4][6];
#pragma unroll
  for (int r = 0; r < 4; ++r) {
    const int rloc = rg * 16 + quad * 4 + r;
    const int row = bm * 32 + rloc;
    const ushort* xp = XC + (size_t)row * DMODEL;
    float s = 0.f, sq = 0.f;
#pragma unroll
    for (int j = 0; j < 6; ++j) {
      const int col = (cg * 6 + j) * 16 + l16;
      const float o = acc[j][r] + bias[col] + bf2f(xp[col]);
      xr[r][j] = o; s += o; sq += o * o;
    }
#pragma unroll
    for (int m = 1; m < 16; m <<= 1) {
      s += __shfl_xor(s, m, 64); sq += __shfl_xor(sq, m, 64);
    }
    if (l16 == 0) { p1s[cg][rloc] = s; p1q[cg][rloc] = sq; }
  }
  __syncthreads();
#pragma unroll
  for (int r = 0; r < 4; ++r) {
    const int rloc = rg * 16 + quad * 4 + r;
    const float s = p1s[0][rloc] + p1s[1][rloc];
    const float sq = p1q[0][rloc] + p1q[1][rloc];
    const float mu = s * (1.f / 192.f);
    const float var = sq * (1.f / 192.f) - mu * mu;
    const float rs = rsqrtf(var + 1e-5f);
#pragma unroll
    for (int j = 0; j < 6; ++j) {
      const int col = (cg * 6 + j) * 16 + l16;
      xr[r][j] = (xr[r][j] - mu) * rs * ga[col] + ba[col];
    }
  }
  if (dln) {
#pragma unroll
    for (int r = 0; r < 4; ++r) {
      const int rloc = rg * 16 + quad * 4 + r;
      float s = 0.f, sq = 0.f;
#pragma unroll
      for (int j = 0; j < 6; ++j) { s += xr[r][j]; sq += xr[r][j] * xr[r][j]; }
#pragma unroll
      for (int m = 1; m < 16; m <<= 1) {
        s += __shfl_xor(s, m, 64); sq += __shfl_xor(sq, m, 64);
      }
      if (l16 == 0) { p2s[cg][rloc] = s; p2q[cg][rloc] = sq; }
    }
    __syncthreads();
#pragma unroll
    for (int r = 0; r < 4; ++r) {
      const int rloc = rg * 16 + quad * 4 + r;
      const float s = p2s[0][rloc] + p2s[1][rloc];
      const float sq = p2q[0][rloc] + p2q[1][rloc];
      const float mu = s * (1.f / 192.f);
      const float var = sq * (1.f / 192.f) - mu * mu;
      const float rs = rsqrtf(var + 1e-5f);
#pragma unroll
      for (int j = 0; j < 6; ++j) {
        const int col = (cg * 6 + j) * 16 + l16;
        xr[r][j] = (xr[r][j] - mu) * rs * gb[col] + bb[col];
      }
    }
  }
#pragma unroll
  for (int r = 0; r < 4; ++r) {
    const int row = bm * 32 + rg * 16 + quad * 4 + r;
    ushort* xp = XC + (size_t)row * DMODEL;
#pragma unroll
    for (int j = 0; j < 6; ++j) xp[(cg * 6 + j) * 16 + l16] = f2bf(xr[r][j]);
  }
}

// =========== fused FAVOR-K + KV accumulation (V pre-transposed) ===========
// grid (192 bh, 2 mh). Per 32-token chunk: u = K*scale @ Om_half^T (MFMA),
// phi -> PhT [128 m][32 l] (pad 40); Vts staged d-major from Vt (dbuf, group-
// swizzled src); KV += PhT @ Vts. Out KVt [bh][80 d][256 f] (d=64: ksum).
__global__ __launch_bounds__(256) void kv_fused(
    const ushort* __restrict__ qkv, const ushort* __restrict__ OmT,
    const ushort* __restrict__ Vt, ushort* __restrict__ KVt)
{
  __shared__ __align__(16) ushort Ks[32 * 64];        // 4 KB (swz8)
  __shared__ __align__(16) ushort Om[64 * 64];        // 8 KB (swz8)
  __shared__ __align__(16) ushort PhT[128 * PHTRS];   // 10 KB
  __shared__ __align__(16) ushort Vts[2][64 * 32];    // 8 KB (swz4, dbuf)
  __shared__ __align__(16) ushort Vcst[16 * 32];      // 1 KB (ksum + zero rows)
  __shared__ float offs[32];
  const int tid = threadIdx.x;
  const int bh = blockIdx.x, mh = blockIdx.y;
  const int b = bh / 3, h = bh - b * 3;
  const int wave = tid >> 6, lane = tid & 63;
  const int quad = lane >> 4, l16 = lane & 15;
  const int lr8 = lane >> 3, g8 = lane & 7;
  const int lr4 = lane >> 2, g4 = lane & 3;
#pragma unroll
  for (int t = 0; t < 2; ++t) {
    const int rb = (t * 4 + wave) * 8;
    const int row = rb + lr8;
    gll16(OmT + (size_t)(mh * 64 + row) * 64 + ((g8 ^ (row & 7)) * 8), &Om[rb * 64]);
  }
  {
    const int rowK = wave * 8 + lr8;
    gll16(qkv + (size_t)(b * 197 + rowK) * 576 + 192 + h * 64 + ((g8 ^ (rowK & 7)) * 8),
          &Ks[wave * 8 * 64]);
    const int rowV = wave * 16 + lr4;
    gll16(Vt + ((size_t)bh * 64 + rowV) * VLT + ((g4 ^ (rowV & 3)) * 8),
          &Vts[0][wave * 16 * 32]);
  }
  for (int e = tid; e < 16 * 32; e += 256) Vcst[e] = (e < 32) ? 0x3F80 : 0;
  floatx4 acc[2][5] = {};
  for (int c = 0; c < 7; ++c) {
    const int l0 = c * 32;
    const int cur = c & 1;
    __syncthreads();   // staged data ready (vmcnt0)
    if (tid < 64) {
      const int row = tid >> 1, half = tid & 1;
      float s = 0.f;
#pragma unroll
      for (int t = 0; t < 4; ++t) {
        bf16x8 v8 = *(const bf16x8*)&Ks[row * 64 + (((half * 4 + t) ^ (row & 7)) * 8)];
#pragma unroll
        for (int q = 0; q < 8; ++q) { float xv = bf2f((ushort)v8[q]); s += xv * xv; }
      }
      s += __shfl_xor(s, 1, 64);
      if (half == 0) offs[row] = 0.0625f * s;   // 0.5*scale^2 (scale^2=0.125)
    }
    floatx4 ui[2] = {};
#pragma unroll
    for (int ksb = 0; ksb < 2; ++ksb) {
      bf16x8 af[2], bfm;
#pragma unroll
      for (int i = 0; i < 2; ++i) {
        const int row = i * 16 + l16;
        af[i] = *(const bf16x8*)&Ks[row * 64 + (((quad + (ksb << 2)) ^ (row & 7)) * 8)];
      }
      {
        const int row = wave * 16 + l16;
        bfm = *(const bf16x8*)&Om[row * 64 + (((quad + (ksb << 2)) ^ (row & 7)) * 8)];
      }
#pragma unroll
      for (int i = 0; i < 2; ++i)
        ui[i] = __builtin_amdgcn_mfma_f32_16x16x32_bf16(af[i], bfm, ui[i], 0, 0, 0);
    }
    __syncthreads();   // Ks/Om reads done
    {
      const int mloc = wave * 16 + l16;
#pragma unroll
      for (int i = 0; i < 2; ++i) {
#pragma unroll
        for (int r = 0; r < 4; ++r) {
          const int ll = i * 16 + quad * 4 + r;
          float ep = 0.f, em = 0.f;
          if (l0 + ll < 197) {
            const float off = offs[ll];
            const float u = ui[i][r];
            ep = __expf(u - off) * 0.0625f;
            em = __expf(-u - off) * 0.0625f;
          }
          PhT[mloc * PHTRS + ll] = f2bf(ep);
          PhT[(64 + mloc) * PHTRS + ll] = f2bf(em);
        }
      }
    }
    if (c + 1 < 7) {   // prefetch next chunk (Ks single-buf safe; Vts dbuf)
      const int rowK = wave * 8 + lr8;
      const int lK = (c + 1) * 32 + rowK;
      gll16(qkv + (size_t)(b * 197 + lK) * 576 + 192 + h * 64 + ((g8 ^ (rowK & 7)) * 8),
            &Ks[wave * 8 * 64]);
      const int rowV = wave * 16 + lr4;
      gll16(Vt + ((size_t)bh * 64 + rowV) * VLT + (c + 1) * 32 + ((g4 ^ (rowV & 3)) * 8),
            &Vts[cur ^ 1][wave * 16 * 32]);
    }
    __syncthreads();   // PhT visible (also drains prefetch; harmless)
    bf16x8 af[2], bf[5];
#pragma unroll
    for (int i = 0; i < 2; ++i)
      af[i] = *(const bf16x8*)&PhT[(wave * 32 + i * 16 + l16) * PHTRS + quad * 8];
#pragma unroll
    for (int j = 0; j < 4; ++j) {
      const int row = j * 16 + l16;
      bf[j] = *(const bf16x8*)&Vts[cur][row * 32 + ((quad ^ (row & 3)) * 8)];
    }
    bf[4] = *(const bf16x8*)&Vcst[l16 * 32 + quad * 8];
#pragma unroll
    for (int i = 0; i < 2; ++i)
#pragma unroll
      for (int j = 0; j < 5; ++j)
        acc[i][j] = __builtin_amdgcn_mfma_f32_16x16x32_bf16(af[i], bf[j], acc[i][j], 0, 0, 0);
  }
#pragma unroll
  for (int i = 0; i < 2; ++i) {
    const int prow0 = wave * 32 + i * 16 + quad * 4;
    const int f0 = (prow0 < 64) ? (mh * 64 + prow0) : (128 + mh * 64 + prow0 - 64);
#pragma unroll
    for (int j = 0; j < 5; ++j) {
      const int d = j * 16 + l16;
      short4v pk;
#pragma unroll
      for (int r = 0; r < 4; ++r) pk[r] = (short)f2bf(acc[i][j][r]);
      *(short4v*)(KVt + ((size_t)bh * 80 + d) * 256 + f0) = pk;
    }
  }
}

// =========== fused FAVOR-Q + attn: out = Z * (phiQ @ KVt^T) ===========
// grid (4 l-tiles of 64, 192 bh) -> 768 blocks = 3/CU for barrier overlap.
__global__ __launch_bounds__(256) void attn_fused(
    const ushort* __restrict__ qkv, const ushort* __restrict__ OmT,
    const ushort* __restrict__ KVt, ushort* __restrict__ OUT)
{
  __shared__ __align__(16) ushort Phi[64 * PHIRS];   // 33 KB; [0:8K)=Qs, [8K:24K)=Om
  __shared__ __align__(16) ushort Bs[2][80 * 32];    // 10 KB (swz4)
  __shared__ float offs[64];
  __shared__ float zs[64];
  ushort* Qs = Phi;                 // 64 x 64 (swz8)
  ushort* Om = Phi + 64 * 64;       // 128 x 64 (swz8)
  const int tid = threadIdx.x;
  const int bx = blockIdx.x, bh = blockIdx.y;
  const int b = bh / 3, h = bh - b * 3;
  const int wave = tid >> 6, lane = tid & 63;
  const int quad = lane >> 4, l16 = lane & 15;
  const int lr8 = lane >> 3, g8 = lane & 7;
  const int lr4 = lane >> 2, g4 = lane & 3;
#pragma unroll
  for (int t = 0; t < 2; ++t) {
    const int rb = wave * 16 + t * 8;
    const int row = rb + lr8;
    const int l = bx * 64 + row;
    gll16(qkv + (size_t)(b * 197 + l) * 576 + h * 64 + ((g8 ^ (row & 7)) * 8), &Qs[rb * 64]);
  }
#pragma unroll
  for (int t = 0; t < 4; ++t) {
    const int rb = wave * 32 + t * 8;
    const int row = rb + lr8;
    gll16(OmT + (size_t)row * 64 + ((g8 ^ (row & 7)) * 8), &Om[rb * 64]);
  }
  __syncthreads();
  if (tid < 128) {
    const int row = tid >> 1, half = tid & 1;
    float s = 0.f;
#pragma unroll
    for (int t = 0; t < 4; ++t) {
      bf16x8 v8 = *(const bf16x8*)&Qs[row * 64 + (((half * 4 + t) ^ (row & 7)) * 8)];
#pragma unroll
      for (int q = 0; q < 8; ++q) { float xv = bf2f((ushort)v8[q]); s += xv * xv; }
    }
    s += __shfl_xor(s, 1, 64);
    if (half == 0) offs[row] = 0.0625f * s;
  }
  floatx4 uacc[8] = {};
#pragma unroll
  for (int ksb = 0; ksb < 2; ++ksb) {
    bf16x8 af, bf[8];
    {
      const int row = wave * 16 + l16;
      af = *(const bf16x8*)&Qs[row * 64 + (((quad + (ksb << 2)) ^ (row & 7)) * 8)];
    }
#pragma unroll
    for (int j = 0; j < 8; ++j) {
      const int row = j * 16 + l16;
      bf[j] = *(const bf16x8*)&Om[row * 64 + (((quad + (ksb << 2)) ^ (row & 7)) * 8)];
    }
#pragma unroll
    for (int j = 0; j < 8; ++j)
      uacc[j] = __builtin_amdgcn_mfma_f32_16x16x32_bf16(af, bf[j], uacc[j], 0, 0, 0);
  }
  __syncthreads();   // Qs/Om reads done -> Phi overwrite legal
#pragma unroll
  for (int r = 0; r < 4; ++r) {
    const int l = wave * 16 + quad * 4 + r;
    const float off = offs[l];
#pragma unroll
    for (int j = 0; j < 8; ++j) {
      const int m = j * 16 + l16;
      const float u = uacc[j][r];
      Phi[l * PHIRS + m]       = f2bf(__expf(u - off)  * 0.0625f);
      Phi[l * PHIRS + m + 128] = f2bf(__expf(-u - off) * 0.0625f);
    }
  }
  const ushort* Bp = KVt + (size_t)bh * 80 * 256;
  {
    const int row = wave * 16 + lr4;
    gll16(Bp + (size_t)row * 256 + ((g4 ^ (row & 3)) * 8), &Bs[0][wave * 16 * 32]);
    if (wave == 0)
      gll16(Bp + (size_t)(64 + lr4) * 256 + ((g4 ^ (lr4 & 3)) * 8), &Bs[0][64 * 32]);
  }
  floatx4 acc[5] = {};
  for (int c = 0; c < 8; ++c) {
    const int cur = c & 1;
    __syncthreads();   // Phi visible (c=0) + Bs staging drained + dbuf guard
    if (c + 1 < 8) {
      const int m0 = (c + 1) * 32, nxt = cur ^ 1;
      const int row = wave * 16 + lr4;
      gll16(Bp + (size_t)row * 256 + m0 + ((g4 ^ (row & 3)) * 8), &Bs[nxt][wave * 16 * 32]);
      if (wave == 0)
        gll16(Bp + (size_t)(64 + lr4) * 256 + m0 + ((g4 ^ (lr4 & 3)) * 8), &Bs[nxt][64 * 32]);
    }
    const int m0 = c * 32;
    bf16x8 af, bf[5];
    af = *(const bf16x8*)&Phi[(wave * 16 + l16) * PHIRS + m0 + quad * 8];
#pragma unroll
    for (int j = 0; j < 5; ++j) {
      const int row = j * 16 + l16;
      bf[j] = *(const bf16x8*)&Bs[cur][row * 32 + ((quad ^ (row & 3)) * 8)];
    }
#pragma unroll
    for (int j = 0; j < 5; ++j)
      acc[j] = __builtin_amdgcn_mfma_f32_16x16x32_bf16(af, bf[j], acc[j], 0, 0, 0);
  }
  if (l16 == 0) {
#pragma unroll
    for (int r = 0; r < 4; ++r)
      zs[wave * 16 + quad * 4 + r] = acc[4][r];
  }
  __syncthreads();
#pragma unroll
  for (int r = 0; r < 4; ++r) {
    const int ll = wave * 16 + quad * 4 + r;
    const int l = bx * 64 + ll;
    if (l >= 197) continue;
    const float z = 1.f / (zs[ll] + 1e-6f);
#pragma unroll
    for (int j = 0; j < 4; ++j)
      OUT[(size_t)(b * 197 + l) * 192 + h * 64 + j * 16 + l16] =
          f2bf(acc[j][r] * z);
  }
}

// ---------------- weight pre-conversion ----------------
__global__ void conv_qkv(const float* __restrict__ Wq, const float* __restrict__ Wk,
                         const float* __restrict__ Wv, const float* __restrict__ bq,
                         const float* __restrict__ bk, const float* __restrict__ bv,
                         ushort* __restrict__ dst, float* __restrict__ bdst) {
  const int l = blockIdx.y;
  const int e = blockIdx.x * 256 + threadIdx.x;   // < 576*192
  const int n = e / 192, k = e - n * 192;
  const float* src;
  if (n < 192)      src = Wq + (size_t)l * 36864 + n * 192;
  else if (n < 384) src = Wk + (size_t)l * 36864 + (n - 192) * 192;
  else              src = Wv + (size_t)l * 36864 + (n - 384) * 192;
  dst[(size_t)l * 640 * 192 + e] = f2bf(src[k]);
  if (e < 576) {
    float bvv;
    if (e < 192)      bvv = bq[l * 192 + e];
    else if (e < 384) bvv = bk[l * 192 + e - 192];
    else              bvv = bv[l * 192 + e - 384];
    bdst[l * 576 + e] = bvv;
  }
}

__global__ void conv_pad(const float* __restrict__ src, ushort* __restrict__ dst,
                         int NK, int padNK) {
  const int l = blockIdx.y;
  const int e = blockIdx.x * 256 + threadIdx.x;
  if (e < NK) dst[(size_t)l * padNK + e] = f2bf(src[(size_t)l * NK + e]);
}

// omega [l][64 d][128 m] -> OmT' [l][128 m][64 d] * sqrt(temp)
__global__ void conv_omt(const float* __restrict__ om, ushort* __restrict__ dst) {
  const int l = blockIdx.y;
  const int e = blockIdx.x * 256 + threadIdx.x;   // < 8192
  const int m = e >> 6, d = e & 63;
  dst[(size_t)l * 8192 + e] = f2bf(0.35355339059327379f * om[(size_t)l * 8192 + d * 128 + m]);
}

// head_w [j][1000 n][192 d] -> HWt [j][192 d][1000 n] (coalesced head GEMV)
__global__ void conv_headw(const float* __restrict__ src, float* __restrict__ dst) {
  const int j = blockIdx.y;
  const int e = blockIdx.x * 256 + threadIdx.x;   // < 192000
  if (e < 192000) {
    const int d = e / NCLS, n = e - d * NCLS;
    dst[(size_t)j * 192000 + e] = src[(size_t)j * 192000 + (size_t)n * DMODEL + d];
  }
}

// ---------------- im2col (fp32 in -> bf16 out) ----------------
__global__ __launch_bounds__(256) void im2col_kernel(
    const float* __restrict__ X, ushort* __restrict__ Apd)
{
  const int bp = blockIdx.x;
  const int b = bp / NPATCH, p = bp - b * NPATCH;
  const int gh = p / 14, gw = p - gh * 14;
  for (int e = threadIdx.x; e < KPATCH; e += 256) {
    const int c = e >> 8, rem = e & 255, ph = rem >> 4, pw = rem & 15;
    Apd[(size_t)bp * KPATCH + e] =
        f2bf(X[((size_t)(b * 3 + c) * 224 + gh * 16 + ph) * 224 + gw * 16 + pw]);
  }
}

// ---------------- assemble tokens ----------------
__global__ __launch_bounds__(256) void assemble_kernel(
    const ushort* __restrict__ TK, const float* __restrict__ g,
    const float* __restrict__ bt, const float* __restrict__ cls,
    const float* __restrict__ pos, ushort* __restrict__ XC)
{
  const int w = threadIdx.x >> 6, lane = threadIdx.x & 63;
  const int row = blockIdx.x * 4 + w;
  const int b = row / LLEN, l = row - b * LLEN;
  float o0, o1, o2;
  if (l == 0) {
    o0 = cls[lane]; o1 = cls[lane + 64]; o2 = cls[lane + 128];
  } else {
    const ushort* tp = TK + (size_t)(b * NPATCH + l - 1) * DMODEL;
    const float x0 = bf2f(tp[lane]), x1 = bf2f(tp[lane + 64]), x2 = bf2f(tp[lane + 128]);
    const float s  = wave_reduce_sum(x0 + x1 + x2);
    const float sq = wave_reduce_sum(x0 * x0 + x1 * x1 + x2 * x2);
    const float mu = s * (1.f / 192.f);
    const float var = sq * (1.f / 192.f) - mu * mu;
    const float rs = rsqrtf(var + 1e-5f);
    o0 = (x0 - mu) * rs * g[lane]       + bt[lane];
    o1 = (x1 - mu) * rs * g[lane + 64]  + bt[lane + 64];
    o2 = (x2 - mu) * rs * g[lane + 128] + bt[lane + 128];
  }
  o0 += pos[l * DMODEL + lane];
  o1 += pos[l * DMODEL + lane + 64];
  o2 += pos[l * DMODEL + lane + 128];
  ushort* xp = XC + (size_t)row * DMODEL;
  xp[lane] = f2bf(o0); xp[lane + 64] = f2bf(o1); xp[lane + 128] = f2bf(o2);
}

// ----- fused pool + head (per-thread class, COALESCED via transposed HWt) ----
// Round-7 per-thread version had 768 B thread-stride scatter (39.7 us); round-8
// wave-per-class had 1 class in flight per wave, latency-bound (66.7 us).
// Fix: per-thread class + HWt[d][n] transposed weights -> consecutive lanes
// read consecutive addresses (256 B/wave-load), 250 independent chains/block,
// z[d] broadcast from LDS. Same fp32 fma order over d as round-5 version.
__global__ __launch_bounds__(256) void head_kernel(
    const ushort* __restrict__ XC, const float* __restrict__ HWt,
    const float* __restrict__ HB, float* __restrict__ OUTp)
{
  __shared__ float zsh[DMODEL];
  const int b = blockIdx.y;
  const int tid = threadIdx.x;
  const int wave = tid >> 6, lane = tid & 63;
  if (wave < 3) {
    const int d = wave * 64 + lane;
    const ushort* xp = XC + (size_t)b * LLEN * DMODEL + d;
    float s = 0.f;
#pragma unroll 4
    for (int l = 0; l < LLEN; ++l) s += bf2f(xp[(size_t)l * DMODEL]);
    zsh[d] = s * (1.f / 197.f);
  }
  __syncthreads();
  const int n = blockIdx.x * 250 + tid;
  if (tid < 250 && n < NCLS) {
    float s = HB[n];
#pragma unroll 8
    for (int d = 0; d < DMODEL; ++d)
      s = fmaf(zsh[d], HWt[(size_t)d * NCLS + n], s);
    OUTp[(size_t)b * NCLS + n] = s;
  }
}

// ---------------- host orchestration ----------------
extern "C" void kernel_launch(void* const* d_in, const int* in_sizes, int n_in,
                              void* d_out, int out_size, void* d_ws, size_t ws_size,
                              hipStream_t stream) {
  const float* x        = (const float*)d_in[0];
  const float* patch_w  = (const float*)d_in[1];
  const float* patch_b  = (const float*)d_in[2];
  const float* pe_ln_g  = (const float*)d_in[3];
  const float* pe_ln_b  = (const float*)d_in[4];
  const float* cls_tok  = (const float*)d_in[5];
  const float* pos_emb  = (const float*)d_in[6];
  const float* Wq = (const float*)d_in[7];
  const float* bq = (const float*)d_in[8];
  const float* Wk = (const float*)d_in[9];
  const float* bk = (const float*)d_in[10];
  const float* Wv = (const float*)d_in[11];
  const float* bv = (const float*)d_in[12];
  const float* Wo = (const float*)d_in[13];
  const float* bo = (const float*)d_in[14];
  const float* ln1_g = (const float*)d_in[15];
  const float* ln1_b = (const float*)d_in[16];
  const float* ln2_g = (const float*)d_in[17];
  const float* ln2_b = (const float*)d_in[18];
  const float* lnb_g = (const float*)d_in[19];
  const float* lnb_b = (const float*)d_in[20];
  const float* W1 = (const float*)d_in[21];
  const float* b1 = (const float*)d_in[22];
  const float* W2 = (const float*)d_in[23];
  const float* b2 = (const float*)d_in[24];
  const float* omega  = (const float*)d_in[25];
  const float* head_w = (const float*)d_in[26];
  const float* head_b = (const float*)d_in[27];
  float* out = (float*)d_out;
  char* wsb = (char*)d_ws;

  size_t off = 0;
  auto carve = [&](size_t bytes) { size_t o = off; off += (bytes + 255) & ~(size_t)255; return o; };
  ushort* xc     = (ushort*)(wsb + carve((size_t)MPAD * 192 * 2));
  ushort* qkv    = (ushort*)(wsb + carve((size_t)MPAD * 576 * 2));
  ushort* ab     = (ushort*)(wsb + carve((size_t)MPAD * 192 * 2));
  ushort* hidden = (ushort*)(wsb + carve((size_t)MPAD * 768 * 2));   // aliases im2col
  ushort* KVt    = (ushort*)(wsb + carve((size_t)192 * 80 * 256 * 2));
  ushort* Vt     = (ushort*)(wsb + carve((size_t)192 * 64 * VLT * 2 + 1024)); // +pad for swz overrun
  float*  bqkv   = (float*)(wsb + carve((size_t)12 * 576 * 4));
  ushort* Wqkv_bf = (ushort*)(wsb + carve((size_t)12 * 640 * 192 * 2));
  ushort* Wo_bf   = (ushort*)(wsb + carve((size_t)12 * 256 * 192 * 2));
  ushort* W1_bf   = (ushort*)(wsb + carve((size_t)12 * 768 * 192 * 2));
  ushort* W2_bf   = (ushort*)(wsb + carve((size_t)12 * 256 * 768 * 2));
  ushort* Wp_bf   = (ushort*)(wsb + carve((size_t)256 * 768 * 2));
  ushort* Om_bf   = (ushort*)(wsb + carve((size_t)12 * 128 * 64 * 2));
  float*  HWt     = (float*)(wsb + carve((size_t)3 * 192 * NCLS * 4));
  ushort* i2c     = hidden;   // patch GEMM consumes before FF uses hidden

  // ---- zero Vt (pad cols l in [197,208) + swz-overrun tail must be finite 0) ----
  {
    const int n16 = (int)(((size_t)192 * 64 * VLT * 2 + 1024) / 16);
    zero_buf<<<(n16 + 255) / 256, 256, 0, stream>>>((uint4*)Vt, n16);
  }

  // ---- pre-conversion ----
  conv_qkv<<<dim3(432, 12), 256, 0, stream>>>(Wq, Wk, Wv, bq, bk, bv, Wqkv_bf, bqkv);
  conv_pad<<<dim3(144, 12), 256, 0, stream>>>(Wo, Wo_bf, 36864, 256 * 192);
  conv_pad<<<dim3(576, 12), 256, 0, stream>>>(W1, W1_bf, 147456, 768 * 192);
  conv_pad<<<dim3(576, 12), 256, 0, stream>>>(W2, W2_bf, 147456, 256 * 768);
  conv_pad<<<dim3(576, 1), 256, 0, stream>>>(patch_w, Wp_bf, 147456, 256 * 768);
  conv_omt<<<dim3(32, 12), 256, 0, stream>>>(omega, Om_bf);
  conv_headw<<<dim3(750, 3), 256, 0, stream>>>(head_w, HWt);

  // ---- patch embedding ----
  im2col_kernel<<<BPROWS, 256, 0, stream>>>(x, i2c);
  gemm_bf2<<<dim3(98, 3), 256, 0, stream>>>(i2c, KPATCH, Wp_bf, KPATCH,
      patch_b, ab, DMODEL, nullptr, KPATCH, MODE_PLAIN);
  assemble_kernel<<<BLROWS / 4, 256, 0, stream>>>(ab, pe_ln_g, pe_ln_b,
                                                  cls_tok, pos_emb, xc);

  const int exits[3] = {3, 7, 11};
  for (int i = 0; i < NDEPTH; ++i) {
    // QKV: 128x64 tiles, N=576 -> 9 N-tiles, 891 blocks; V -> Vt
    gemm_bf2<<<dim3(99, 9), 256, 0, stream>>>(xc, DMODEL,
        Wqkv_bf + (size_t)i * 640 * 192, DMODEL, bqkv + i * 576,
        qkv, 576, Vt, DMODEL, MODE_QKV);
    // fused FAVOR-K + KV (V pre-transposed)
    kv_fused<<<dim3(192, 2), 256, 0, stream>>>(qkv,
        Om_bf + (size_t)i * 8192, Vt, KVt);
    // fused FAVOR-Q + attn (64-row tiles, 768 blocks)
    attn_fused<<<dim3(4, 192), 256, 0, stream>>>(qkv,
        Om_bf + (size_t)i * 8192, KVt, ab);
    // O-proj + bias + residual + LN1, fused (32-row tiles, 396 blocks)
    gemm_ln<<<MPAD / 32, 256, 0, stream>>>(ab, DMODEL,
        Wo_bf + (size_t)i * 256 * 192, DMODEL, bo + i * DMODEL, xc,
        ln1_g + i * DMODEL, ln1_b + i * DMODEL, nullptr, nullptr,
        DMODEL, 0);
    // W1: 128x64 tiles, N=768 -> 12 N-tiles, 1188 blocks
    gemm_bf2<<<dim3(99, 12), 256, 0, stream>>>(xc, DMODEL,
        W1_bf + (size_t)i * 768 * 192, DMODEL, b1 + i * FFDIM,
        hidden, FFDIM, nullptr, DMODEL, MODE_RELU);
    // W2 + bias + residual + LN2 + LNb, fused (32-row tiles, 396 blocks)
    gemm_ln<<<MPAD / 32, 256, 0, stream>>>(hidden, FFDIM,
        W2_bf + (size_t)i * 256 * 768, FFDIM, b2 + i * DMODEL, xc,
        ln2_g + i * DMODEL, ln2_b + i * DMODEL,
        lnb_g + i * DMODEL, lnb_b + i * DMODEL,
        FFDIM, 1);

    for (int j = 0; j < 3; ++j) {
      if (i == exits[j]) {
        head_kernel<<<dim3(4, BB), 256, 0, stream>>>(
            xc, HWt + (size_t)j * 192 * NCLS, head_b + (size_t)j * NCLS,
            out + (size_t)j * BB * NCLS);
      }
    }
  }
}

// Round 10
// 1302.722 us; speedup vs baseline: 1.3031x; 1.0167x over previous
//
#include <hip/hip_runtime.h>
#include <math.h>

// ---------------- problem constants ----------------
#define BB     64
#define LLEN   197
#define BLROWS 12608      // BB*LLEN
#define MPAD   12672      // BLROWS padded to 99*128 (= 396*32)
#define DMODEL 192
#define NHEAD  3
#define DHEAD  64
#define M2FEAT 256
#define FFDIM  768
#define NDEPTH 12
#define NCLS   1000
#define NPATCH 196
#define BPROWS 12544      // BB*NPATCH (= 98*128 exactly)
#define KPATCH 768
#define PHIRS  264        // Phi LDS row stride (256 + 8 pad, 16B-aligned)
#define PHTRS  40         // PhT LDS row stride (32 + 8 pad, 16B-aligned)
#define VLT    208        // Vt row length (197 padded, 16B-aligned)

#define MODE_PLAIN 0
#define MODE_RELU  1
#define MODE_QKV   2      // cols<384 -> qkv; cols>=384 -> transposed Vt

typedef unsigned short ushort;
typedef __attribute__((ext_vector_type(8))) short bf16x8;
typedef __attribute__((ext_vector_type(4))) float floatx4;
typedef __attribute__((ext_vector_type(4))) short short4v;

__device__ __forceinline__ float wave_reduce_sum(float v) {
#pragma unroll
  for (int s = 32; s > 0; s >>= 1) v += __shfl_xor(v, s, 64);
  return v;
}
__device__ __forceinline__ ushort f2bf(float f) {  // RNE fp32->bf16
  unsigned u = __float_as_uint(f);
  return (ushort)((u + 0x7fffu + ((u >> 16) & 1u)) >> 16);
}
__device__ __forceinline__ float bf2f(ushort u) {
  return __uint_as_float(((unsigned)u) << 16);
}
// async global->LDS, 16 B per lane; LDS dest wave-uniform (HW adds lane*16);
// global src is PER-LANE -> swizzled LDS layouts via pre-swizzled src (T2).
__device__ __forceinline__ void gll16(const ushort* g, ushort* l) {
  __builtin_amdgcn_global_load_lds(
      (const __attribute__((address_space(1))) void*)g,
      (__attribute__((address_space(3))) void*)l, 16, 0, 0);
}

__global__ void zero_buf(uint4* __restrict__ p, int n16) {
  const int i = blockIdx.x * 256 + threadIdx.x;
  if (i < n16) p[i] = uint4{0, 0, 0, 0};
}

// ====== bf16 GEMM, 128x64 tile, BK=64, dbuf LDS, swz8 (all wide GEMMs) ======
// block 256 = 4 waves (2x2 of 64x32), 48 KB LDS -> 3 blocks/CU for drain
// overlap. bias (+relu) out. MODE_QKV: cols<384 -> qkv; [384,576) -> Vt[bh][d][l].
// (round-5 verified version; W-in-regs variant regressed: uncoalesced 384B-
//  strided per-lane loads — keep W staged via coalesced gll16.)
__global__ __launch_bounds__(256) void gemm_bf2(
    const ushort* __restrict__ A, int lda,
    const ushort* __restrict__ W, int ldw,
    const float* __restrict__ bias,
    ushort* __restrict__ C, int ldc, ushort* __restrict__ Vt,
    int Kdim, int mode)
{
  __shared__ __align__(16) ushort As[2][128 * 64];   // 32 KB
  __shared__ __align__(16) ushort Ws[2][64 * 64];    // 16 KB
  const int tid = threadIdx.x;
  const int bm = blockIdx.x, bn = blockIdx.y;
  const int wave = tid >> 6, lane = tid & 63;
  const int wm = (wave >> 1) * 64, wn = (wave & 1) * 32;
  const int quad = lane >> 4, l16 = lane & 15;
  const int srow = lane >> 3;                 // 0..7 within an 8-row stage call
  const int scol = ((lane & 7) ^ srow) * 8;   // swizzled source col group
  const ushort* Ap = A + (size_t)(bm * 128) * lda;
  const ushort* Wp = W + (size_t)(bn * 64) * ldw;
  floatx4 acc[4][2] = {};
  const int nT = Kdim >> 6;
#pragma unroll
  for (int t = 0; t < 4; ++t) {
    const int rb = (t * 4 + wave) * 8;
    gll16(Ap + (size_t)(rb + srow) * lda + scol, &As[0][rb * 64]);
  }
#pragma unroll
  for (int t = 0; t < 2; ++t) {
    const int rb = (t * 4 + wave) * 8;
    gll16(Wp + (size_t)(rb + srow) * ldw + scol, &Ws[0][rb * 64]);
  }
  for (int kt = 0; kt < nT; ++kt) {
    const int cur = kt & 1;
    __syncthreads();                 // drains prefetch(kt) (vmcnt0) + buf reuse
    if (kt + 1 < nT) {
      const int kk = (kt + 1) * 64, nxt = cur ^ 1;
#pragma unroll
      for (int t = 0; t < 4; ++t) {
        const int rb = (t * 4 + wave) * 8;
        gll16(Ap + (size_t)(rb + srow) * lda + kk + scol, &As[nxt][rb * 64]);
      }
#pragma unroll
      for (int t = 0; t < 2; ++t) {
        const int rb = (t * 4 + wave) * 8;
        gll16(Wp + (size_t)(rb + srow) * ldw + kk + scol, &Ws[nxt][rb * 64]);
      }
    }
#pragma unroll
    for (int ks = 0; ks < 2; ++ks) {
      bf16x8 af[4], bf[2];
#pragma unroll
      for (int i = 0; i < 4; ++i) {
        const int ra = wm + i * 16 + l16;
        af[i] = *(const bf16x8*)&As[cur][ra * 64 + ((((ks << 2) | quad) ^ (ra & 7)) * 8)];
      }
#pragma unroll
      for (int j = 0; j < 2; ++j) {
        const int rw = wn + j * 16 + l16;
        bf[j] = *(const bf16x8*)&Ws[cur][rw * 64 + ((((ks << 2) | quad) ^ (rw & 7)) * 8)];
      }
#pragma unroll
      for (int i = 0; i < 4; ++i)
#pragma unroll
        for (int j = 0; j < 2; ++j)
          acc[i][j] = __builtin_amdgcn_mfma_f32_16x16x32_bf16(af[i], bf[j], acc[i][j], 0, 0, 0);
    }
  }
  if (mode == MODE_QKV) {
#pragma unroll
    for (int i = 0; i < 4; ++i)
#pragma unroll
      for (int r = 0; r < 4; ++r) {
        const int grow = bm * 128 + wm + i * 16 + quad * 4 + r;
        const int bidx = grow / 197;           // magic-mul
        const int lloc = grow - bidx * 197;
#pragma unroll
        for (int j = 0; j < 2; ++j) {
          const int col = bn * 64 + wn + j * 16 + l16;
          const float o = acc[i][j][r] + bias[col];
          if (col < 384) {
            C[(size_t)grow * ldc + col] = f2bf(o);
          } else if (grow < BLROWS) {
            const int h = (col - 384) >> 6, d = (col - 384) & 63;
            Vt[((size_t)(bidx * 3 + h) * 64 + d) * VLT + lloc] = f2bf(o);
          }
        }
      }
  } else {
#pragma unroll
    for (int j = 0; j < 2; ++j) {
      const int col = bn * 64 + wn + j * 16 + l16;
      const float bv = bias[col];
#pragma unroll
      for (int i = 0; i < 4; ++i)
#pragma unroll
        for (int r = 0; r < 4; ++r) {
          const int grow = bm * 128 + wm + i * 16 + quad * 4 + r;
          float o = acc[i][j][r] + bv;
          if (mode == MODE_RELU) o = fmaxf(o, 0.f);
          C[(size_t)grow * ldc + col] = f2bf(o);
        }
    }
  }
}

// ====== fused GEMM + bias + residual + LayerNorm(x1 or x2), BK=64, swz8 ======
// Tile 32 rows x 192 cols -> 396 blocks (round-5 verified sweet spot: 16-row/
// 792-block variant regressed — W-staging per block is fixed, so halving rows
// doubles total W LDS-staging traffic; 64-row/198-block under-occupies CUs).
// 4 waves: rg=wave>>1 picks row half (16 rows), cg=wave&1 picks col half
// (96 cols, 6 n-tiles -> acc[6]). Row LN = quad shfl + cross-wave LDS partial
// combine (2 extra barriers total). Writes XC in place.
__global__ __launch_bounds__(256) void gemm_ln(
    const ushort* __restrict__ A, int lda,
    const ushort* __restrict__ W, int ldw,
    const float* __restrict__ bias,
    ushort* __restrict__ XC,
    const float* __restrict__ ga, const float* __restrict__ ba,
    const float* __restrict__ gb, const float* __restrict__ bb,
    int Kdim, int dln)
{
  __shared__ __align__(16) ushort As[2][32 * 64];    // 8 KB
  __shared__ __align__(16) ushort Ws[2][192 * 64];   // 48 KB
  __shared__ float p1s[2][32], p1q[2][32], p2s[2][32], p2q[2][32];
  const int tid = threadIdx.x;
  const int bm = blockIdx.x;
  const int wave = tid >> 6, lane = tid & 63;
  const int rg = wave >> 1, cg = wave & 1;
  const int quad = lane >> 4, l16 = lane & 15;
  const int srow = lane >> 3;
  const int scol = ((lane & 7) ^ srow) * 8;
  const ushort* Ap = A + (size_t)(bm * 32) * lda;
  floatx4 acc[6] = {};
  const int nT = Kdim >> 6;
  gll16(Ap + (size_t)(wave * 8 + srow) * lda + scol, &As[0][wave * 8 * 64]);
#pragma unroll
  for (int t = 0; t < 6; ++t) {
    const int rb = (t * 4 + wave) * 8;
    gll16(W + (size_t)(rb + srow) * ldw + scol, &Ws[0][rb * 64]);
  }
  for (int kt = 0; kt < nT; ++kt) {
    const int cur = kt & 1;
    __syncthreads();
    if (kt + 1 < nT) {
      const int kk = (kt + 1) * 64, nxt = cur ^ 1;
      gll16(Ap + (size_t)(wave * 8 + srow) * lda + kk + scol, &As[nxt][wave * 8 * 64]);
#pragma unroll
      for (int t = 0; t < 6; ++t) {
        const int rb = (t * 4 + wave) * 8;
        gll16(W + (size_t)(rb + srow) * ldw + kk + scol, &Ws[nxt][rb * 64]);
      }
    }
#pragma unroll
    for (int ks = 0; ks < 2; ++ks) {
      const int ra = rg * 16 + l16;
      const bf16x8 af = *(const bf16x8*)&As[cur][ra * 64 + ((((ks << 2) | quad) ^ (ra & 7)) * 8)];
#pragma unroll
      for (int j = 0; j < 6; ++j) {
        const int rw = (cg * 6 + j) * 16 + l16;
        const bf16x8 bf = *(const bf16x8*)&Ws[cur][rw * 64 + ((((ks << 2) | quad) ^ (rw & 7)) * 8)];
        acc[j] = __builtin_amdgcn_mfma_f32_16x16x32_bf16(af, bf, acc[j], 0, 0, 0);
      }
    }
  }
  // ---- epilogue: bias + residual; LN via quad-shfl + cross-wave combine ----
  float xr[4][6];
#pragma unroll
  for (int r = 0; r < 4; ++r) {
    const int rloc = rg * 16 + quad * 4 + r;
    const int row = bm * 32 + rloc;
    const ushort* xp = XC + (size_t)row * DMODEL;
    float s = 0.f, sq = 0.f;
#pragma unroll
    for (int j = 0; j < 6; ++j) {
      const int col = (cg * 6 + j) * 16 + l16;
      const float o = acc[j][r] + bias[col] + bf2f(xp[col]);
      xr[r][j] = o; s += o; sq += o * o;
    }
#pragma unroll
    for (int m = 1; m < 16; m <<= 1) {
      s += __shfl_xor(s, m, 64); sq += __shfl_xor(sq, m, 64);
    }
    if (l16 == 0) { p1s[cg][rloc] = s; p1q[cg][rloc] = sq; }
  }
  __syncthreads();
#pragma unroll
  for (int r = 0; r < 4; ++r) {
    const int rloc = rg * 16 + quad * 4 + r;
    const float s = p1s[0][rloc] + p1s[1][rloc];
    const float sq = p1q[0][rloc] + p1q[1][rloc];
    const float mu = s * (1.f / 192.f);
    const float var = sq * (1.f / 192.f) - mu * mu;
    const float rs = rsqrtf(var + 1e-5f);
#pragma unroll
    for (int j = 0; j < 6; ++j) {
      const int col = (cg * 6 + j) * 16 + l16;
      xr[r][j] = (xr[r][j] - mu) * rs * ga[col] + ba[col];
    }
  }
  if (dln) {
#pragma unroll
    for (int r = 0; r < 4; ++r) {
      const int rloc = rg * 16 + quad * 4 + r;
      float s = 0.f, sq = 0.f;
#pragma unroll
      for (int j = 0; j < 6; ++j) { s += xr[r][j]; sq += xr[r][j] * xr[r][j]; }
#pragma unroll
      for (int m = 1; m < 16; m <<= 1) {
        s += __shfl_xor(s, m, 64); sq += __shfl_xor(sq, m, 64);
      }
      if (l16 == 0) { p2s[cg][rloc] = s; p2q[cg][rloc] = sq; }
    }
    __syncthreads();
#pragma unroll
    for (int r = 0; r < 4; ++r) {
      const int rloc = rg * 16 + quad * 4 + r;
      const float s = p2s[0][rloc] + p2s[1][rloc];
      const float sq = p2q[0][rloc] + p2q[1][rloc];
      const float mu = s * (1.f / 192.f);
      const float var = sq * (1.f / 192.f) - mu * mu;
      const float rs = rsqrtf(var + 1e-5f);
#pragma unroll
      for (int j = 0; j < 6; ++j) {
        const int col = (cg * 6 + j) * 16 + l16;
        xr[r][j] = (xr[r][j] - mu) * rs * gb[col] + bb[col];
      }
    }
  }
#pragma unroll
  for (int r = 0; r < 4; ++r) {
    const int row = bm * 32 + rg * 16 + quad * 4 + r;
    ushort* xp = XC + (size_t)row * DMODEL;
#pragma unroll
    for (int j = 0; j < 6; ++j) xp[(cg * 6 + j) * 16 + l16] = f2bf(xr[r][j]);
  }
}

// =========== fused FAVOR-K + KV accumulation (V pre-transposed) ===========
// grid (192 bh, 2 mh). Per 32-token chunk: u = K*scale @ Om_half^T (MFMA),
// phi -> PhT [128 m][32 l] (pad 40); Vts staged d-major from Vt (dbuf, group-
// swizzled src); KV += PhT @ Vts. Out KVt [bh][80 d][256 f] (d=64: ksum).
__global__ __launch_bounds__(256) void kv_fused(
    const ushort* __restrict__ qkv, const ushort* __restrict__ OmT,
    const ushort* __restrict__ Vt, ushort* __restrict__ KVt)
{
  __shared__ __align__(16) ushort Ks[32 * 64];        // 4 KB (swz8)
  __shared__ __align__(16) ushort Om[64 * 64];        // 8 KB (swz8)
  __shared__ __align__(16) ushort PhT[128 * PHTRS];   // 10 KB
  __shared__ __align__(16) ushort Vts[2][64 * 32];    // 8 KB (swz4, dbuf)
  __shared__ __align__(16) ushort Vcst[16 * 32];      // 1 KB (ksum + zero rows)
  __shared__ float offs[32];
  const int tid = threadIdx.x;
  const int bh = blockIdx.x, mh = blockIdx.y;
  const int b = bh / 3, h = bh - b * 3;
  const int wave = tid >> 6, lane = tid & 63;
  const int quad = lane >> 4, l16 = lane & 15;
  const int lr8 = lane >> 3, g8 = lane & 7;
  const int lr4 = lane >> 2, g4 = lane & 3;
#pragma unroll
  for (int t = 0; t < 2; ++t) {
    const int rb = (t * 4 + wave) * 8;
    const int row = rb + lr8;
    gll16(OmT + (size_t)(mh * 64 + row) * 64 + ((g8 ^ (row & 7)) * 8), &Om[rb * 64]);
  }
  {
    const int rowK = wave * 8 + lr8;
    gll16(qkv + (size_t)(b * 197 + rowK) * 576 + 192 + h * 64 + ((g8 ^ (rowK & 7)) * 8),
          &Ks[wave * 8 * 64]);
    const int rowV = wave * 16 + lr4;
    gll16(Vt + ((size_t)bh * 64 + rowV) * VLT + ((g4 ^ (rowV & 3)) * 8),
          &Vts[0][wave * 16 * 32]);
  }
  for (int e = tid; e < 16 * 32; e += 256) Vcst[e] = (e < 32) ? 0x3F80 : 0;
  floatx4 acc[2][5] = {};
  for (int c = 0; c < 7; ++c) {
    const int l0 = c * 32;
    const int cur = c & 1;
    __syncthreads();   // staged data ready (vmcnt0)
    if (tid < 64) {
      const int row = tid >> 1, half = tid & 1;
      float s = 0.f;
#pragma unroll
      for (int t = 0; t < 4; ++t) {
        bf16x8 v8 = *(const bf16x8*)&Ks[row * 64 + (((half * 4 + t) ^ (row & 7)) * 8)];
#pragma unroll
        for (int q = 0; q < 8; ++q) { float xv = bf2f((ushort)v8[q]); s += xv * xv; }
      }
      s += __shfl_xor(s, 1, 64);
      if (half == 0) offs[row] = 0.0625f * s;   // 0.5*scale^2 (scale^2=0.125)
    }
    floatx4 ui[2] = {};
#pragma unroll
    for (int ksb = 0; ksb < 2; ++ksb) {
      bf16x8 af[2], bfm;
#pragma unroll
      for (int i = 0; i < 2; ++i) {
        const int row = i * 16 + l16;
        af[i] = *(const bf16x8*)&Ks[row * 64 + (((quad + (ksb << 2)) ^ (row & 7)) * 8)];
      }
      {
        const int row = wave * 16 + l16;
        bfm = *(const bf16x8*)&Om[row * 64 + (((quad + (ksb << 2)) ^ (row & 7)) * 8)];
      }
#pragma unroll
      for (int i = 0; i < 2; ++i)
        ui[i] = __builtin_amdgcn_mfma_f32_16x16x32_bf16(af[i], bfm, ui[i], 0, 0, 0);
    }
    __syncthreads();   // Ks/Om reads done
    {
      const int mloc = wave * 16 + l16;
#pragma unroll
      for (int i = 0; i < 2; ++i) {
#pragma unroll
        for (int r = 0; r < 4; ++r) {
          const int ll = i * 16 + quad * 4 + r;
          float ep = 0.f, em = 0.f;
          if (l0 + ll < 197) {
            const float off = offs[ll];
            const float u = ui[i][r];
            ep = __expf(u - off) * 0.0625f;
            em = __expf(-u - off) * 0.0625f;
          }
          PhT[mloc * PHTRS + ll] = f2bf(ep);
          PhT[(64 + mloc) * PHTRS + ll] = f2bf(em);
        }
      }
    }
    if (c + 1 < 7) {   // prefetch next chunk (Ks single-buf safe; Vts dbuf)
      const int rowK = wave * 8 + lr8;
      const int lK = (c + 1) * 32 + rowK;
      gll16(qkv + (size_t)(b * 197 + lK) * 576 + 192 + h * 64 + ((g8 ^ (rowK & 7)) * 8),
            &Ks[wave * 8 * 64]);
      const int rowV = wave * 16 + lr4;
      gll16(Vt + ((size_t)bh * 64 + rowV) * VLT + (c + 1) * 32 + ((g4 ^ (rowV & 3)) * 8),
            &Vts[cur ^ 1][wave * 16 * 32]);
    }
    __syncthreads();   // PhT visible (also drains prefetch; harmless)
    bf16x8 af[2], bf[5];
#pragma unroll
    for (int i = 0; i < 2; ++i)
      af[i] = *(const bf16x8*)&PhT[(wave * 32 + i * 16 + l16) * PHTRS + quad * 8];
#pragma unroll
    for (int j = 0; j < 4; ++j) {
      const int row = j * 16 + l16;
      bf[j] = *(const bf16x8*)&Vts[cur][row * 32 + ((quad ^ (row & 3)) * 8)];
    }
    bf[4] = *(const bf16x8*)&Vcst[l16 * 32 + quad * 8];
#pragma unroll
    for (int i = 0; i < 2; ++i)
#pragma unroll
      for (int j = 0; j < 5; ++j)
        acc[i][j] = __builtin_amdgcn_mfma_f32_16x16x32_bf16(af[i], bf[j], acc[i][j], 0, 0, 0);
  }
#pragma unroll
  for (int i = 0; i < 2; ++i) {
    const int prow0 = wave * 32 + i * 16 + quad * 4;
    const int f0 = (prow0 < 64) ? (mh * 64 + prow0) : (128 + mh * 64 + prow0 - 64);
#pragma unroll
    for (int j = 0; j < 5; ++j) {
      const int d = j * 16 + l16;
      short4v pk;
#pragma unroll
      for (int r = 0; r < 4; ++r) pk[r] = (short)f2bf(acc[i][j][r]);
      *(short4v*)(KVt + ((size_t)bh * 80 + d) * 256 + f0) = pk;
    }
  }
}

// =========== fused FAVOR-Q + attn: out = Z * (phiQ @ KVt^T) ===========
// grid (4 l-tiles of 64, 192 bh) -> 768 blocks = 3/CU for barrier overlap.
__global__ __launch_bounds__(256) void attn_fused(
    const ushort* __restrict__ qkv, const ushort* __restrict__ OmT,
    const ushort* __restrict__ KVt, ushort* __restrict__ OUT)
{
  __shared__ __align__(16) ushort Phi[64 * PHIRS];   // 33 KB; [0:8K)=Qs, [8K:24K)=Om
  __shared__ __align__(16) ushort Bs[2][80 * 32];    // 10 KB (swz4)
  __shared__ float offs[64];
  __shared__ float zs[64];
  ushort* Qs = Phi;                 // 64 x 64 (swz8)
  ushort* Om = Phi + 64 * 64;       // 128 x 64 (swz8)
  const int tid = threadIdx.x;
  const int bx = blockIdx.x, bh = blockIdx.y;
  const int b = bh / 3, h = bh - b * 3;
  const int wave = tid >> 6, lane = tid & 63;
  const int quad = lane >> 4, l16 = lane & 15;
  const int lr8 = lane >> 3, g8 = lane & 7;
  const int lr4 = lane >> 2, g4 = lane & 3;
#pragma unroll
  for (int t = 0; t < 2; ++t) {
    const int rb = wave * 16 + t * 8;
    const int row = rb + lr8;
    const int l = bx * 64 + row;
    gll16(qkv + (size_t)(b * 197 + l) * 576 + h * 64 + ((g8 ^ (row & 7)) * 8), &Qs[rb * 64]);
  }
#pragma unroll
  for (int t = 0; t < 4; ++t) {
    const int rb = wave * 32 + t * 8;
    const int row = rb + lr8;
    gll16(OmT + (size_t)row * 64 + ((g8 ^ (row & 7)) * 8), &Om[rb * 64]);
  }
  __syncthreads();
  if (tid < 128) {
    const int row = tid >> 1, half = tid & 1;
    float s = 0.f;
#pragma unroll
    for (int t = 0; t < 4; ++t) {
      bf16x8 v8 = *(const bf16x8*)&Qs[row * 64 + (((half * 4 + t) ^ (row & 7)) * 8)];
#pragma unroll
      for (int q = 0; q < 8; ++q) { float xv = bf2f((ushort)v8[q]); s += xv * xv; }
    }
    s += __shfl_xor(s, 1, 64);
    if (half == 0) offs[row] = 0.0625f * s;
  }
  floatx4 uacc[8] = {};
#pragma unroll
  for (int ksb = 0; ksb < 2; ++ksb) {
    bf16x8 af, bf[8];
    {
      const int row = wave * 16 + l16;
      af = *(const bf16x8*)&Qs[row * 64 + (((quad + (ksb << 2)) ^ (row & 7)) * 8)];
    }
#pragma unroll
    for (int j = 0; j < 8; ++j) {
      const int row = j * 16 + l16;
      bf[j] = *(const bf16x8*)&Om[row * 64 + (((quad + (ksb << 2)) ^ (row & 7)) * 8)];
    }
#pragma unroll
    for (int j = 0; j < 8; ++j)
      uacc[j] = __builtin_amdgcn_mfma_f32_16x16x32_bf16(af, bf[j], uacc[j], 0, 0, 0);
  }
  __syncthreads();   // Qs/Om reads done -> Phi overwrite legal
#pragma unroll
  for (int r = 0; r < 4; ++r) {
    const int l = wave * 16 + quad * 4 + r;
    const float off = offs[l];
#pragma unroll
    for (int j = 0; j < 8; ++j) {
      const int m = j * 16 + l16;
      const float u = uacc[j][r];
      Phi[l * PHIRS + m]       = f2bf(__expf(u - off)  * 0.0625f);
      Phi[l * PHIRS + m + 128] = f2bf(__expf(-u - off) * 0.0625f);
    }
  }
  const ushort* Bp = KVt + (size_t)bh * 80 * 256;
  {
    const int row = wave * 16 + lr4;
    gll16(Bp + (size_t)row * 256 + ((g4 ^ (row & 3)) * 8), &Bs[0][wave * 16 * 32]);
    if (wave == 0)
      gll16(Bp + (size_t)(64 + lr4) * 256 + ((g4 ^ (lr4 & 3)) * 8), &Bs[0][64 * 32]);
  }
  floatx4 acc[5] = {};
  for (int c = 0; c < 8; ++c) {
    const int cur = c & 1;
    __syncthreads();   // Phi visible (c=0) + Bs staging drained + dbuf guard
    if (c + 1 < 8) {
      const int m0 = (c + 1) * 32, nxt = cur ^ 1;
      const int row = wave * 16 + lr4;
      gll16(Bp + (size_t)row * 256 + m0 + ((g4 ^ (row & 3)) * 8), &Bs[nxt][wave * 16 * 32]);
      if (wave == 0)
        gll16(Bp + (size_t)(64 + lr4) * 256 + m0 + ((g4 ^ (lr4 & 3)) * 8), &Bs[nxt][64 * 32]);
    }
    const int m0 = c * 32;
    bf16x8 af, bf[5];
    af = *(const bf16x8*)&Phi[(wave * 16 + l16) * PHIRS + m0 + quad * 8];
#pragma unroll
    for (int j = 0; j < 5; ++j) {
      const int row = j * 16 + l16;
      bf[j] = *(const bf16x8*)&Bs[cur][row * 32 + ((quad ^ (row & 3)) * 8)];
    }
#pragma unroll
    for (int j = 0; j < 5; ++j)
      acc[j] = __builtin_amdgcn_mfma_f32_16x16x32_bf16(af, bf[j], acc[j], 0, 0, 0);
  }
  if (l16 == 0) {
#pragma unroll
    for (int r = 0; r < 4; ++r)
      zs[wave * 16 + quad * 4 + r] = acc[4][r];
  }
  __syncthreads();
#pragma unroll
  for (int r = 0; r < 4; ++r) {
    const int ll = wave * 16 + quad * 4 + r;
    const int l = bx * 64 + ll;
    if (l >= 197) continue;
    const float z = 1.f / (zs[ll] + 1e-6f);
#pragma unroll
    for (int j = 0; j < 4; ++j)
      OUT[(size_t)(b * 197 + l) * 192 + h * 64 + j * 16 + l16] =
          f2bf(acc[j][r] * z);
  }
}

// ---------------- weight pre-conversion ----------------
__global__ void conv_qkv(const float* __restrict__ Wq, const float* __restrict__ Wk,
                         const float* __restrict__ Wv, const float* __restrict__ bq,
                         const float* __restrict__ bk, const float* __restrict__ bv,
                         ushort* __restrict__ dst, float* __restrict__ bdst) {
  const int l = blockIdx.y;
  const int e = blockIdx.x * 256 + threadIdx.x;   // < 576*192
  const int n = e / 192, k = e - n * 192;
  const float* src;
  if (n < 192)      src = Wq + (size_t)l * 36864 + n * 192;
  else if (n < 384) src = Wk + (size_t)l * 36864 + (n - 192) * 192;
  else              src = Wv + (size_t)l * 36864 + (n - 384) * 192;
  dst[(size_t)l * 640 * 192 + e] = f2bf(src[k]);
  if (e < 576) {
    float bvv;
    if (e < 192)      bvv = bq[l * 192 + e];
    else if (e < 384) bvv = bk[l * 192 + e - 192];
    else              bvv = bv[l * 192 + e - 384];
    bdst[l * 576 + e] = bvv;
  }
}

__global__ void conv_pad(const float* __restrict__ src, ushort* __restrict__ dst,
                         int NK, int padNK) {
  const int l = blockIdx.y;
  const int e = blockIdx.x * 256 + threadIdx.x;
  if (e < NK) dst[(size_t)l * padNK + e] = f2bf(src[(size_t)l * NK + e]);
}

// omega [l][64 d][128 m] -> OmT' [l][128 m][64 d] * sqrt(temp)
__global__ void conv_omt(const float* __restrict__ om, ushort* __restrict__ dst) {
  const int l = blockIdx.y;
  const int e = blockIdx.x * 256 + threadIdx.x;   // < 8192
  const int m = e >> 6, d = e & 63;
  dst[(size_t)l * 8192 + e] = f2bf(0.35355339059327379f * om[(size_t)l * 8192 + d * 128 + m]);
}

// head_w [j][1000 n][192 d] -> HWt [j][192 d][1000 n] (coalesced head GEMV)
__global__ void conv_headw(const float* __restrict__ src, float* __restrict__ dst) {
  const int j = blockIdx.y;
  const int e = blockIdx.x * 256 + threadIdx.x;   // < 192000
  if (e < 192000) {
    const int d = e / NCLS, n = e - d * NCLS;
    dst[(size_t)j * 192000 + e] = src[(size_t)j * 192000 + (size_t)n * DMODEL + d];
  }
}

// ---------------- im2col (fp32 in -> bf16 out) ----------------
__global__ __launch_bounds__(256) void im2col_kernel(
    const float* __restrict__ X, ushort* __restrict__ Apd)
{
  const int bp = blockIdx.x;
  const int b = bp / NPATCH, p = bp - b * NPATCH;
  const int gh = p / 14, gw = p - gh * 14;
  for (int e = threadIdx.x; e < KPATCH; e += 256) {
    const int c = e >> 8, rem = e & 255, ph = rem >> 4, pw = rem & 15;
    Apd[(size_t)bp * KPATCH + e] =
        f2bf(X[((size_t)(b * 3 + c) * 224 + gh * 16 + ph) * 224 + gw * 16 + pw]);
  }
}

// ---------------- assemble tokens ----------------
__global__ __launch_bounds__(256) void assemble_kernel(
    const ushort* __restrict__ TK, const float* __restrict__ g,
    const float* __restrict__ bt, const float* __restrict__ cls,
    const float* __restrict__ pos, ushort* __restrict__ XC)
{
  const int w = threadIdx.x >> 6, lane = threadIdx.x & 63;
  const int row = blockIdx.x * 4 + w;
  const int b = row / LLEN, l = row - b * LLEN;
  float o0, o1, o2;
  if (l == 0) {
    o0 = cls[lane]; o1 = cls[lane + 64]; o2 = cls[lane + 128];
  } else {
    const ushort* tp = TK + (size_t)(b * NPATCH + l - 1) * DMODEL;
    const float x0 = bf2f(tp[lane]), x1 = bf2f(tp[lane + 64]), x2 = bf2f(tp[lane + 128]);
    const float s  = wave_reduce_sum(x0 + x1 + x2);
    const float sq = wave_reduce_sum(x0 * x0 + x1 * x1 + x2 * x2);
    const float mu = s * (1.f / 192.f);
    const float var = sq * (1.f / 192.f) - mu * mu;
    const float rs = rsqrtf(var + 1e-5f);
    o0 = (x0 - mu) * rs * g[lane]       + bt[lane];
    o1 = (x1 - mu) * rs * g[lane + 64]  + bt[lane + 64];
    o2 = (x2 - mu) * rs * g[lane + 128] + bt[lane + 128];
  }
  o0 += pos[l * DMODEL + lane];
  o1 += pos[l * DMODEL + lane + 64];
  o2 += pos[l * DMODEL + lane + 128];
  ushort* xp = XC + (size_t)row * DMODEL;
  xp[lane] = f2bf(o0); xp[lane + 64] = f2bf(o1); xp[lane + 128] = f2bf(o2);
}

// ----- fused pool + head (4-wave-parallel pool + coalesced HWt GEMV) --------
// Pool was the hidden cost (r8/r9 post-mortem): 3 waves x 197 SERIAL strided
// loads, recomputed by all 4 class-blocks. Now all 4 waves each sum ~50 rows
// (lane d holds cols d/d+64/d+128: 3 independent chains, coalesced 128 B
// wave-reads), then 4-way LDS partial combine. GEMV part unchanged (verified
// coalesced via transposed HWt).
__global__ __launch_bounds__(256) void head_kernel(
    const ushort* __restrict__ XC, const float* __restrict__ HWt,
    const float* __restrict__ HB, float* __restrict__ OUTp)
{
  __shared__ float part[4][DMODEL];
  __shared__ float zsh[DMODEL];
  const int b = blockIdx.y;
  const int tid = threadIdx.x;
  const int wave = tid >> 6, lane = tid & 63;
  {
    const int l0 = wave * 50;
    const int l1 = (l0 + 50 < LLEN) ? l0 + 50 : LLEN;
    const ushort* xp = XC + ((size_t)b * LLEN + l0) * DMODEL;
    float s0 = 0.f, s1 = 0.f, s2 = 0.f;
    for (int l = l0; l < l1; ++l) {
      s0 += bf2f(xp[lane]);
      s1 += bf2f(xp[lane + 64]);
      s2 += bf2f(xp[lane + 128]);
      xp += DMODEL;
    }
    part[wave][lane] = s0;
    part[wave][lane + 64] = s1;
    part[wave][lane + 128] = s2;
  }
  __syncthreads();
  if (tid < DMODEL)
    zsh[tid] = (part[0][tid] + part[1][tid] + part[2][tid] + part[3][tid]) * (1.f / 197.f);
  __syncthreads();
  const int n = blockIdx.x * 250 + tid;
  if (tid < 250 && n < NCLS) {
    float s = HB[n];
#pragma unroll 8
    for (int d = 0; d < DMODEL; ++d)
      s = fmaf(zsh[d], HWt[(size_t)d * NCLS + n], s);
    OUTp[(size_t)b * NCLS + n] = s;
  }
}

// ---------------- host orchestration ----------------
extern "C" void kernel_launch(void* const* d_in, const int* in_sizes, int n_in,
                              void* d_out, int out_size, void* d_ws, size_t ws_size,
                              hipStream_t stream) {
  const float* x        = (const float*)d_in[0];
  const float* patch_w  = (const float*)d_in[1];
  const float* patch_b  = (const float*)d_in[2];
  const float* pe_ln_g  = (const float*)d_in[3];
  const float* pe_ln_b  = (const float*)d_in[4];
  const float* cls_tok  = (const float*)d_in[5];
  const float* pos_emb  = (const float*)d_in[6];
  const float* Wq = (const float*)d_in[7];
  const float* bq = (const float*)d_in[8];
  const float* Wk = (const float*)d_in[9];
  const float* bk = (const float*)d_in[10];
  const float* Wv = (const float*)d_in[11];
  const float* bv = (const float*)d_in[12];
  const float* Wo = (const float*)d_in[13];
  const float* bo = (const float*)d_in[14];
  const float* ln1_g = (const float*)d_in[15];
  const float* ln1_b = (const float*)d_in[16];
  const float* ln2_g = (const float*)d_in[17];
  const float* ln2_b = (const float*)d_in[18];
  const float* lnb_g = (const float*)d_in[19];
  const float* lnb_b = (const float*)d_in[20];
  const float* W1 = (const float*)d_in[21];
  const float* b1 = (const float*)d_in[22];
  const float* W2 = (const float*)d_in[23];
  const float* b2 = (const float*)d_in[24];
  const float* omega  = (const float*)d_in[25];
  const float* head_w = (const float*)d_in[26];
  const float* head_b = (const float*)d_in[27];
  float* out = (float*)d_out;
  char* wsb = (char*)d_ws;

  size_t off = 0;
  auto carve = [&](size_t bytes) { size_t o = off; off += (bytes + 255) & ~(size_t)255; return o; };
  ushort* xc     = (ushort*)(wsb + carve((size_t)MPAD * 192 * 2));
  ushort* qkv    = (ushort*)(wsb + carve((size_t)MPAD * 576 * 2));
  ushort* ab     = (ushort*)(wsb + carve((size_t)MPAD * 192 * 2));
  ushort* hidden = (ushort*)(wsb + carve((size_t)MPAD * 768 * 2));   // aliases im2col
  ushort* KVt    = (ushort*)(wsb + carve((size_t)192 * 80 * 256 * 2));
  ushort* Vt     = (ushort*)(wsb + carve((size_t)192 * 64 * VLT * 2 + 1024)); // +pad for swz overrun
  float*  bqkv   = (float*)(wsb + carve((size_t)12 * 576 * 4));
  ushort* Wqkv_bf = (ushort*)(wsb + carve((size_t)12 * 640 * 192 * 2));
  ushort* Wo_bf   = (ushort*)(wsb + carve((size_t)12 * 256 * 192 * 2));
  ushort* W1_bf   = (ushort*)(wsb + carve((size_t)12 * 768 * 192 * 2));
  ushort* W2_bf   = (ushort*)(wsb + carve((size_t)12 * 256 * 768 * 2));
  ushort* Wp_bf   = (ushort*)(wsb + carve((size_t)256 * 768 * 2));
  ushort* Om_bf   = (ushort*)(wsb + carve((size_t)12 * 128 * 64 * 2));
  float*  HWt     = (float*)(wsb + carve((size_t)3 * 192 * NCLS * 4));
  ushort* i2c     = hidden;   // patch GEMM consumes before FF uses hidden

  // ---- zero Vt (pad cols l in [197,208) + swz-overrun tail must be finite 0) ----
  {
    const int n16 = (int)(((size_t)192 * 64 * VLT * 2 + 1024) / 16);
    zero_buf<<<(n16 + 255) / 256, 256, 0, stream>>>((uint4*)Vt, n16);
  }

  // ---- pre-conversion ----
  conv_qkv<<<dim3(432, 12), 256, 0, stream>>>(Wq, Wk, Wv, bq, bk, bv, Wqkv_bf, bqkv);
  conv_pad<<<dim3(144, 12), 256, 0, stream>>>(Wo, Wo_bf, 36864, 256 * 192);
  conv_pad<<<dim3(576, 12), 256, 0, stream>>>(W1, W1_bf, 147456, 768 * 192);
  conv_pad<<<dim3(576, 12), 256, 0, stream>>>(W2, W2_bf, 147456, 256 * 768);
  conv_pad<<<dim3(576, 1), 256, 0, stream>>>(patch_w, Wp_bf, 147456, 256 * 768);
  conv_omt<<<dim3(32, 12), 256, 0, stream>>>(omega, Om_bf);
  conv_headw<<<dim3(750, 3), 256, 0, stream>>>(head_w, HWt);

  // ---- patch embedding ----
  im2col_kernel<<<BPROWS, 256, 0, stream>>>(x, i2c);
  gemm_bf2<<<dim3(98, 3), 256, 0, stream>>>(i2c, KPATCH, Wp_bf, KPATCH,
      patch_b, ab, DMODEL, nullptr, KPATCH, MODE_PLAIN);
  assemble_kernel<<<BLROWS / 4, 256, 0, stream>>>(ab, pe_ln_g, pe_ln_b,
                                                  cls_tok, pos_emb, xc);

  const int exits[3] = {3, 7, 11};
  for (int i = 0; i < NDEPTH; ++i) {
    // QKV: 128x64 tiles, N=576 -> 9 N-tiles, 891 blocks; V -> Vt
    gemm_bf2<<<dim3(99, 9), 256, 0, stream>>>(xc, DMODEL,
        Wqkv_bf + (size_t)i * 640 * 192, DMODEL, bqkv + i * 576,
        qkv, 576, Vt, DMODEL, MODE_QKV);
    // fused FAVOR-K + KV (V pre-transposed)
    kv_fused<<<dim3(192, 2), 256, 0, stream>>>(qkv,
        Om_bf + (size_t)i * 8192, Vt, KVt);
    // fused FAVOR-Q + attn (64-row tiles, 768 blocks)
    attn_fused<<<dim3(4, 192), 256, 0, stream>>>(qkv,
        Om_bf + (size_t)i * 8192, KVt, ab);
    // O-proj + bias + residual + LN1, fused (32-row tiles, 396 blocks)
    gemm_ln<<<MPAD / 32, 256, 0, stream>>>(ab, DMODEL,
        Wo_bf + (size_t)i * 256 * 192, DMODEL, bo + i * DMODEL, xc,
        ln1_g + i * DMODEL, ln1_b + i * DMODEL, nullptr, nullptr,
        DMODEL, 0);
    // W1: 128x64 tiles, N=768 -> 12 N-tiles, 1188 blocks
    gemm_bf2<<<dim3(99, 12), 256, 0, stream>>>(xc, DMODEL,
        W1_bf + (size_t)i * 768 * 192, DMODEL, b1 + i * FFDIM,
        hidden, FFDIM, nullptr, DMODEL, MODE_RELU);
    // W2 + bias + residual + LN2 + LNb, fused (32-row tiles, 396 blocks)
    gemm_ln<<<MPAD / 32, 256, 0, stream>>>(hidden, FFDIM,
        W2_bf + (size_t)i * 256 * 768, FFDIM, b2 + i * DMODEL, xc,
        ln2_g + i * DMODEL, ln2_b + i * DMODEL,
        lnb_g + i * DMODEL, lnb_b + i * DMODEL,
        FFDIM, 1);

    for (int j = 0; j < 3; ++j) {
      if (i == exits[j]) {
        head_kernel<<<dim3(4, BB), 256, 0, stream>>>(
            xc, HWt + (size_t)j * 192 * NCLS, head_b + (size_t)j * NCLS,
            out + (size_t)j * BB * NCLS);
      }
    }
  }
}